// Round 7
// baseline (701.811 us; speedup 1.0000x reference)
//
#include <hip/hip_runtime.h>
#include <cmath>

// ---------------------------------------------------------------------------
// ClassifierGNN: N=768 nodes, D=128 feat, edge-MLP channels 256->128->1,
// node-MLP 256->130->65.
// 3 recompute phases (stats0, stats1, sim) using bf16 MFMA 16x16x32.
// R6 -> R7: latency pipeline.
//   R6 killed the spill (WRITE 1.38GB->9.5MB, 305us/phase) but MfmaUtil=10%,
//   HBM=0.6%: latency-bound. The per-ks sched_barrier(0) pair serialized
//   load-latency (L2 ~200cy) against the 8-MFMA cluster (~40cy).
//   Fix: 1-deep register ping-pong prefetch (loads for ks+1 issue before
//   MFMA of ks; single sched_barrier after each MFMA cluster caps hoisting
//   at 2 stages = ~48 operand regs). X-gen restructured to 16B reads/8B
//   writes to kill the 4-way LDS bank conflict (1.12e7 counter).
// ---------------------------------------------------------------------------

#define N_NODES 768
#define NBJ 96          // j-tiles per row of tiles (768/8)
#define NTILES 9216     // (768/8) * (768/8)

// LDS layout (bytes), NO overlay: total 59392 -> 2 blocks/CU (=> 128-reg budget).
#define L_FEAT 0        // 16 rows * 128 f32 = 8192
#define L_X    8192     // 64 q * 128 c * bf16 = 16384
#define L_A0   24576    // 64 q * 256 c * bf16 = 32768
#define L_SB   57344    // 512 f32 = 2048 (stat/sim staging)
#define L_TOT  59392

static_assert(L_TOT > 53760 && L_TOT <= 81920, "want exactly 2 blocks/CU");

typedef __bf16 bf16x8_t __attribute__((ext_vector_type(8)));
typedef float f32x4_t __attribute__((ext_vector_type(4)));
typedef unsigned short u16x8_t __attribute__((ext_vector_type(8)));
typedef unsigned short u16x4_t __attribute__((ext_vector_type(4)));

__device__ __forceinline__ unsigned short f2bf(float f) {
  unsigned int u = __float_as_uint(f);
  u += 0x7fffu + ((u >> 16) & 1u);          // round-to-nearest-even
  return (unsigned short)(u >> 16);
}

// ---------------------------------------------------------------------------
// Weight pre-cast: f32 -> bf16, same row-major layout (fragment-ready).
// ---------------------------------------------------------------------------
__global__ void wcast_kernel(const float* __restrict__ w0, const float* __restrict__ w1,
                             unsigned short* __restrict__ w0b, unsigned short* __restrict__ w1b)
{
  const int i = (int)(blockIdx.x * 256 + threadIdx.x);
  if (i < 32768) { w0b[i] = f2bf(w0[i]); w1b[i] = f2bf(w1[i]); }
}

// ---------------------------------------------------------------------------
// Fused pair-MLP kernel.
// Tile = 8 i-rows x 8 j-cols = 64 pairs. 512 threads = 8 waves.
// Waves: aog = wid>>1 (layer0: 64 o's / layer1: 32 p's), bqg = wid&1 (32 q's).
// PHASE 1: z0 -> per-channel sum/sumsq (atomics)
// PHASE 2: z0 -> a0 -> z1 -> sum/sumsq
// PHASE 3: z0 -> a0 -> z1 -> a1 -> sim = sigmoid(wout.a1 + bout)
// ---------------------------------------------------------------------------

// layer-0 load/mfma clusters (ping-pong buffers passed in)
#define LOAD0(AF, BF, KS)                                                      \
  {                                                                            \
    _Pragma("unroll") for (int ot_ = 0; ot_ < 4; ++ot_)                        \
      AF[ot_] = *(const bf16x8_t*)(W0base + ot_ * 2048 + (KS) * 32);           \
    _Pragma("unroll") for (int qt_ = 0; qt_ < 2; ++qt_) {                      \
      const int q_ = bqg * 32 + qt_ * 16 + lr;                                 \
      const int off_ = ((q_ << 8) + ((KS) << 6) + (g << 4)) ^ ((q_ & 7) << 4); \
      BF[qt_] = *(const bf16x8_t*)(Xb + off_);                                 \
    }                                                                          \
  }

#define MFMA0(AF, BF)                                                          \
  {                                                                            \
    _Pragma("unroll") for (int ot_ = 0; ot_ < 4; ++ot_)                        \
      _Pragma("unroll") for (int qt_ = 0; qt_ < 2; ++qt_)                      \
        acc0[ot_][qt_] = __builtin_amdgcn_mfma_f32_16x16x32_bf16(              \
            AF[ot_], BF[qt_], acc0[ot_][qt_], 0, 0, 0);                        \
  }

// layer-1 load/mfma clusters
#define LOAD1(AF, BF, KS)                                                      \
  {                                                                            \
    _Pragma("unroll") for (int pt_ = 0; pt_ < 2; ++pt_)                        \
      AF[pt_] = *(const bf16x8_t*)(W1base + pt_ * 4096 + (KS) * 32);           \
    _Pragma("unroll") for (int qt_ = 0; qt_ < 2; ++qt_) {                      \
      const int q_ = bqg * 32 + qt_ * 16 + lr;                                 \
      const int off_ = ((q_ << 9) + ((KS) << 6) + (g << 4)) ^ ((q_ & 7) << 4); \
      BF[qt_] = *(const bf16x8_t*)(Ab + off_);                                 \
    }                                                                          \
  }

#define MFMA1(AF, BF)                                                          \
  {                                                                            \
    _Pragma("unroll") for (int pt_ = 0; pt_ < 2; ++pt_)                        \
      _Pragma("unroll") for (int qt_ = 0; qt_ < 2; ++qt_)                      \
        acc1[pt_][qt_] = __builtin_amdgcn_mfma_f32_16x16x32_bf16(              \
            AF[pt_], BF[qt_], acc1[pt_][qt_], 0, 0, 0);                        \
  }

#define SBAR __builtin_amdgcn_sched_barrier(0)

template<int PHASE>
__global__ void
__attribute__((amdgpu_flat_work_group_size(512, 512)))
pair_phase_kernel(const float* __restrict__ feat,
                  const unsigned short* __restrict__ W0b,
                  const unsigned short* __restrict__ W1b,
                  const float* __restrict__ wout,
                  const float* __restrict__ boutp,
                  const float* __restrict__ sc0, const float* __restrict__ sh0,
                  const float* __restrict__ sc1, const float* __restrict__ sh1,
                  float* __restrict__ stats,
                  float* __restrict__ sim)
{
  __shared__ __align__(16) unsigned char smem[L_TOT];
  float* featL = (float*)(smem + L_FEAT);
  unsigned char* Xb = smem + L_X;
  unsigned char* Ab = smem + L_A0;
  float* sb = (float*)(smem + L_SB);

  const int tid = (int)threadIdx.x;
  const int wid = tid >> 6;
  const int lane = tid & 63;
  const int lr = lane & 15;
  const int g = lane >> 4;
  const int aog = wid >> 1;   // 0..3
  const int bqg = wid & 1;    // 0..1

  // per-wave weight base pointers (element offsets; +ot*2048 / +pt*4096 later)
  const unsigned short* W0base = W0b + (aog * 64 + lr) * 128 + g * 8;
  const unsigned short* W1base = W1b + (aog * 32 + lr) * 256 + g * 8;

  float s1[4][4], s2v[4][4];   // phase1 accumulators (z0)
  float t1[2][4], t2v[2][4];   // phase2 accumulators (z1)
  if constexpr (PHASE == 1) {
#pragma unroll
    for (int ot = 0; ot < 4; ++ot)
#pragma unroll
      for (int r2 = 0; r2 < 4; ++r2) { s1[ot][r2] = 0.f; s2v[ot][r2] = 0.f; }
  }
  if constexpr (PHASE == 2) {
#pragma unroll
    for (int pt = 0; pt < 2; ++pt)
#pragma unroll
      for (int r2 = 0; r2 < 4; ++r2) { t1[pt][r2] = 0.f; t2v[pt][r2] = 0.f; }
  }

  for (int tile = (int)blockIdx.x; tile < NTILES; tile += (int)gridDim.x) {
    const int ti = tile / NBJ;
    const int i0 = ti * 8;
    const int j0 = (tile - ti * NBJ) * 8;
    __syncthreads();   // prev tile's LDS reads done before overwrite

    // stage 16 feat rows (8 i-rows, 8 j-rows) -> LDS (512 f32x4 items)
    {
      const int rrow = tid >> 5;
      const int c4 = (tid & 31) * 4;
      const int grow = (rrow < 8) ? (i0 + rrow) : (j0 + rrow - 8);
      *(f32x4_t*)(featL + rrow * 128 + c4) = *(const f32x4_t*)(feat + grow * 128 + c4);
    }
    __syncthreads();

    // generate X[q][c] = |f_i[c] - f_j[c]| as bf16, XOR-swizzled rows.
    // 16B/lane reads (2-way bank alias = free), 8B writes. 2048 items.
#pragma unroll
    for (int it = 0; it < 4; ++it) {
      const int id = tid + it * 512;
      const int q = id >> 5;
      const int c0 = (id & 31) * 4;
      const f32x4_t a = *(const f32x4_t*)(featL + (q >> 3) * 128 + c0);
      const f32x4_t b = *(const f32x4_t*)(featL + (8 + (q & 7)) * 128 + c0);
      u16x4_t xv;
#pragma unroll
      for (int s = 0; s < 4; ++s) xv[s] = f2bf(fabsf(a[s] - b[s]));
      const int off = ((q << 8) + (c0 << 1)) ^ ((q & 7) << 4);
      *(u16x4_t*)(Xb + off) = xv;
    }
    __syncthreads();

    // ---- layer 0: z0[o][q] = W0 . X ---- (ping-pong 1-deep pipeline)
    f32x4_t acc0[4][2];
#pragma unroll
    for (int ot = 0; ot < 4; ++ot)
#pragma unroll
      for (int qt = 0; qt < 2; ++qt)
        acc0[ot][qt] = f32x4_t{0.f, 0.f, 0.f, 0.f};
    {
      bf16x8_t A0p[4], B0p[2], A0q[4], B0q[2];
      LOAD0(A0p, B0p, 0);
      LOAD0(A0q, B0q, 1); MFMA0(A0p, B0p); SBAR;
      LOAD0(A0p, B0p, 2); MFMA0(A0q, B0q); SBAR;
      LOAD0(A0q, B0q, 3); MFMA0(A0p, B0p); SBAR;
      MFMA0(A0q, B0q);
    }

    if constexpr (PHASE == 1) {
#pragma unroll
      for (int ot = 0; ot < 4; ++ot)
#pragma unroll
        for (int qt = 0; qt < 2; ++qt)
#pragma unroll
          for (int r2 = 0; r2 < 4; ++r2) {
            const float z = acc0[ot][qt][r2];
            s1[ot][r2] += z;
            s2v[ot][r2] += z * z;
          }
    } else {
      // a0 = lrelu(scale0*z0 + shift0), write bf16 into swizzled LDS [q][o]
#pragma unroll
      for (int ot = 0; ot < 4; ++ot) {
        const int o0 = aog * 64 + ot * 16 + g * 4;
        const f32x4_t scv = *(const f32x4_t*)(sc0 + o0);
        const f32x4_t shv = *(const f32x4_t*)(sh0 + o0);
#pragma unroll
        for (int qt = 0; qt < 2; ++qt) {
          const int q = bqg * 32 + qt * 16 + lr;
          u16x4_t pk;
#pragma unroll
          for (int r2 = 0; r2 < 4; ++r2) {
            float v = acc0[ot][qt][r2] * scv[r2] + shv[r2];
            v = (v >= 0.f) ? v : 0.01f * v;
            pk[r2] = f2bf(v);
          }
          const int off = ((q << 9) + (o0 << 1)) ^ ((q & 7) << 4);
          *(u16x4_t*)(Ab + off) = pk;
        }
      }
      __syncthreads();

      // ---- layer 1: z1[p][q] = W1 . a0 ---- (ping-pong 1-deep pipeline)
      f32x4_t acc1[2][2];
#pragma unroll
      for (int pt = 0; pt < 2; ++pt)
#pragma unroll
        for (int qt = 0; qt < 2; ++qt)
          acc1[pt][qt] = f32x4_t{0.f, 0.f, 0.f, 0.f};
      {
        bf16x8_t A1p[2], B1p[2], A1q[2], B1q[2];
        LOAD1(A1p, B1p, 0);
        LOAD1(A1q, B1q, 1); MFMA1(A1p, B1p); SBAR;
        LOAD1(A1p, B1p, 2); MFMA1(A1q, B1q); SBAR;
        LOAD1(A1q, B1q, 3); MFMA1(A1p, B1p); SBAR;
        LOAD1(A1p, B1p, 4); MFMA1(A1q, B1q); SBAR;
        LOAD1(A1q, B1q, 5); MFMA1(A1p, B1p); SBAR;
        LOAD1(A1p, B1p, 6); MFMA1(A1q, B1q); SBAR;
        LOAD1(A1q, B1q, 7); MFMA1(A1p, B1p); SBAR;
        MFMA1(A1q, B1q);
      }

      if constexpr (PHASE == 2) {
#pragma unroll
        for (int pt = 0; pt < 2; ++pt)
#pragma unroll
          for (int qt = 0; qt < 2; ++qt)
#pragma unroll
            for (int r2 = 0; r2 < 4; ++r2) {
              const float z = acc1[pt][qt][r2];
              t1[pt][r2] += z;
              t2v[pt][r2] += z * z;
            }
      } else {
        // PHASE 3: a1 = lrelu(scale1*z1+shift1); sim = sigmoid(wout.a1+bout)
        float part[2] = {0.f, 0.f};
#pragma unroll
        for (int pt = 0; pt < 2; ++pt) {
          const int p0 = aog * 32 + pt * 16 + g * 4;
          const f32x4_t scv = *(const f32x4_t*)(sc1 + p0);
          const f32x4_t shv = *(const f32x4_t*)(sh1 + p0);
          const f32x4_t wv = *(const f32x4_t*)(wout + p0);
#pragma unroll
          for (int qt = 0; qt < 2; ++qt)
#pragma unroll
            for (int r2 = 0; r2 < 4; ++r2) {
              float v = acc1[pt][qt][r2] * scv[r2] + shv[r2];
              v = (v >= 0.f) ? v : 0.01f * v;
              part[qt] += wv[r2] * v;
            }
        }
#pragma unroll
        for (int qt = 0; qt < 2; ++qt) {   // reduce over g (p sub-slots)
          part[qt] += __shfl_xor(part[qt], 16, 64);
          part[qt] += __shfl_xor(part[qt], 32, 64);
        }
        if (lane < 16) {
#pragma unroll
          for (int qt = 0; qt < 2; ++qt)
            sb[aog * 64 + bqg * 32 + qt * 16 + lr] = part[qt];
        }
        __syncthreads();
        if (tid < 64) {
          const float sv = sb[tid] + sb[64 + tid] + sb[128 + tid] + sb[192 + tid] + boutp[0];
          const float sg = 1.f / (1.f + expf(-sv));
          sim[(i0 + (tid >> 3)) * N_NODES + j0 + (tid & 7)] = sg;
        }
      }
    }
  }

  // ---- stats flush: shuffle-reduce over the 16 q-lanes, combine the two
  //      q-group waves in LDS, then one atomicAdd per stat per block. ----
  if constexpr (PHASE == 1) {
#pragma unroll
    for (int ot = 0; ot < 4; ++ot)
#pragma unroll
      for (int r2 = 0; r2 < 4; ++r2) {
        float v1 = s1[ot][r2], v2 = s2v[ot][r2];
#pragma unroll
        for (int m = 1; m < 16; m <<= 1) {
          v1 += __shfl_xor(v1, m, 64);
          v2 += __shfl_xor(v2, m, 64);
        }
        s1[ot][r2] = v1; s2v[ot][r2] = v2;
      }
    __syncthreads();
    if (bqg == 0 && lr == 0) {
#pragma unroll
      for (int ot = 0; ot < 4; ++ot)
#pragma unroll
        for (int r2 = 0; r2 < 4; ++r2) {
          const int o = aog * 64 + ot * 16 + g * 4 + r2;
          sb[o] = s1[ot][r2];
          sb[256 + o] = s2v[ot][r2];
        }
    }
    __syncthreads();
    if (bqg == 1 && lr == 0) {
#pragma unroll
      for (int ot = 0; ot < 4; ++ot)
#pragma unroll
        for (int r2 = 0; r2 < 4; ++r2) {
          const int o = aog * 64 + ot * 16 + g * 4 + r2;
          sb[o] += s1[ot][r2];
          sb[256 + o] += s2v[ot][r2];
        }
    }
    __syncthreads();
    atomicAdd(stats + tid, sb[tid]);   // tid < 512: 256 sums + 256 sumsq
  }
  if constexpr (PHASE == 2) {
#pragma unroll
    for (int pt = 0; pt < 2; ++pt)
#pragma unroll
      for (int r2 = 0; r2 < 4; ++r2) {
        float v1 = t1[pt][r2], v2 = t2v[pt][r2];
#pragma unroll
        for (int m = 1; m < 16; m <<= 1) {
          v1 += __shfl_xor(v1, m, 64);
          v2 += __shfl_xor(v2, m, 64);
        }
        t1[pt][r2] = v1; t2v[pt][r2] = v2;
      }
    __syncthreads();
    if (bqg == 0 && lr == 0) {
#pragma unroll
      for (int pt = 0; pt < 2; ++pt)
#pragma unroll
        for (int r2 = 0; r2 < 4; ++r2) {
          const int p = aog * 32 + pt * 16 + g * 4 + r2;
          sb[p] = t1[pt][r2];
          sb[128 + p] = t2v[pt][r2];
        }
    }
    __syncthreads();
    if (bqg == 1 && lr == 0) {
#pragma unroll
      for (int pt = 0; pt < 2; ++pt)
#pragma unroll
        for (int r2 = 0; r2 < 4; ++r2) {
          const int p = aog * 32 + pt * 16 + g * 4 + r2;
          sb[p] += t1[pt][r2];
          sb[128 + p] += t2v[pt][r2];
        }
    }
    __syncthreads();
    if (tid < 256) atomicAdd(stats + tid, sb[tid]);
  }
}

// ---------------------------------------------------------------------------
// finalize: mean/var -> per-channel scale/shift for BN(+gamma,beta)
// ---------------------------------------------------------------------------
__global__ void finalize_kernel(const float* __restrict__ ssum, const float* __restrict__ ssq,
                                const float* __restrict__ gamma, const float* __restrict__ beta,
                                float* __restrict__ sc, float* __restrict__ sh, int n)
{
  const int i = (int)(blockIdx.x * blockDim.x + threadIdx.x);
  if (i < n) {
    const float invN = 1.f / 589824.f;
    const float m = ssum[i] * invN;
    const float var = ssq[i] * invN - m * m;
    const float is = rsqrtf(var + 1e-5f);
    const float s = gamma[i] * is;
    sc[i] = s;
    sh[i] = beta[i] - m * s;
  }
}

// ---------------------------------------------------------------------------
// edge graph tail: colsum of edge matrix (edge = same_label*sim + I + 1e-6)
// ---------------------------------------------------------------------------
__global__ void colsum_kernel(const float* __restrict__ sim, const int* __restrict__ lab,
                              float* __restrict__ colsum)
{
  const int t = (int)threadIdx.x;
  const int bi = (int)blockIdx.x * 8;
  const int lj0 = lab[t], lj1 = lab[t + 256], lj2 = lab[t + 512];
  float a0 = 0.f, a1 = 0.f, a2 = 0.f;
  for (int r = 0; r < 8; ++r) {
    const int i = bi + r;
    const int li = lab[i];
    const float* srow = sim + i * N_NODES;
    a0 += ((li == lj0) ? srow[t] : 0.f) + ((i == t) ? 1.f : 0.f) + 1e-6f;
    a1 += ((li == lj1) ? srow[t + 256] : 0.f) + ((i == t + 256) ? 1.f : 0.f) + 1e-6f;
    a2 += ((li == lj2) ? srow[t + 512] : 0.f) + ((i == t + 512) ? 1.f : 0.f) + 1e-6f;
  }
  atomicAdd(colsum + t, a0);
  atomicAdd(colsum + t + 256, a1);
  atomicAdd(colsum + t + 512, a2);
}

// aggr[i][:] = (e_row_i / max(sum|e_row_i|,1e-12)) @ feat,  e = colnorm(edge) with zero diag
__global__ void aggr_kernel(const float* __restrict__ sim, const int* __restrict__ lab,
                            const float* __restrict__ colsum, const float* __restrict__ feat,
                            float* __restrict__ aggr)
{
  __shared__ float wrow[N_NODES];
  __shared__ float red[128];
  const int i = (int)blockIdx.x, t = (int)threadIdx.x;
  const int li = lab[i];
  const float* srow = sim + i * N_NODES;
  float rs = 0.f;
  for (int s = 0; s < 6; ++s) {
    const int j = t + s * 128;
    const float e = ((li == lab[j]) ? srow[j] : 0.f) + ((i == j) ? 1.f : 0.f) + 1e-6f;
    const float w = (j == i) ? 0.f : e / colsum[j];
    wrow[j] = w;
    rs += w;
  }
  red[t] = rs;
  __syncthreads();
  for (int off = 64; off > 0; off >>= 1) {
    if (t < off) red[t] += red[t + off];
    __syncthreads();
  }
  const float inv = 1.f / fmaxf(red[0], 1e-12f);
  float acc = 0.f;
  for (int j = 0; j < N_NODES; ++j) acc += wrow[j] * feat[j * 128 + t];
  aggr[i * 128 + t] = acc * inv;
}

// node MLP layer0: h2[r][n] = lrelu(bn(n_w0 @ [feat;aggr]^T)), bn over n
__global__ void mlp0_kernel(const float* __restrict__ feat, const float* __restrict__ aggr,
                            const float* __restrict__ w, const float* __restrict__ gamma,
                            const float* __restrict__ beta, float* __restrict__ h2)
{
  __shared__ float wr[256];
  __shared__ float redA[256], redB[256];
  const int r = (int)blockIdx.x, t = (int)threadIdx.x;
  wr[t] = w[r * 256 + t];
  __syncthreads();
  float v[3];
#pragma unroll
  for (int s = 0; s < 3; ++s) {
    const int n = t + s * 256;
    const float* fr = feat + n * 128;
    const float* ar = aggr + n * 128;
    float acc = 0.f;
#pragma unroll 4
    for (int c = 0; c < 128; c += 4) {
      const f32x4_t fv = *(const f32x4_t*)(fr + c);
      acc += wr[c] * fv[0] + wr[c + 1] * fv[1] + wr[c + 2] * fv[2] + wr[c + 3] * fv[3];
    }
#pragma unroll 4
    for (int c = 0; c < 128; c += 4) {
      const f32x4_t av = *(const f32x4_t*)(ar + c);
      acc += wr[128 + c] * av[0] + wr[129 + c] * av[1] + wr[130 + c] * av[2] + wr[131 + c] * av[3];
    }
    v[s] = acc;
  }
  redA[t] = v[0] + v[1] + v[2];
  redB[t] = v[0] * v[0] + v[1] * v[1] + v[2] * v[2];
  __syncthreads();
  for (int off = 128; off > 0; off >>= 1) {
    if (t < off) { redA[t] += redA[t + off]; redB[t] += redB[t + off]; }
    __syncthreads();
  }
  const float m = redA[0] * (1.f / 768.f);
  const float var = redB[0] * (1.f / 768.f) - m * m;
  const float is = rsqrtf(var + 1e-5f);
  const float sc = gamma[r] * is;
  const float sh = beta[r] - m * sc;
#pragma unroll
  for (int s = 0; s < 3; ++s) {
    float y = v[s] * sc + sh;
    y = (y >= 0.f) ? y : 0.01f * y;
    h2[r * 768 + t + s * 256] = y;
  }
}

// node MLP layer1: logits[n][r] = bn(n_w1 @ h2)[r][n]  (no lrelu)
__global__ void mlp1_kernel(const float* __restrict__ h2, const float* __restrict__ w,
                            const float* __restrict__ gamma, const float* __restrict__ beta,
                            float* __restrict__ logits)
{
  __shared__ float wr[130];
  __shared__ float redA[256], redB[256];
  const int r = (int)blockIdx.x, t = (int)threadIdx.x;
  if (t < 130) wr[t] = w[r * 130 + t];
  __syncthreads();
  float v[3];
#pragma unroll
  for (int s = 0; s < 3; ++s) {
    const int n = t + s * 256;
    float acc = 0.f;
    for (int c = 0; c < 130; ++c) acc += wr[c] * h2[c * 768 + n];
    v[s] = acc;
  }
  redA[t] = v[0] + v[1] + v[2];
  redB[t] = v[0] * v[0] + v[1] * v[1] + v[2] * v[2];
  __syncthreads();
  for (int off = 128; off > 0; off >>= 1) {
    if (t < off) { redA[t] += redA[t + off]; redB[t] += redB[t + off]; }
    __syncthreads();
  }
  const float m = redA[0] * (1.f / 768.f);
  const float var = redB[0] * (1.f / 768.f) - m * m;
  const float is = rsqrtf(var + 1e-5f);
  const float sc = gamma[r] * is;
  const float sh = beta[r] - m * sc;
#pragma unroll
  for (int s = 0; s < 3; ++s) {
    const float y = v[s] * sc + sh;
    logits[(t + s * 256) * 65 + r] = y;
  }
}

// ---------------------------------------------------------------------------
extern "C" void kernel_launch(void* const* d_in, const int* in_sizes, int n_in,
                              void* d_out, int out_size, void* d_ws, size_t ws_size,
                              hipStream_t stream)
{
  (void)in_sizes; (void)n_in; (void)out_size; (void)ws_size;
  const float* feat   = (const float*)d_in[0];
  const int*   lab    = (const int*)d_in[1];
  const float* e_w0   = (const float*)d_in[2];
  const float* e_g0   = (const float*)d_in[3];
  const float* e_b0   = (const float*)d_in[4];
  const float* e_w1   = (const float*)d_in[5];
  const float* e_g1   = (const float*)d_in[6];
  const float* e_b1   = (const float*)d_in[7];
  const float* e_wout = (const float*)d_in[8];
  const float* e_bout = (const float*)d_in[9];
  const float* n_w0   = (const float*)d_in[10];
  const float* n_g0   = (const float*)d_in[11];
  const float* n_b0   = (const float*)d_in[12];
  const float* n_w1   = (const float*)d_in[13];
  const float* n_g1   = (const float*)d_in[14];
  const float* n_b1   = (const float*)d_in[15];

  float* out = (float*)d_out;
  float* logits = out;                 // 768*65
  float* sim = out + 768 * 65;         // 768*768

  // workspace layout (floats)
  float* wsf = (float*)d_ws;
  float* S0A = wsf + 0;      // 256  (sum z0)
  float* S0B = wsf + 256;    // 256  (sumsq z0)
  float* S1A = wsf + 512;    // 128
  float* S1B = wsf + 640;    // 128
  float* colsum = wsf + 768; // 768
  float* sc0 = wsf + 1536;   // 256
  float* sh0 = wsf + 1792;   // 256
  float* sc1 = wsf + 2048;   // 128
  float* sh1 = wsf + 2176;   // 128
  float* aggr = wsf + 2304;            // 768*128
  float* h2 = wsf + 2304 + 768 * 128;  // 130*768
  unsigned short* W0bf = (unsigned short*)(wsf + 200448);   // 32768 bf16 (64KB)
  unsigned short* W1bf = W0bf + 32768;                      // 32768 bf16 (64KB)

  // zero stat + colsum accumulators (replayed every graph launch)
  hipMemsetAsync(d_ws, 0, 2304 * sizeof(float), stream);

  wcast_kernel<<<128, 256, 0, stream>>>(e_w0, e_w1, W0bf, W1bf);

  pair_phase_kernel<1><<<2304, 512, 0, stream>>>(feat, W0bf, nullptr, nullptr, nullptr,
                                                 nullptr, nullptr, nullptr, nullptr, S0A, nullptr);
  finalize_kernel<<<1, 256, 0, stream>>>(S0A, S0B, e_g0, e_b0, sc0, sh0, 256);
  pair_phase_kernel<2><<<2304, 512, 0, stream>>>(feat, W0bf, W1bf, nullptr, nullptr,
                                                 sc0, sh0, nullptr, nullptr, S1A, nullptr);
  finalize_kernel<<<1, 128, 0, stream>>>(S1A, S1B, e_g1, e_b1, sc1, sh1, 128);
  pair_phase_kernel<3><<<4608, 512, 0, stream>>>(feat, W0bf, W1bf, e_wout, e_bout,
                                                 sc0, sh0, sc1, sh1, nullptr, sim);
  colsum_kernel<<<96, 256, 0, stream>>>(sim, lab, colsum);
  aggr_kernel<<<768, 128, 0, stream>>>(sim, lab, colsum, feat, aggr);
  mlp0_kernel<<<130, 256, 0, stream>>>(feat, aggr, n_w0, n_g0, n_b0, h2);
  mlp1_kernel<<<65, 256, 0, stream>>>(h2, n_w1, n_g1, n_b1, logits);
}

// Round 8
// 496.073 us; speedup vs baseline: 1.4147x; 1.4147x over previous
//
#include <hip/hip_runtime.h>
#include <cmath>

// ---------------------------------------------------------------------------
// ClassifierGNN: N=768 nodes, D=128 feat, edge-MLP channels 256->128->1,
// node-MLP 256->130->65.
// 3 recompute phases (stats0, stats1, sim) using bf16 MFMA 16x16x32.
// R7 -> R8: kill the per-ks L2 weight storm.
//   Diagnosis: per-SIMD budget shows 70% stall; W-frag gathers (stride 256B,
//   16 half-used lines per load, every ks, every tile, every wave) saturate
//   L2 request rate chip-wide. Fix: weights VGPR-persistent, loaded once per
//   block. New wave split: each of 8 waves owns 32 o's (layer0) / 16 p's
//   (layer1), all 64 q. W0f=32 + W1f=32 + acc0=32 + Bf=8 + stats=8 + addr
//   ~= 124 <= 128 budget (R6's proven LDS config, 59.4KB -> 2 blk/CU).
//   Hot loop = LDS reads + MFMA only.
// ---------------------------------------------------------------------------

#define N_NODES 768
#define NBJ 96          // j-tiles per row of tiles (768/8)
#define NTILES 9216     // (768/8) * (768/8)

// LDS layout (bytes), NO overlay: total 59392 -> 2 blocks/CU (=> 128-reg budget).
#define L_FEAT 0        // 16 rows * 128 f32 = 8192
#define L_X    8192     // 64 q * 128 c * bf16 = 16384
#define L_A0   24576    // 64 q * 256 c * bf16 = 32768
#define L_SB   57344    // 512 f32 = 2048 (stat/sim staging)
#define L_TOT  59392

static_assert(L_TOT > 53760 && L_TOT <= 81920, "want exactly 2 blocks/CU");

typedef __bf16 bf16x8_t __attribute__((ext_vector_type(8)));
typedef float f32x4_t __attribute__((ext_vector_type(4)));
typedef unsigned short u16x8_t __attribute__((ext_vector_type(8)));
typedef unsigned short u16x4_t __attribute__((ext_vector_type(4)));

__device__ __forceinline__ unsigned short f2bf(float f) {
  unsigned int u = __float_as_uint(f);
  u += 0x7fffu + ((u >> 16) & 1u);          // round-to-nearest-even
  return (unsigned short)(u >> 16);
}

#define SBAR __builtin_amdgcn_sched_barrier(0)

// ---------------------------------------------------------------------------
// Weight pre-cast: f32 -> bf16, same row-major layout (fragment-ready).
// ---------------------------------------------------------------------------
__global__ void wcast_kernel(const float* __restrict__ w0, const float* __restrict__ w1,
                             unsigned short* __restrict__ w0b, unsigned short* __restrict__ w1b)
{
  const int i = (int)(blockIdx.x * 256 + threadIdx.x);
  if (i < 32768) { w0b[i] = f2bf(w0[i]); w1b[i] = f2bf(w1[i]); }
}

// ---------------------------------------------------------------------------
// Fused pair-MLP kernel.
// Tile = 8 i-rows x 8 j-cols = 64 pairs (q = i_loc*8 + j_loc). 512 thr = 8 waves.
// Wave w owns o in [32w,32w+32) for layer0 (2 ot-tiles) and p in [16w,16w+16)
// for layer1 (1 tile); every wave processes all 64 q (4 qt-tiles).
// Weights are persistent VGPR fragments, loaded once per block.
// PHASE 1: z0 -> per-channel sum/sumsq (atomics)
// PHASE 2: z0 -> a0 -> z1 -> sum/sumsq
// PHASE 3: z0 -> a0 -> z1 -> a1 -> sim = sigmoid(wout.a1 + bout)
// ---------------------------------------------------------------------------
template<int PHASE>
__global__ void
__attribute__((amdgpu_flat_work_group_size(512, 512)))
pair_phase_kernel(const float* __restrict__ feat,
                  const unsigned short* __restrict__ W0b,
                  const unsigned short* __restrict__ W1b,
                  const float* __restrict__ wout,
                  const float* __restrict__ boutp,
                  const float* __restrict__ sc0, const float* __restrict__ sh0,
                  const float* __restrict__ sc1, const float* __restrict__ sh1,
                  float* __restrict__ stats,
                  float* __restrict__ sim)
{
  __shared__ __align__(16) unsigned char smem[L_TOT];
  float* featL = (float*)(smem + L_FEAT);
  unsigned char* Xb = smem + L_X;
  unsigned char* Ab = smem + L_A0;
  float* sb = (float*)(smem + L_SB);

  const int tid = (int)threadIdx.x;
  const int wid = tid >> 6;
  const int lane = tid & 63;
  const int lr = lane & 15;
  const int g = lane >> 4;

  // ---- persistent weight fragments (loaded once per block) ----
  // k-slot convention (k = ks*32 + g*8) matches the B-frag LDS layout, so any
  // HW k-permutation cancels between A and B.
  bf16x8_t W0f[2][4];
#pragma unroll
  for (int ot = 0; ot < 2; ++ot)
#pragma unroll
    for (int ks = 0; ks < 4; ++ks)
      W0f[ot][ks] = *(const bf16x8_t*)(W0b + (wid * 32 + ot * 16 + lr) * 128 + ks * 32 + g * 8);

  bf16x8_t W1f[8];
  if constexpr (PHASE >= 2) {
#pragma unroll
    for (int ks = 0; ks < 8; ++ks)
      W1f[ks] = *(const bf16x8_t*)(W1b + (wid * 16 + lr) * 256 + ks * 32 + g * 8);
  }

  float s1[2][4], s2v[2][4];   // phase1 stats (z0), o = wid*32+ot*16+g*4+r2
  float t1[4], t2v[4];         // phase2 stats (z1), p = wid*16+g*4+r2
  if constexpr (PHASE == 1) {
#pragma unroll
    for (int ot = 0; ot < 2; ++ot)
#pragma unroll
      for (int r2 = 0; r2 < 4; ++r2) { s1[ot][r2] = 0.f; s2v[ot][r2] = 0.f; }
  }
  if constexpr (PHASE == 2) {
#pragma unroll
    for (int r2 = 0; r2 < 4; ++r2) { t1[r2] = 0.f; t2v[r2] = 0.f; }
  }

  for (int tile = (int)blockIdx.x; tile < NTILES; tile += (int)gridDim.x) {
    const int ti = tile / NBJ;
    const int i0 = ti * 8;
    const int j0 = (tile - ti * NBJ) * 8;
    __syncthreads();   // prev tile's LDS reads done before overwrite

    // stage 16 feat rows (8 i-rows, 8 j-rows) -> LDS (512 f32x4 items)
    {
      const int rrow = tid >> 5;
      const int c4 = (tid & 31) * 4;
      const int grow = (rrow < 8) ? (i0 + rrow) : (j0 + rrow - 8);
      *(f32x4_t*)(featL + rrow * 128 + c4) = *(const f32x4_t*)(feat + grow * 128 + c4);
    }
    __syncthreads();

    // generate X[q][c] = |f_i[c] - f_j[c]| as bf16, XOR-swizzled rows
    // 64 q * 16 c-groups = 1024 items; 2 iters/thread
#pragma unroll
    for (int it = 0; it < 2; ++it) {
      const int id = tid + it * 512;
      const int q = id >> 4;
      const int c0 = (id & 15) * 8;
      const float* fi = featL + (q >> 3) * 128 + c0;
      const float* fj = featL + (8 + (q & 7)) * 128 + c0;
      u16x8_t xv;
#pragma unroll
      for (int s = 0; s < 8; ++s) xv[s] = f2bf(fabsf(fi[s] - fj[s]));
      const int off = ((q << 8) + (c0 << 1)) ^ ((q & 7) << 4);
      *(u16x8_t*)(Xb + off) = xv;
    }
    __syncthreads();

    // ---- layer 0: z0[o][q] = W0 . X ----
    // per ks: two half-steps of {2 LDS B-loads, 4 MFMA}; loads of half 2
    // overlap MFMA of half 1 (region between SBARs).
    f32x4_t acc0[2][4];
#pragma unroll
    for (int ot = 0; ot < 2; ++ot)
#pragma unroll
      for (int qt = 0; qt < 4; ++qt)
        acc0[ot][qt] = f32x4_t{0.f, 0.f, 0.f, 0.f};
#pragma unroll
    for (int ks = 0; ks < 4; ++ks) {
      bf16x8_t Ba[2], Bb[2];
#pragma unroll
      for (int h = 0; h < 2; ++h) {
        const int q = h * 16 + lr;
        const int off = ((q << 8) + (ks << 6) + (g << 4)) ^ ((q & 7) << 4);
        Ba[h] = *(const bf16x8_t*)(Xb + off);
      }
      SBAR;
#pragma unroll
      for (int ot = 0; ot < 2; ++ot)
#pragma unroll
        for (int h = 0; h < 2; ++h)
          acc0[ot][h] = __builtin_amdgcn_mfma_f32_16x16x32_bf16(W0f[ot][ks], Ba[h], acc0[ot][h], 0, 0, 0);
#pragma unroll
      for (int h = 0; h < 2; ++h) {
        const int q = 32 + h * 16 + lr;
        const int off = ((q << 8) + (ks << 6) + (g << 4)) ^ ((q & 7) << 4);
        Bb[h] = *(const bf16x8_t*)(Xb + off);
      }
      SBAR;
#pragma unroll
      for (int ot = 0; ot < 2; ++ot)
#pragma unroll
        for (int h = 0; h < 2; ++h)
          acc0[ot][2 + h] = __builtin_amdgcn_mfma_f32_16x16x32_bf16(W0f[ot][ks], Bb[h], acc0[ot][2 + h], 0, 0, 0);
      SBAR;
    }

    if constexpr (PHASE == 1) {
#pragma unroll
      for (int ot = 0; ot < 2; ++ot)
#pragma unroll
        for (int qt = 0; qt < 4; ++qt)
#pragma unroll
          for (int r2 = 0; r2 < 4; ++r2) {
            const float z = acc0[ot][qt][r2];
            s1[ot][r2] += z;
            s2v[ot][r2] += z * z;
          }
    } else {
      // a0 = lrelu(scale0*z0 + shift0), write bf16 into swizzled LDS [q][o]
#pragma unroll
      for (int ot = 0; ot < 2; ++ot) {
        const int o0 = wid * 32 + ot * 16 + g * 4;
        const f32x4_t scv = *(const f32x4_t*)(sc0 + o0);
        const f32x4_t shv = *(const f32x4_t*)(sh0 + o0);
#pragma unroll
        for (int qt = 0; qt < 4; ++qt) {
          const int q = qt * 16 + lr;
          u16x4_t pk;
#pragma unroll
          for (int r2 = 0; r2 < 4; ++r2) {
            float v = acc0[ot][qt][r2] * scv[r2] + shv[r2];
            v = (v >= 0.f) ? v : 0.01f * v;
            pk[r2] = f2bf(v);
          }
          const int off = ((q << 9) + (o0 << 1)) ^ ((q & 7) << 4);
          *(u16x4_t*)(Ab + off) = pk;
        }
      }
      __syncthreads();

      // ---- layer 1: z1[p][q] = W1 . a0 ----
      f32x4_t acc1[4];
#pragma unroll
      for (int qt = 0; qt < 4; ++qt)
        acc1[qt] = f32x4_t{0.f, 0.f, 0.f, 0.f};
#pragma unroll
      for (int ks = 0; ks < 8; ++ks) {
        bf16x8_t Ba[2], Bb[2];
#pragma unroll
        for (int h = 0; h < 2; ++h) {
          const int q = h * 16 + lr;
          const int off = ((q << 9) + (ks << 6) + (g << 4)) ^ ((q & 7) << 4);
          Ba[h] = *(const bf16x8_t*)(Ab + off);
        }
        SBAR;
#pragma unroll
        for (int h = 0; h < 2; ++h)
          acc1[h] = __builtin_amdgcn_mfma_f32_16x16x32_bf16(W1f[ks], Ba[h], acc1[h], 0, 0, 0);
#pragma unroll
        for (int h = 0; h < 2; ++h) {
          const int q = 32 + h * 16 + lr;
          const int off = ((q << 9) + (ks << 6) + (g << 4)) ^ ((q & 7) << 4);
          Bb[h] = *(const bf16x8_t*)(Ab + off);
        }
        SBAR;
#pragma unroll
        for (int h = 0; h < 2; ++h)
          acc1[2 + h] = __builtin_amdgcn_mfma_f32_16x16x32_bf16(W1f[ks], Bb[h], acc1[2 + h], 0, 0, 0);
        SBAR;
      }

      if constexpr (PHASE == 2) {
#pragma unroll
        for (int qt = 0; qt < 4; ++qt)
#pragma unroll
          for (int r2 = 0; r2 < 4; ++r2) {
            const float z = acc1[qt][r2];
            t1[r2] += z;
            t2v[r2] += z * z;
          }
      } else {
        // PHASE 3: a1 = lrelu(scale1*z1+shift1); sim = sigmoid(wout.a1+bout)
        const int p0 = wid * 16 + g * 4;
        const f32x4_t scv = *(const f32x4_t*)(sc1 + p0);
        const f32x4_t shv = *(const f32x4_t*)(sh1 + p0);
        const f32x4_t wv = *(const f32x4_t*)(wout + p0);
        float part[4];
#pragma unroll
        for (int qt = 0; qt < 4; ++qt) {
          part[qt] = 0.f;
#pragma unroll
          for (int r2 = 0; r2 < 4; ++r2) {
            float v = acc1[qt][r2] * scv[r2] + shv[r2];
            v = (v >= 0.f) ? v : 0.01f * v;
            part[qt] += wv[r2] * v;
          }
        }
#pragma unroll
        for (int qt = 0; qt < 4; ++qt) {   // reduce over g (p sub-slots)
          part[qt] += __shfl_xor(part[qt], 16, 64);
          part[qt] += __shfl_xor(part[qt], 32, 64);
        }
        if (lane < 16) {
#pragma unroll
          for (int qt = 0; qt < 4; ++qt)
            sb[wid * 64 + qt * 16 + lr] = part[qt];
        }
        __syncthreads();
        if (tid < 64) {
          float sv = boutp[0];
#pragma unroll
          for (int w = 0; w < 8; ++w) sv += sb[w * 64 + tid];
          const float sg = 1.f / (1.f + expf(-sv));
          sim[(i0 + (tid >> 3)) * N_NODES + j0 + (tid & 7)] = sg;
        }
      }
    }
  }

  // ---- stats flush: shuffle-reduce over the 16 q-lanes; o/p slices are
  //      wave-disjoint, so one LDS write + one atomicAdd per stat. ----
  if constexpr (PHASE == 1) {
#pragma unroll
    for (int ot = 0; ot < 2; ++ot)
#pragma unroll
      for (int r2 = 0; r2 < 4; ++r2) {
        float v1 = s1[ot][r2], v2 = s2v[ot][r2];
#pragma unroll
        for (int m = 1; m < 16; m <<= 1) {
          v1 += __shfl_xor(v1, m, 64);
          v2 += __shfl_xor(v2, m, 64);
        }
        s1[ot][r2] = v1; s2v[ot][r2] = v2;
      }
    __syncthreads();
    if (lr == 0) {
#pragma unroll
      for (int ot = 0; ot < 2; ++ot)
#pragma unroll
        for (int r2 = 0; r2 < 4; ++r2) {
          const int o = wid * 32 + ot * 16 + g * 4 + r2;
          sb[o] = s1[ot][r2];
          sb[256 + o] = s2v[ot][r2];
        }
    }
    __syncthreads();
    atomicAdd(stats + tid, sb[tid]);   // tid < 512: 256 sums + 256 sumsq
  }
  if constexpr (PHASE == 2) {
#pragma unroll
    for (int r2 = 0; r2 < 4; ++r2) {
      float v1 = t1[r2], v2 = t2v[r2];
#pragma unroll
      for (int m = 1; m < 16; m <<= 1) {
        v1 += __shfl_xor(v1, m, 64);
        v2 += __shfl_xor(v2, m, 64);
      }
      t1[r2] = v1; t2v[r2] = v2;
    }
    __syncthreads();
    if (lr == 0) {
#pragma unroll
      for (int r2 = 0; r2 < 4; ++r2) {
        const int p = wid * 16 + g * 4 + r2;
        sb[p] = t1[r2];
        sb[128 + p] = t2v[r2];
      }
    }
    __syncthreads();
    if (tid < 256) atomicAdd(stats + tid, sb[tid]);
  }
}

// ---------------------------------------------------------------------------
// finalize: mean/var -> per-channel scale/shift for BN(+gamma,beta)
// ---------------------------------------------------------------------------
__global__ void finalize_kernel(const float* __restrict__ ssum, const float* __restrict__ ssq,
                                const float* __restrict__ gamma, const float* __restrict__ beta,
                                float* __restrict__ sc, float* __restrict__ sh, int n)
{
  const int i = (int)(blockIdx.x * blockDim.x + threadIdx.x);
  if (i < n) {
    const float invN = 1.f / 589824.f;
    const float m = ssum[i] * invN;
    const float var = ssq[i] * invN - m * m;
    const float is = rsqrtf(var + 1e-5f);
    const float s = gamma[i] * is;
    sc[i] = s;
    sh[i] = beta[i] - m * s;
  }
}

// ---------------------------------------------------------------------------
// edge graph tail: colsum of edge matrix (edge = same_label*sim + I + 1e-6)
// ---------------------------------------------------------------------------
__global__ void colsum_kernel(const float* __restrict__ sim, const int* __restrict__ lab,
                              float* __restrict__ colsum)
{
  const int t = (int)threadIdx.x;
  const int bi = (int)blockIdx.x * 8;
  const int lj0 = lab[t], lj1 = lab[t + 256], lj2 = lab[t + 512];
  float a0 = 0.f, a1 = 0.f, a2 = 0.f;
  for (int r = 0; r < 8; ++r) {
    const int i = bi + r;
    const int li = lab[i];
    const float* srow = sim + i * N_NODES;
    a0 += ((li == lj0) ? srow[t] : 0.f) + ((i == t) ? 1.f : 0.f) + 1e-6f;
    a1 += ((li == lj1) ? srow[t + 256] : 0.f) + ((i == t + 256) ? 1.f : 0.f) + 1e-6f;
    a2 += ((li == lj2) ? srow[t + 512] : 0.f) + ((i == t + 512) ? 1.f : 0.f) + 1e-6f;
  }
  atomicAdd(colsum + t, a0);
  atomicAdd(colsum + t + 256, a1);
  atomicAdd(colsum + t + 512, a2);
}

// aggr[i][:] = (e_row_i / max(sum|e_row_i|,1e-12)) @ feat,  e = colnorm(edge) with zero diag
__global__ void aggr_kernel(const float* __restrict__ sim, const int* __restrict__ lab,
                            const float* __restrict__ colsum, const float* __restrict__ feat,
                            float* __restrict__ aggr)
{
  __shared__ float wrow[N_NODES];
  __shared__ float red[128];
  const int i = (int)blockIdx.x, t = (int)threadIdx.x;
  const int li = lab[i];
  const float* srow = sim + i * N_NODES;
  float rs = 0.f;
  for (int s = 0; s < 6; ++s) {
    const int j = t + s * 128;
    const float e = ((li == lab[j]) ? srow[j] : 0.f) + ((i == j) ? 1.f : 0.f) + 1e-6f;
    const float w = (j == i) ? 0.f : e / colsum[j];
    wrow[j] = w;
    rs += w;
  }
  red[t] = rs;
  __syncthreads();
  for (int off = 64; off > 0; off >>= 1) {
    if (t < off) red[t] += red[t + off];
    __syncthreads();
  }
  const float inv = 1.f / fmaxf(red[0], 1e-12f);
  float acc = 0.f;
  for (int j = 0; j < N_NODES; ++j) acc += wrow[j] * feat[j * 128 + t];
  aggr[i * 128 + t] = acc * inv;
}

// node MLP layer0: h2[r][n] = lrelu(bn(n_w0 @ [feat;aggr]^T)), bn over n
__global__ void mlp0_kernel(const float* __restrict__ feat, const float* __restrict__ aggr,
                            const float* __restrict__ w, const float* __restrict__ gamma,
                            const float* __restrict__ beta, float* __restrict__ h2)
{
  __shared__ float wr[256];
  __shared__ float redA[256], redB[256];
  const int r = (int)blockIdx.x, t = (int)threadIdx.x;
  wr[t] = w[r * 256 + t];
  __syncthreads();
  float v[3];
#pragma unroll
  for (int s = 0; s < 3; ++s) {
    const int n = t + s * 256;
    const float* fr = feat + n * 128;
    const float* ar = aggr + n * 128;
    float acc = 0.f;
#pragma unroll 4
    for (int c = 0; c < 128; c += 4) {
      const f32x4_t fv = *(const f32x4_t*)(fr + c);
      acc += wr[c] * fv[0] + wr[c + 1] * fv[1] + wr[c + 2] * fv[2] + wr[c + 3] * fv[3];
    }
#pragma unroll 4
    for (int c = 0; c < 128; c += 4) {
      const f32x4_t av = *(const f32x4_t*)(ar + c);
      acc += wr[128 + c] * av[0] + wr[129 + c] * av[1] + wr[130 + c] * av[2] + wr[131 + c] * av[3];
    }
    v[s] = acc;
  }
  redA[t] = v[0] + v[1] + v[2];
  redB[t] = v[0] * v[0] + v[1] * v[1] + v[2] * v[2];
  __syncthreads();
  for (int off = 128; off > 0; off >>= 1) {
    if (t < off) { redA[t] += redA[t + off]; redB[t] += redB[t + off]; }
    __syncthreads();
  }
  const float m = redA[0] * (1.f / 768.f);
  const float var = redB[0] * (1.f / 768.f) - m * m;
  const float is = rsqrtf(var + 1e-5f);
  const float sc = gamma[r] * is;
  const float sh = beta[r] - m * sc;
#pragma unroll
  for (int s = 0; s < 3; ++s) {
    float y = v[s] * sc + sh;
    y = (y >= 0.f) ? y : 0.01f * y;
    h2[r * 768 + t + s * 256] = y;
  }
}

// node MLP layer1: logits[n][r] = bn(n_w1 @ h2)[r][n]  (no lrelu)
__global__ void mlp1_kernel(const float* __restrict__ h2, const float* __restrict__ w,
                            const float* __restrict__ gamma, const float* __restrict__ beta,
                            float* __restrict__ logits)
{
  __shared__ float wr[130];
  __shared__ float redA[256], redB[256];
  const int r = (int)blockIdx.x, t = (int)threadIdx.x;
  if (t < 130) wr[t] = w[r * 130 + t];
  __syncthreads();
  float v[3];
#pragma unroll
  for (int s = 0; s < 3; ++s) {
    const int n = t + s * 256;
    float acc = 0.f;
    for (int c = 0; c < 130; ++c) acc += wr[c] * h2[c * 768 + n];
    v[s] = acc;
  }
  redA[t] = v[0] + v[1] + v[2];
  redB[t] = v[0] * v[0] + v[1] * v[1] + v[2] * v[2];
  __syncthreads();
  for (int off = 128; off > 0; off >>= 1) {
    if (t < off) { redA[t] += redA[t + off]; redB[t] += redB[t + off]; }
    __syncthreads();
  }
  const float m = redA[0] * (1.f / 768.f);
  const float var = redB[0] * (1.f / 768.f) - m * m;
  const float is = rsqrtf(var + 1e-5f);
  const float sc = gamma[r] * is;
  const float sh = beta[r] - m * sc;
#pragma unroll
  for (int s = 0; s < 3; ++s) {
    const float y = v[s] * sc + sh;
    logits[(t + s * 256) * 65 + r] = y;
  }
}

// ---------------------------------------------------------------------------
extern "C" void kernel_launch(void* const* d_in, const int* in_sizes, int n_in,
                              void* d_out, int out_size, void* d_ws, size_t ws_size,
                              hipStream_t stream)
{
  (void)in_sizes; (void)n_in; (void)out_size; (void)ws_size;
  const float* feat   = (const float*)d_in[0];
  const int*   lab    = (const int*)d_in[1];
  const float* e_w0   = (const float*)d_in[2];
  const float* e_g0   = (const float*)d_in[3];
  const float* e_b0   = (const float*)d_in[4];
  const float* e_w1   = (const float*)d_in[5];
  const float* e_g1   = (const float*)d_in[6];
  const float* e_b1   = (const float*)d_in[7];
  const float* e_wout = (const float*)d_in[8];
  const float* e_bout = (const float*)d_in[9];
  const float* n_w0   = (const float*)d_in[10];
  const float* n_g0   = (const float*)d_in[11];
  const float* n_b0   = (const float*)d_in[12];
  const float* n_w1   = (const float*)d_in[13];
  const float* n_g1   = (const float*)d_in[14];
  const float* n_b1   = (const float*)d_in[15];

  float* out = (float*)d_out;
  float* logits = out;                 // 768*65
  float* sim = out + 768 * 65;         // 768*768

  // workspace layout (floats)
  float* wsf = (float*)d_ws;
  float* S0A = wsf + 0;      // 256  (sum z0)
  float* S0B = wsf + 256;    // 256  (sumsq z0)
  float* S1A = wsf + 512;    // 128
  float* S1B = wsf + 640;    // 128
  float* colsum = wsf + 768; // 768
  float* sc0 = wsf + 1536;   // 256
  float* sh0 = wsf + 1792;   // 256
  float* sc1 = wsf + 2048;   // 128
  float* sh1 = wsf + 2176;   // 128
  float* aggr = wsf + 2304;            // 768*128
  float* h2 = wsf + 2304 + 768 * 128;  // 130*768
  unsigned short* W0bf = (unsigned short*)(wsf + 200448);   // 32768 bf16 (64KB)
  unsigned short* W1bf = W0bf + 32768;                      // 32768 bf16 (64KB)

  // zero stat + colsum accumulators (replayed every graph launch)
  hipMemsetAsync(d_ws, 0, 2304 * sizeof(float), stream);

  wcast_kernel<<<128, 256, 0, stream>>>(e_w0, e_w1, W0bf, W1bf);

  pair_phase_kernel<1><<<2304, 512, 0, stream>>>(feat, W0bf, nullptr, nullptr, nullptr,
                                                 nullptr, nullptr, nullptr, nullptr, S0A, nullptr);
  finalize_kernel<<<1, 256, 0, stream>>>(S0A, S0B, e_g0, e_b0, sc0, sh0, 256);
  pair_phase_kernel<2><<<2304, 512, 0, stream>>>(feat, W0bf, W1bf, nullptr, nullptr,
                                                 sc0, sh0, nullptr, nullptr, S1A, nullptr);
  finalize_kernel<<<1, 128, 0, stream>>>(S1A, S1B, e_g1, e_b1, sc1, sh1, 128);
  pair_phase_kernel<3><<<4608, 512, 0, stream>>>(feat, W0bf, W1bf, e_wout, e_bout,
                                                 sc0, sh0, sc1, sh1, nullptr, sim);
  colsum_kernel<<<96, 256, 0, stream>>>(sim, lab, colsum);
  aggr_kernel<<<768, 128, 0, stream>>>(sim, lab, colsum, feat, aggr);
  mlp0_kernel<<<130, 256, 0, stream>>>(feat, aggr, n_w0, n_g0, n_b0, h2);
  mlp1_kernel<<<65, 256, 0, stream>>>(h2, n_w1, n_g1, n_b1, logits);
}

// Round 9
// 431.147 us; speedup vs baseline: 1.6278x; 1.1506x over previous
//
#include <hip/hip_runtime.h>
#include <cmath>

// ---------------------------------------------------------------------------
// ClassifierGNN: N=768 nodes, D=128 feat, edge-MLP channels 256->128->1,
// node-MLP 256->130->65.
// 3 recompute phases (stats0, stats1, sim) using bf16 MFMA 16x16x32.
// R8 -> R9: attack the shared front-end (P1 == P2 == 217us despite half work).
//   - featL staging deleted: X-gen reads feat direct from global (L2-resident,
//     coalesced). Kills one barrier + the 4-way-conflict featL LDS reads.
//   - X double-buffered (LDS 67.6KB, still 2 blk/CU = proven 128-reg budget):
//     gen X[t+1] at top of tile t -> global latency + cvt VALU overlap the
//     MFMA/LDS of tile t. P1: 1 barrier/tile; P2: 2.
//   - native (__bf16) casts (v_cvt_pk_bf16_f32) replace 4-op manual RNE.
// ---------------------------------------------------------------------------

#define N_NODES 768
#define NBJ 96          // j-tiles per row of tiles (768/8)
#define NTILES 9216     // (768/8) * (768/8)

// LDS layout (bytes): total 67584 -> 2 blocks/CU (=> 128-reg budget).
#define L_X0   0        // X buf0: 64 q * 128 c * bf16 = 16384
#define L_X1   16384    // X buf1: 16384
#define L_A0   32768    // 64 q * 256 c * bf16 = 32768
#define L_SB   65536    // 512 f32 = 2048 (stat/sim staging)
#define L_TOT  67584

static_assert(L_TOT > 53760 && L_TOT <= 81920, "want exactly 2 blocks/CU");

typedef __bf16 bf16x8_t __attribute__((ext_vector_type(8)));
typedef __bf16 bf16x4_t __attribute__((ext_vector_type(4)));
typedef float f32x4_t __attribute__((ext_vector_type(4)));

#define SBAR __builtin_amdgcn_sched_barrier(0)

// ---------------------------------------------------------------------------
// Weight pre-cast: f32 -> bf16, same row-major layout (fragment-ready).
// ---------------------------------------------------------------------------
__global__ void wcast_kernel(const float* __restrict__ w0, const float* __restrict__ w1,
                             __bf16* __restrict__ w0b, __bf16* __restrict__ w1b)
{
  const int i = (int)(blockIdx.x * 256 + threadIdx.x);
  if (i < 32768) { w0b[i] = (__bf16)w0[i]; w1b[i] = (__bf16)w1[i]; }
}

// ---------------------------------------------------------------------------
// X-gen: X[q][c] = |feat[i0+q/8][c] - feat[j0+q%8][c]| as bf16 into swizzled
// LDS rows. Reads feat DIRECT from global (L2-resident, coalesced: 16
// consecutive lanes cover one 512B row-half).
// ---------------------------------------------------------------------------
__device__ __forceinline__ void gen_x(const float* __restrict__ feat,
                                      int i0, int j0, int tid,
                                      unsigned char* __restrict__ Xdst)
{
#pragma unroll
  for (int it = 0; it < 2; ++it) {
    const int id = tid + it * 512;
    const int q = id >> 4;
    const int c0 = (id & 15) * 8;
    const float* gi = feat + (i0 + (q >> 3)) * 128 + c0;
    const float* gj = feat + (j0 + (q & 7)) * 128 + c0;
    const f32x4_t ia = *(const f32x4_t*)gi;
    const f32x4_t ib = *(const f32x4_t*)(gi + 4);
    const f32x4_t ja = *(const f32x4_t*)gj;
    const f32x4_t jb = *(const f32x4_t*)(gj + 4);
    bf16x8_t xv;
#pragma unroll
    for (int s = 0; s < 4; ++s) {
      xv[s] = (__bf16)fabsf(ia[s] - ja[s]);
      xv[4 + s] = (__bf16)fabsf(ib[s] - jb[s]);
    }
    const int off = ((q << 8) + (c0 << 1)) ^ ((q & 7) << 4);
    *(bf16x8_t*)(Xdst + off) = xv;
  }
}

// ---------------------------------------------------------------------------
// Fused pair-MLP kernel.
// Tile = 8 i-rows x 8 j-cols = 64 pairs (q = i_loc*8 + j_loc). 512 thr = 8 waves.
// Wave w owns o in [32w,32w+32) for layer0 and p in [16w,16w+16) for layer1;
// every wave processes all 64 q. Weights are persistent VGPR fragments.
// PHASE 1: z0 -> per-channel sum/sumsq (atomics)
// PHASE 2: z0 -> a0 -> z1 -> sum/sumsq
// PHASE 3: z0 -> a0 -> z1 -> a1 -> sim = sigmoid(wout.a1 + bout)
// ---------------------------------------------------------------------------
template<int PHASE>
__global__ void
__attribute__((amdgpu_flat_work_group_size(512, 512)))
pair_phase_kernel(const float* __restrict__ feat,
                  const __bf16* __restrict__ W0b,
                  const __bf16* __restrict__ W1b,
                  const float* __restrict__ wout,
                  const float* __restrict__ boutp,
                  const float* __restrict__ sc0, const float* __restrict__ sh0,
                  const float* __restrict__ sc1, const float* __restrict__ sh1,
                  float* __restrict__ stats,
                  float* __restrict__ sim)
{
  __shared__ __align__(16) unsigned char smem[L_TOT];
  unsigned char* Ab = smem + L_A0;
  float* sb = (float*)(smem + L_SB);

  const int tid = (int)threadIdx.x;
  const int wid = tid >> 6;
  const int lane = tid & 63;
  const int lr = lane & 15;
  const int g = lane >> 4;

  // ---- persistent weight fragments (loaded once per block) ----
  // k-slot convention (k = ks*32 + g*8) matches the B-frag LDS layout, so any
  // HW k-permutation cancels between A and B.
  bf16x8_t W0f[2][4];
#pragma unroll
  for (int ot = 0; ot < 2; ++ot)
#pragma unroll
    for (int ks = 0; ks < 4; ++ks)
      W0f[ot][ks] = *(const bf16x8_t*)(W0b + (wid * 32 + ot * 16 + lr) * 128 + ks * 32 + g * 8);

  bf16x8_t W1f[8];
  if constexpr (PHASE >= 2) {
#pragma unroll
    for (int ks = 0; ks < 8; ++ks)
      W1f[ks] = *(const bf16x8_t*)(W1b + (wid * 16 + lr) * 256 + ks * 32 + g * 8);
  }

  float s1[2][4], s2v[2][4];   // phase1 stats (z0), o = wid*32+ot*16+g*4+r2
  float t1[4], t2v[4];         // phase2 stats (z1), p = wid*16+g*4+r2
  if constexpr (PHASE == 1) {
#pragma unroll
    for (int ot = 0; ot < 2; ++ot)
#pragma unroll
      for (int r2 = 0; r2 < 4; ++r2) { s1[ot][r2] = 0.f; s2v[ot][r2] = 0.f; }
  }
  if constexpr (PHASE == 2) {
#pragma unroll
    for (int r2 = 0; r2 < 4; ++r2) { t1[r2] = 0.f; t2v[r2] = 0.f; }
  }

  // prologue: generate X for this block's first tile into buf0
  {
    const int t0 = (int)blockIdx.x;
    const int ti = t0 / NBJ;
    gen_x(feat, ti * 8, (t0 - ti * NBJ) * 8, tid, smem + L_X0);
  }
  int bufc = 0;

  for (int tile = (int)blockIdx.x; tile < NTILES; tile += (int)gridDim.x) {
    const int ti = tile / NBJ;
    const int i0 = ti * 8;
    const int j0 = (tile - ti * NBJ) * 8;

    // B1: X[tile] visible; prev tile's layer-1 Ab reads + X[alt] reads done.
    __syncthreads();

    // generate X for tile+1 into the alternate buffer (overlaps this tile's
    // compute; safe: all reads of that buffer finished before B1).
    const int nxt = tile + (int)gridDim.x;
    if (nxt < NTILES) {
      const int nti = nxt / NBJ;
      gen_x(feat, nti * 8, (nxt - nti * NBJ) * 8, tid, smem + (bufc ? L_X0 : L_X1));
    }
    unsigned char* Xc = smem + (bufc ? L_X1 : L_X0);
    bufc ^= 1;

    // ---- layer 0: z0[o][q] = W0 . X ----
    f32x4_t acc0[2][4];
#pragma unroll
    for (int ot = 0; ot < 2; ++ot)
#pragma unroll
      for (int qt = 0; qt < 4; ++qt)
        acc0[ot][qt] = f32x4_t{0.f, 0.f, 0.f, 0.f};
#pragma unroll
    for (int ks = 0; ks < 4; ++ks) {
      bf16x8_t Ba[2], Bb[2];
#pragma unroll
      for (int h = 0; h < 2; ++h) {
        const int q = h * 16 + lr;
        const int off = ((q << 8) + (ks << 6) + (g << 4)) ^ ((q & 7) << 4);
        Ba[h] = *(const bf16x8_t*)(Xc + off);
      }
      SBAR;
#pragma unroll
      for (int ot = 0; ot < 2; ++ot)
#pragma unroll
        for (int h = 0; h < 2; ++h)
          acc0[ot][h] = __builtin_amdgcn_mfma_f32_16x16x32_bf16(W0f[ot][ks], Ba[h], acc0[ot][h], 0, 0, 0);
#pragma unroll
      for (int h = 0; h < 2; ++h) {
        const int q = 32 + h * 16 + lr;
        const int off = ((q << 8) + (ks << 6) + (g << 4)) ^ ((q & 7) << 4);
        Bb[h] = *(const bf16x8_t*)(Xc + off);
      }
      SBAR;
#pragma unroll
      for (int ot = 0; ot < 2; ++ot)
#pragma unroll
        for (int h = 0; h < 2; ++h)
          acc0[ot][2 + h] = __builtin_amdgcn_mfma_f32_16x16x32_bf16(W0f[ot][ks], Bb[h], acc0[ot][2 + h], 0, 0, 0);
      SBAR;
    }

    if constexpr (PHASE == 1) {
#pragma unroll
      for (int ot = 0; ot < 2; ++ot)
#pragma unroll
        for (int qt = 0; qt < 4; ++qt)
#pragma unroll
          for (int r2 = 0; r2 < 4; ++r2) {
            const float z = acc0[ot][qt][r2];
            s1[ot][r2] += z;
            s2v[ot][r2] += z * z;
          }
    } else {
      // a0 = lrelu(scale0*z0 + shift0), write bf16 into swizzled LDS [q][o]
#pragma unroll
      for (int ot = 0; ot < 2; ++ot) {
        const int o0 = wid * 32 + ot * 16 + g * 4;
        const f32x4_t scv = *(const f32x4_t*)(sc0 + o0);
        const f32x4_t shv = *(const f32x4_t*)(sh0 + o0);
#pragma unroll
        for (int qt = 0; qt < 4; ++qt) {
          const int q = qt * 16 + lr;
          bf16x4_t pk;
#pragma unroll
          for (int r2 = 0; r2 < 4; ++r2) {
            float v = acc0[ot][qt][r2] * scv[r2] + shv[r2];
            v = (v >= 0.f) ? v : 0.01f * v;
            pk[r2] = (__bf16)v;
          }
          const int off = ((q << 9) + (o0 << 1)) ^ ((q & 7) << 4);
          *(bf16x4_t*)(Ab + off) = pk;
        }
      }
      __syncthreads();   // B2: a0 visible before layer-1 reads

      // ---- layer 1: z1[p][q] = W1 . a0 ----
      f32x4_t acc1[4];
#pragma unroll
      for (int qt = 0; qt < 4; ++qt)
        acc1[qt] = f32x4_t{0.f, 0.f, 0.f, 0.f};
#pragma unroll
      for (int ks = 0; ks < 8; ++ks) {
        bf16x8_t Ba[2], Bb[2];
#pragma unroll
        for (int h = 0; h < 2; ++h) {
          const int q = h * 16 + lr;
          const int off = ((q << 9) + (ks << 6) + (g << 4)) ^ ((q & 7) << 4);
          Ba[h] = *(const bf16x8_t*)(Ab + off);
        }
        SBAR;
#pragma unroll
        for (int h = 0; h < 2; ++h)
          acc1[h] = __builtin_amdgcn_mfma_f32_16x16x32_bf16(W1f[ks], Ba[h], acc1[h], 0, 0, 0);
#pragma unroll
        for (int h = 0; h < 2; ++h) {
          const int q = 32 + h * 16 + lr;
          const int off = ((q << 9) + (ks << 6) + (g << 4)) ^ ((q & 7) << 4);
          Bb[h] = *(const bf16x8_t*)(Ab + off);
        }
        SBAR;
#pragma unroll
        for (int h = 0; h < 2; ++h)
          acc1[2 + h] = __builtin_amdgcn_mfma_f32_16x16x32_bf16(W1f[ks], Bb[h], acc1[2 + h], 0, 0, 0);
        SBAR;
      }

      if constexpr (PHASE == 2) {
#pragma unroll
        for (int qt = 0; qt < 4; ++qt)
#pragma unroll
          for (int r2 = 0; r2 < 4; ++r2) {
            const float z = acc1[qt][r2];
            t1[r2] += z;
            t2v[r2] += z * z;
          }
      } else {
        // PHASE 3: a1 = lrelu(scale1*z1+shift1); sim = sigmoid(wout.a1+bout)
        const int p0 = wid * 16 + g * 4;
        const f32x4_t scv = *(const f32x4_t*)(sc1 + p0);
        const f32x4_t shv = *(const f32x4_t*)(sh1 + p0);
        const f32x4_t wv = *(const f32x4_t*)(wout + p0);
        float part[4];
#pragma unroll
        for (int qt = 0; qt < 4; ++qt) {
          part[qt] = 0.f;
#pragma unroll
          for (int r2 = 0; r2 < 4; ++r2) {
            float v = acc1[qt][r2] * scv[r2] + shv[r2];
            v = (v >= 0.f) ? v : 0.01f * v;
            part[qt] += wv[r2] * v;
          }
        }
#pragma unroll
        for (int qt = 0; qt < 4; ++qt) {   // reduce over g (p sub-slots)
          part[qt] += __shfl_xor(part[qt], 16, 64);
          part[qt] += __shfl_xor(part[qt], 32, 64);
        }
        if (lane < 16) {
#pragma unroll
          for (int qt = 0; qt < 4; ++qt)
            sb[wid * 64 + qt * 16 + lr] = part[qt];
        }
        __syncthreads();   // B3: sb visible
        if (tid < 64) {
          float sv = boutp[0];
#pragma unroll
          for (int w = 0; w < 8; ++w) sv += sb[w * 64 + tid];
          const float sg = 1.f / (1.f + expf(-sv));
          sim[(i0 + (tid >> 3)) * N_NODES + j0 + (tid & 7)] = sg;
        }
      }
    }
  }

  // ---- stats flush: shuffle-reduce over the 16 q-lanes; o/p slices are
  //      wave-disjoint, so one LDS write + one atomicAdd per stat. ----
  if constexpr (PHASE == 1) {
#pragma unroll
    for (int ot = 0; ot < 2; ++ot)
#pragma unroll
      for (int r2 = 0; r2 < 4; ++r2) {
        float v1 = s1[ot][r2], v2 = s2v[ot][r2];
#pragma unroll
        for (int m = 1; m < 16; m <<= 1) {
          v1 += __shfl_xor(v1, m, 64);
          v2 += __shfl_xor(v2, m, 64);
        }
        s1[ot][r2] = v1; s2v[ot][r2] = v2;
      }
    __syncthreads();
    if (lr == 0) {
#pragma unroll
      for (int ot = 0; ot < 2; ++ot)
#pragma unroll
        for (int r2 = 0; r2 < 4; ++r2) {
          const int o = wid * 32 + ot * 16 + g * 4 + r2;
          sb[o] = s1[ot][r2];
          sb[256 + o] = s2v[ot][r2];
        }
    }
    __syncthreads();
    atomicAdd(stats + tid, sb[tid]);   // tid < 512: 256 sums + 256 sumsq
  }
  if constexpr (PHASE == 2) {
#pragma unroll
    for (int r2 = 0; r2 < 4; ++r2) {
      float v1 = t1[r2], v2 = t2v[r2];
#pragma unroll
      for (int m = 1; m < 16; m <<= 1) {
        v1 += __shfl_xor(v1, m, 64);
        v2 += __shfl_xor(v2, m, 64);
      }
      t1[r2] = v1; t2v[r2] = v2;
    }
    __syncthreads();
    if (lr == 0) {
#pragma unroll
      for (int r2 = 0; r2 < 4; ++r2) {
        const int p = wid * 16 + g * 4 + r2;
        sb[p] = t1[r2];
        sb[128 + p] = t2v[r2];
      }
    }
    __syncthreads();
    if (tid < 256) atomicAdd(stats + tid, sb[tid]);
  }
}

// ---------------------------------------------------------------------------
// finalize: mean/var -> per-channel scale/shift for BN(+gamma,beta)
// ---------------------------------------------------------------------------
__global__ void finalize_kernel(const float* __restrict__ ssum, const float* __restrict__ ssq,
                                const float* __restrict__ gamma, const float* __restrict__ beta,
                                float* __restrict__ sc, float* __restrict__ sh, int n)
{
  const int i = (int)(blockIdx.x * blockDim.x + threadIdx.x);
  if (i < n) {
    const float invN = 1.f / 589824.f;
    const float m = ssum[i] * invN;
    const float var = ssq[i] * invN - m * m;
    const float is = rsqrtf(var + 1e-5f);
    const float s = gamma[i] * is;
    sc[i] = s;
    sh[i] = beta[i] - m * s;
  }
}

// ---------------------------------------------------------------------------
// edge graph tail: colsum of edge matrix (edge = same_label*sim + I + 1e-6)
// ---------------------------------------------------------------------------
__global__ void colsum_kernel(const float* __restrict__ sim, const int* __restrict__ lab,
                              float* __restrict__ colsum)
{
  const int t = (int)threadIdx.x;
  const int bi = (int)blockIdx.x * 8;
  const int lj0 = lab[t], lj1 = lab[t + 256], lj2 = lab[t + 512];
  float a0 = 0.f, a1 = 0.f, a2 = 0.f;
  for (int r = 0; r < 8; ++r) {
    const int i = bi + r;
    const int li = lab[i];
    const float* srow = sim + i * N_NODES;
    a0 += ((li == lj0) ? srow[t] : 0.f) + ((i == t) ? 1.f : 0.f) + 1e-6f;
    a1 += ((li == lj1) ? srow[t + 256] : 0.f) + ((i == t + 256) ? 1.f : 0.f) + 1e-6f;
    a2 += ((li == lj2) ? srow[t + 512] : 0.f) + ((i == t + 512) ? 1.f : 0.f) + 1e-6f;
  }
  atomicAdd(colsum + t, a0);
  atomicAdd(colsum + t + 256, a1);
  atomicAdd(colsum + t + 512, a2);
}

// aggr[i][:] = (e_row_i / max(sum|e_row_i|,1e-12)) @ feat,  e = colnorm(edge) with zero diag
__global__ void aggr_kernel(const float* __restrict__ sim, const int* __restrict__ lab,
                            const float* __restrict__ colsum, const float* __restrict__ feat,
                            float* __restrict__ aggr)
{
  __shared__ float wrow[N_NODES];
  __shared__ float red[128];
  const int i = (int)blockIdx.x, t = (int)threadIdx.x;
  const int li = lab[i];
  const float* srow = sim + i * N_NODES;
  float rs = 0.f;
  for (int s = 0; s < 6; ++s) {
    const int j = t + s * 128;
    const float e = ((li == lab[j]) ? srow[j] : 0.f) + ((i == j) ? 1.f : 0.f) + 1e-6f;
    const float w = (j == i) ? 0.f : e / colsum[j];
    wrow[j] = w;
    rs += w;
  }
  red[t] = rs;
  __syncthreads();
  for (int off = 64; off > 0; off >>= 1) {
    if (t < off) red[t] += red[t + off];
    __syncthreads();
  }
  const float inv = 1.f / fmaxf(red[0], 1e-12f);
  float acc = 0.f;
  for (int j = 0; j < N_NODES; ++j) acc += wrow[j] * feat[j * 128 + t];
  aggr[i * 128 + t] = acc * inv;
}

// node MLP layer0: h2[r][n] = lrelu(bn(n_w0 @ [feat;aggr]^T)), bn over n
__global__ void mlp0_kernel(const float* __restrict__ feat, const float* __restrict__ aggr,
                            const float* __restrict__ w, const float* __restrict__ gamma,
                            const float* __restrict__ beta, float* __restrict__ h2)
{
  __shared__ float wr[256];
  __shared__ float redA[256], redB[256];
  const int r = (int)blockIdx.x, t = (int)threadIdx.x;
  wr[t] = w[r * 256 + t];
  __syncthreads();
  float v[3];
#pragma unroll
  for (int s = 0; s < 3; ++s) {
    const int n = t + s * 256;
    const float* fr = feat + n * 128;
    const float* ar = aggr + n * 128;
    float acc = 0.f;
#pragma unroll 4
    for (int c = 0; c < 128; c += 4) {
      const f32x4_t fv = *(const f32x4_t*)(fr + c);
      acc += wr[c] * fv[0] + wr[c + 1] * fv[1] + wr[c + 2] * fv[2] + wr[c + 3] * fv[3];
    }
#pragma unroll 4
    for (int c = 0; c < 128; c += 4) {
      const f32x4_t av = *(const f32x4_t*)(ar + c);
      acc += wr[128 + c] * av[0] + wr[129 + c] * av[1] + wr[130 + c] * av[2] + wr[131 + c] * av[3];
    }
    v[s] = acc;
  }
  redA[t] = v[0] + v[1] + v[2];
  redB[t] = v[0] * v[0] + v[1] * v[1] + v[2] * v[2];
  __syncthreads();
  for (int off = 128; off > 0; off >>= 1) {
    if (t < off) { redA[t] += redA[t + off]; redB[t] += redB[t + off]; }
    __syncthreads();
  }
  const float m = redA[0] * (1.f / 768.f);
  const float var = redB[0] * (1.f / 768.f) - m * m;
  const float is = rsqrtf(var + 1e-5f);
  const float sc = gamma[r] * is;
  const float sh = beta[r] - m * sc;
#pragma unroll
  for (int s = 0; s < 3; ++s) {
    float y = v[s] * sc + sh;
    y = (y >= 0.f) ? y : 0.01f * y;
    h2[r * 768 + t + s * 256] = y;
  }
}

// node MLP layer1: logits[n][r] = bn(n_w1 @ h2)[r][n]  (no lrelu)
__global__ void mlp1_kernel(const float* __restrict__ h2, const float* __restrict__ w,
                            const float* __restrict__ gamma, const float* __restrict__ beta,
                            float* __restrict__ logits)
{
  __shared__ float wr[130];
  __shared__ float redA[256], redB[256];
  const int r = (int)blockIdx.x, t = (int)threadIdx.x;
  if (t < 130) wr[t] = w[r * 130 + t];
  __syncthreads();
  float v[3];
#pragma unroll
  for (int s = 0; s < 3; ++s) {
    const int n = t + s * 256;
    float acc = 0.f;
    for (int c = 0; c < 130; ++c) acc += wr[c] * h2[c * 768 + n];
    v[s] = acc;
  }
  redA[t] = v[0] + v[1] + v[2];
  redB[t] = v[0] * v[0] + v[1] * v[1] + v[2] * v[2];
  __syncthreads();
  for (int off = 128; off > 0; off >>= 1) {
    if (t < off) { redA[t] += redA[t + off]; redB[t] += redB[t + off]; }
    __syncthreads();
  }
  const float m = redA[0] * (1.f / 768.f);
  const float var = redB[0] * (1.f / 768.f) - m * m;
  const float is = rsqrtf(var + 1e-5f);
  const float sc = gamma[r] * is;
  const float sh = beta[r] - m * sc;
#pragma unroll
  for (int s = 0; s < 3; ++s) {
    const float y = v[s] * sc + sh;
    logits[(t + s * 256) * 65 + r] = y;
  }
}

// ---------------------------------------------------------------------------
extern "C" void kernel_launch(void* const* d_in, const int* in_sizes, int n_in,
                              void* d_out, int out_size, void* d_ws, size_t ws_size,
                              hipStream_t stream)
{
  (void)in_sizes; (void)n_in; (void)out_size; (void)ws_size;
  const float* feat   = (const float*)d_in[0];
  const int*   lab    = (const int*)d_in[1];
  const float* e_w0   = (const float*)d_in[2];
  const float* e_g0   = (const float*)d_in[3];
  const float* e_b0   = (const float*)d_in[4];
  const float* e_w1   = (const float*)d_in[5];
  const float* e_g1   = (const float*)d_in[6];
  const float* e_b1   = (const float*)d_in[7];
  const float* e_wout = (const float*)d_in[8];
  const float* e_bout = (const float*)d_in[9];
  const float* n_w0   = (const float*)d_in[10];
  const float* n_g0   = (const float*)d_in[11];
  const float* n_b0   = (const float*)d_in[12];
  const float* n_w1   = (const float*)d_in[13];
  const float* n_g1   = (const float*)d_in[14];
  const float* n_b1   = (const float*)d_in[15];

  float* out = (float*)d_out;
  float* logits = out;                 // 768*65
  float* sim = out + 768 * 65;         // 768*768

  // workspace layout (floats)
  float* wsf = (float*)d_ws;
  float* S0A = wsf + 0;      // 256  (sum z0)
  float* S0B = wsf + 256;    // 256  (sumsq z0)
  float* S1A = wsf + 512;    // 128
  float* S1B = wsf + 640;    // 128
  float* colsum = wsf + 768; // 768
  float* sc0 = wsf + 1536;   // 256
  float* sh0 = wsf + 1792;   // 256
  float* sc1 = wsf + 2048;   // 128
  float* sh1 = wsf + 2176;   // 128
  float* aggr = wsf + 2304;            // 768*128
  float* h2 = wsf + 2304 + 768 * 128;  // 130*768
  __bf16* W0bf = (__bf16*)(wsf + 200448);   // 32768 bf16 (64KB)
  __bf16* W1bf = W0bf + 32768;              // 32768 bf16 (64KB)

  // zero stat + colsum accumulators (replayed every graph launch)
  hipMemsetAsync(d_ws, 0, 2304 * sizeof(float), stream);

  wcast_kernel<<<128, 256, 0, stream>>>(e_w0, e_w1, W0bf, W1bf);

  pair_phase_kernel<1><<<2304, 512, 0, stream>>>(feat, W0bf, nullptr, nullptr, nullptr,
                                                 nullptr, nullptr, nullptr, nullptr, S0A, nullptr);
  finalize_kernel<<<1, 256, 0, stream>>>(S0A, S0B, e_g0, e_b0, sc0, sh0, 256);
  pair_phase_kernel<2><<<2304, 512, 0, stream>>>(feat, W0bf, W1bf, nullptr, nullptr,
                                                 sc0, sh0, nullptr, nullptr, S1A, nullptr);
  finalize_kernel<<<1, 128, 0, stream>>>(S1A, S1B, e_g1, e_b1, sc1, sh1, 128);
  pair_phase_kernel<3><<<2304, 512, 0, stream>>>(feat, W0bf, W1bf, e_wout, e_bout,
                                                 sc0, sh0, sc1, sh1, nullptr, sim);
  colsum_kernel<<<96, 256, 0, stream>>>(sim, lab, colsum);
  aggr_kernel<<<768, 128, 0, stream>>>(sim, lab, colsum, feat, aggr);
  mlp0_kernel<<<130, 256, 0, stream>>>(feat, aggr, n_w0, n_g0, n_b0, h2);
  mlp1_kernel<<<65, 256, 0, stream>>>(h2, n_w1, n_g1, n_b1, logits);
}

// Round 10
// 424.693 us; speedup vs baseline: 1.6525x; 1.0152x over previous
//
#include <hip/hip_runtime.h>
#include <cmath>

// ---------------------------------------------------------------------------
// ClassifierGNN: N=768 nodes, D=128 feat, edge-MLP channels 256->128->1,
// node-MLP 256->130->65.
// 3 recompute phases (stats0, stats1, sim) using bf16 MFMA 16x16x32.
// R9 -> R10: latency surgery on the per-tile pipeline.
//   - T14 async-split gen_x: bf16 feat (prep kernel), issue 3 global loads
//     after B1, layer-0 runs, THEN cvt+LDS-write (vmcnt hidden under MFMA).
//   - BN scales folded into weights (wscale kernels after finalize):
//     epilogue = lrelu(z + sh); sc loads gone; sh0 persistent in 8 regs.
//   - P3 barriers 3->2: sim write for tile t deferred past tile t+1's B1.
//   - per-lane LDS bases precomputed; per-access addr = add + xor.
// ---------------------------------------------------------------------------

#define N_NODES 768
#define NBJ 96          // j-tiles per row of tiles (768/8)
#define NTILES 9216     // (768/8) * (768/8)

// LDS layout (bytes): total 67584 -> 2 blocks/CU (=> 128-reg budget).
#define L_X0   0        // X buf0: 64 q * 128 c * bf16 = 16384
#define L_X1   16384    // X buf1: 16384
#define L_A0   32768    // 64 q * 256 c * bf16 = 32768
#define L_SB   65536    // 512 f32 = 2048 (stat/sim staging)
#define L_TOT  67584

static_assert(L_TOT > 53760 && L_TOT <= 81920, "want exactly 2 blocks/CU");

typedef __bf16 bf16x8_t __attribute__((ext_vector_type(8)));
typedef __bf16 bf16x4_t __attribute__((ext_vector_type(4)));
typedef unsigned short u16x8_t __attribute__((ext_vector_type(8)));
typedef float f32x4_t __attribute__((ext_vector_type(4)));

#define SBAR __builtin_amdgcn_sched_barrier(0)

// ---------------------------------------------------------------------------
// prep: cast feat (98304) and W0/W1 (32768 each) to bf16.
// ---------------------------------------------------------------------------
__global__ void prep_kernel(const float* __restrict__ feat,
                            const float* __restrict__ w0, const float* __restrict__ w1,
                            __bf16* __restrict__ featb,
                            __bf16* __restrict__ w0b, __bf16* __restrict__ w1b)
{
  const int i = (int)(blockIdx.x * 256 + threadIdx.x);
  if (i < 98304) featb[i] = (__bf16)feat[i];
  if (i < 32768) { w0b[i] = (__bf16)w0[i]; w1b[i] = (__bf16)w1[i]; }
}

// wscale: dst[i] = bf16(w[i] * sc[i/cols])  (fold BN scale into weight rows)
__global__ void wscale_kernel(const float* __restrict__ w, const float* __restrict__ sc,
                              __bf16* __restrict__ dst, int cols, int n)
{
  const int i = (int)(blockIdx.x * 256 + threadIdx.x);
  if (i < n) dst[i] = (__bf16)(w[i] * sc[i / cols]);
}

// ---------------------------------------------------------------------------
// gen_x split: LOAD (3 bf16x8 global loads, 12 regs in flight) / STORE
// (cvt + 2 swizzled LDS writes). jv is shared by both items (same j-row).
// ---------------------------------------------------------------------------
struct XLoad { bf16x8_t iv0, iv1, jv; };

__device__ __forceinline__ XLoad gen_x_load(const __bf16* __restrict__ featb,
                                            int i0, int j0, int q0, int c8)
{
  XLoad r;
  const __bf16* gi = featb + (i0 + (q0 >> 3)) * 128 + c8;
  r.iv0 = *(const bf16x8_t*)gi;
  r.iv1 = *(const bf16x8_t*)(gi + 512);     // item1: i-row + 4
  r.jv  = *(const bf16x8_t*)(featb + (j0 + (q0 & 7)) * 128 + c8);
  return r;
}

__device__ __forceinline__ bf16x8_t absdiff8(bf16x8_t a, bf16x8_t b)
{
  const u16x8_t ua = __builtin_bit_cast(u16x8_t, a);
  const u16x8_t ub = __builtin_bit_cast(u16x8_t, b);
  bf16x8_t r;
#pragma unroll
  for (int s = 0; s < 8; ++s) {
    const float fa = __uint_as_float(((unsigned int)ua[s]) << 16);
    const float fb = __uint_as_float(((unsigned int)ub[s]) << 16);
    r[s] = (__bf16)fabsf(fa - fb);
  }
  return r;
}

__device__ __forceinline__ void gen_x_store(const XLoad& x, unsigned char* __restrict__ Xdst,
                                            int xw)
{
  *(bf16x8_t*)(Xdst + xw) = absdiff8(x.iv0, x.jv);
  *(bf16x8_t*)(Xdst + xw + 8192) = absdiff8(x.iv1, x.jv);
}

// ---------------------------------------------------------------------------
// Fused pair-MLP kernel.
// Tile = 8 i-rows x 8 j-cols = 64 pairs (q = i_loc*8 + j_loc). 512 thr = 8 waves.
// Wave w owns o in [32w,32w+32) for layer0 and p in [16w,16w+16) for layer1;
// every wave processes all 64 q. Weights persistent VGPR fragments; BN scale
// pre-folded into W0b/W1b (except PHASE 1 / the raw-W1 pass of PHASE 2).
// PHASE 1: z0 -> per-channel sum/sumsq (atomics)
// PHASE 2: z0' -> a0 -> z1 -> sum/sumsq
// PHASE 3: z0' -> a0 -> z1' -> a1 -> sim = sigmoid(wout.a1 + bout)
// ---------------------------------------------------------------------------
template<int PHASE>
__global__ void
__attribute__((amdgpu_flat_work_group_size(512, 512)))
pair_phase_kernel(const __bf16* __restrict__ featb,
                  const __bf16* __restrict__ W0b,
                  const __bf16* __restrict__ W1b,
                  const float* __restrict__ wout,
                  const float* __restrict__ boutp,
                  const float* __restrict__ sh0,
                  const float* __restrict__ sh1,
                  float* __restrict__ stats,
                  float* __restrict__ sim)
{
  __shared__ __align__(16) unsigned char smem[L_TOT];
  unsigned char* Ab = smem + L_A0;
  float* sb = (float*)(smem + L_SB);

  const int tid = (int)threadIdx.x;
  const int wid = tid >> 6;
  const int lane = tid & 63;
  const int lr = lane & 15;
  const int g = lane >> 4;

  // ---- persistent weight fragments (loaded once per block) ----
  bf16x8_t W0f[2][4];
#pragma unroll
  for (int ot = 0; ot < 2; ++ot)
#pragma unroll
    for (int ks = 0; ks < 4; ++ks)
      W0f[ot][ks] = *(const bf16x8_t*)(W0b + (wid * 32 + ot * 16 + lr) * 128 + ks * 32 + g * 8);

  bf16x8_t W1f[8];
  if constexpr (PHASE >= 2) {
#pragma unroll
    for (int ks = 0; ks < 8; ++ks)
      W1f[ks] = *(const bf16x8_t*)(W1b + (wid * 16 + lr) * 256 + ks * 32 + g * 8);
  }

  // persistent layer-0 BN shift (scale folded into W0b)
  f32x4_t sh0v[2];
  if constexpr (PHASE >= 2) {
#pragma unroll
    for (int ot = 0; ot < 2; ++ot)
      sh0v[ot] = *(const f32x4_t*)(sh0 + wid * 32 + ot * 16 + g * 4);
  }
  float bout = 0.f;
  if constexpr (PHASE == 3) bout = boutp[0];

  // per-lane LDS address bases (offsets added per access, then XOR swizzle)
  const int swz = (lr & 7) << 4;
  const int xr = (lr << 8) + (g << 4);           // layer-0 B-read
  const int ar = (lr << 9) + (g << 4);           // layer-1 B-read
  const int aw = (lr << 9) + wid * 64 + g * 8;   // a0 write
  const int q0 = tid >> 4;
  const int c8 = (tid & 15) * 8;
  const int xw = (((q0 << 8) + ((tid & 15) << 4)) ^ ((q0 & 7) << 4));  // X write

  float s1[2][4], s2v[2][4];   // phase1 stats (z0)
  float t1[4], t2v[4];         // phase2 stats (z1)
  if constexpr (PHASE == 1) {
#pragma unroll
    for (int ot = 0; ot < 2; ++ot)
#pragma unroll
      for (int r2 = 0; r2 < 4; ++r2) { s1[ot][r2] = 0.f; s2v[ot][r2] = 0.f; }
  }
  if constexpr (PHASE == 2) {
#pragma unroll
    for (int r2 = 0; r2 < 4; ++r2) { t1[r2] = 0.f; t2v[r2] = 0.f; }
  }

  // prologue: X for first tile -> buf0 (load+store back-to-back, one-time stall)
  {
    const int t0 = (int)blockIdx.x;
    const int ti = t0 / NBJ;
    XLoad xl = gen_x_load(featb, ti * 8, (t0 - ti * NBJ) * 8, q0, c8);
    gen_x_store(xl, smem + L_X0, xw);
  }
  int bufc = 0;
  int pi0 = -1, pj0 = -1;   // P3 deferred sim-write coords

  for (int tile = (int)blockIdx.x; tile < NTILES; tile += (int)gridDim.x) {
    const int ti = tile / NBJ;
    const int i0 = ti * 8;
    const int j0 = (tile - ti * NBJ) * 8;

    __syncthreads();   // B1: X[cur] visible; prev-tile LDS reads done

    // deferred sim write for previous tile (reads sb written before B1;
    // next sb write is after this tile's B2 -> ordered)
    if constexpr (PHASE == 3) {
      if (pi0 >= 0 && tid < 64) {
        float sv = bout;
#pragma unroll
        for (int w = 0; w < 8; ++w) sv += sb[w * 64 + tid];
        sim[(pi0 + (tid >> 3)) * N_NODES + pj0 + (tid & 7)] = 1.f / (1.f + expf(-sv));
      }
    }

    // issue next-tile gen_x loads (completion consumed AFTER layer-0)
    const int nxt = tile + (int)gridDim.x;
    const bool hn = (nxt < NTILES);
    XLoad xl;
    if (hn) {
      const int nti = nxt / NBJ;
      xl = gen_x_load(featb, nti * 8, (nxt - nti * NBJ) * 8, q0, c8);
    }
    unsigned char* Xc = smem + (bufc ? L_X1 : L_X0);
    unsigned char* Xa = smem + (bufc ? L_X0 : L_X1);
    bufc ^= 1;

    // ---- layer 0: z0[o][q] = W0 . X ----
    f32x4_t acc0[2][4];
#pragma unroll
    for (int ot = 0; ot < 2; ++ot)
#pragma unroll
      for (int qt = 0; qt < 4; ++qt)
        acc0[ot][qt] = f32x4_t{0.f, 0.f, 0.f, 0.f};
#pragma unroll
    for (int ks = 0; ks < 4; ++ks) {
      bf16x8_t Ba[2], Bb[2];
#pragma unroll
      for (int h = 0; h < 2; ++h)
        Ba[h] = *(const bf16x8_t*)(Xc + ((xr + h * 4096 + ks * 64) ^ swz));
      SBAR;
#pragma unroll
      for (int ot = 0; ot < 2; ++ot)
#pragma unroll
        for (int h = 0; h < 2; ++h)
          acc0[ot][h] = __builtin_amdgcn_mfma_f32_16x16x32_bf16(W0f[ot][ks], Ba[h], acc0[ot][h], 0, 0, 0);
#pragma unroll
      for (int h = 0; h < 2; ++h)
        Bb[h] = *(const bf16x8_t*)(Xc + ((xr + 8192 + h * 4096 + ks * 64) ^ swz));
      SBAR;
#pragma unroll
      for (int ot = 0; ot < 2; ++ot)
#pragma unroll
        for (int h = 0; h < 2; ++h)
          acc0[ot][2 + h] = __builtin_amdgcn_mfma_f32_16x16x32_bf16(W0f[ot][ks], Bb[h], acc0[ot][2 + h], 0, 0, 0);
      SBAR;
    }

    // finish gen_x for next tile (vmcnt drained here, hidden by layer-0)
    if (hn) gen_x_store(xl, Xa, xw);

    if constexpr (PHASE == 1) {
#pragma unroll
      for (int ot = 0; ot < 2; ++ot)
#pragma unroll
        for (int qt = 0; qt < 4; ++qt)
#pragma unroll
          for (int r2 = 0; r2 < 4; ++r2) {
            const float z = acc0[ot][qt][r2];
            s1[ot][r2] += z;
            s2v[ot][r2] += z * z;
          }
    } else {
      // a0 = lrelu(z0' + sh0), bf16 into swizzled LDS [q][o]
#pragma unroll
      for (int ot = 0; ot < 2; ++ot) {
#pragma unroll
        for (int qt = 0; qt < 4; ++qt) {
          bf16x4_t pk;
#pragma unroll
          for (int r2 = 0; r2 < 4; ++r2) {
            float v = acc0[ot][qt][r2] + sh0v[ot][r2];
            v = (v >= 0.f) ? v : 0.01f * v;
            pk[r2] = (__bf16)v;
          }
          *(bf16x4_t*)(Ab + ((aw + ot * 32 + qt * 8192) ^ swz)) = pk;
        }
      }
      __syncthreads();   // B2: a0 visible before layer-1 reads

      // P3 per-tile invariants issued early (latency hidden under layer-1)
      f32x4_t sh1v{}, wv{};
      if constexpr (PHASE == 3) {
        sh1v = *(const f32x4_t*)(sh1 + wid * 16 + g * 4);
        wv = *(const f32x4_t*)(wout + wid * 16 + g * 4);
      }

      // ---- layer 1: z1[p][q] = W1 . a0 ----
      f32x4_t acc1[4];
#pragma unroll
      for (int qt = 0; qt < 4; ++qt)
        acc1[qt] = f32x4_t{0.f, 0.f, 0.f, 0.f};
#pragma unroll
      for (int ks = 0; ks < 8; ++ks) {
        bf16x8_t Ba[2], Bb[2];
#pragma unroll
        for (int h = 0; h < 2; ++h)
          Ba[h] = *(const bf16x8_t*)(Ab + ((ar + h * 8192 + ks * 64) ^ swz));
        SBAR;
#pragma unroll
        for (int h = 0; h < 2; ++h)
          acc1[h] = __builtin_amdgcn_mfma_f32_16x16x32_bf16(W1f[ks], Ba[h], acc1[h], 0, 0, 0);
#pragma unroll
        for (int h = 0; h < 2; ++h)
          Bb[h] = *(const bf16x8_t*)(Ab + ((ar + 16384 + h * 8192 + ks * 64) ^ swz));
        SBAR;
#pragma unroll
        for (int h = 0; h < 2; ++h)
          acc1[2 + h] = __builtin_amdgcn_mfma_f32_16x16x32_bf16(W1f[ks], Bb[h], acc1[2 + h], 0, 0, 0);
        SBAR;
      }

      if constexpr (PHASE == 2) {
#pragma unroll
        for (int qt = 0; qt < 4; ++qt)
#pragma unroll
          for (int r2 = 0; r2 < 4; ++r2) {
            const float z = acc1[qt][r2];
            t1[r2] += z;
            t2v[r2] += z * z;
          }
      } else {
        // PHASE 3: a1 = lrelu(z1' + sh1); partial = wout.a1 -> sb (write only;
        // the sim store happens after next tile's B1)
        float part[4];
#pragma unroll
        for (int qt = 0; qt < 4; ++qt) {
          part[qt] = 0.f;
#pragma unroll
          for (int r2 = 0; r2 < 4; ++r2) {
            float v = acc1[qt][r2] + sh1v[r2];
            v = (v >= 0.f) ? v : 0.01f * v;
            part[qt] += wv[r2] * v;
          }
        }
#pragma unroll
        for (int qt = 0; qt < 4; ++qt) {   // reduce over g (p sub-slots)
          part[qt] += __shfl_xor(part[qt], 16, 64);
          part[qt] += __shfl_xor(part[qt], 32, 64);
        }
        if (lane < 16) {
#pragma unroll
          for (int qt = 0; qt < 4; ++qt)
            sb[wid * 64 + qt * 16 + lr] = part[qt];
        }
        pi0 = i0; pj0 = j0;
      }
    }
  }

  // ---- P3 drain: last tile's sim write ----
  if constexpr (PHASE == 3) {
    __syncthreads();
    if (tid < 64) {
      float sv = bout;
#pragma unroll
      for (int w = 0; w < 8; ++w) sv += sb[w * 64 + tid];
      sim[(pi0 + (tid >> 3)) * N_NODES + pj0 + (tid & 7)] = 1.f / (1.f + expf(-sv));
    }
  }

  // ---- stats flush: shuffle-reduce over the 16 q-lanes; o/p slices are
  //      wave-disjoint, so one LDS write + one atomicAdd per stat. ----
  if constexpr (PHASE == 1) {
#pragma unroll
    for (int ot = 0; ot < 2; ++ot)
#pragma unroll
      for (int r2 = 0; r2 < 4; ++r2) {
        float v1 = s1[ot][r2], v2 = s2v[ot][r2];
#pragma unroll
        for (int m = 1; m < 16; m <<= 1) {
          v1 += __shfl_xor(v1, m, 64);
          v2 += __shfl_xor(v2, m, 64);
        }
        s1[ot][r2] = v1; s2v[ot][r2] = v2;
      }
    __syncthreads();
    if (lr == 0) {
#pragma unroll
      for (int ot = 0; ot < 2; ++ot)
#pragma unroll
        for (int r2 = 0; r2 < 4; ++r2) {
          const int o = wid * 32 + ot * 16 + g * 4 + r2;
          sb[o] = s1[ot][r2];
          sb[256 + o] = s2v[ot][r2];
        }
    }
    __syncthreads();
    atomicAdd(stats + tid, sb[tid]);   // tid < 512: 256 sums + 256 sumsq
  }
  if constexpr (PHASE == 2) {
#pragma unroll
    for (int r2 = 0; r2 < 4; ++r2) {
      float v1 = t1[r2], v2 = t2v[r2];
#pragma unroll
      for (int m = 1; m < 16; m <<= 1) {
        v1 += __shfl_xor(v1, m, 64);
        v2 += __shfl_xor(v2, m, 64);
      }
      t1[r2] = v1; t2v[r2] = v2;
    }
    __syncthreads();
    if (lr == 0) {
#pragma unroll
      for (int r2 = 0; r2 < 4; ++r2) {
        const int p = wid * 16 + g * 4 + r2;
        sb[p] = t1[r2];
        sb[128 + p] = t2v[r2];
      }
    }
    __syncthreads();
    if (tid < 256) atomicAdd(stats + tid, sb[tid]);
  }
}

// ---------------------------------------------------------------------------
// finalize: mean/var -> per-channel scale/shift for BN(+gamma,beta)
// ---------------------------------------------------------------------------
__global__ void finalize_kernel(const float* __restrict__ ssum, const float* __restrict__ ssq,
                                const float* __restrict__ gamma, const float* __restrict__ beta,
                                float* __restrict__ sc, float* __restrict__ sh, int n)
{
  const int i = (int)(blockIdx.x * blockDim.x + threadIdx.x);
  if (i < n) {
    const float invN = 1.f / 589824.f;
    const float m = ssum[i] * invN;
    const float var = ssq[i] * invN - m * m;
    const float is = rsqrtf(var + 1e-5f);
    const float s = gamma[i] * is;
    sc[i] = s;
    sh[i] = beta[i] - m * s;
  }
}

// ---------------------------------------------------------------------------
// edge graph tail: colsum of edge matrix (edge = same_label*sim + I + 1e-6)
// ---------------------------------------------------------------------------
__global__ void colsum_kernel(const float* __restrict__ sim, const int* __restrict__ lab,
                              float* __restrict__ colsum)
{
  const int t = (int)threadIdx.x;
  const int bi = (int)blockIdx.x * 8;
  const int lj0 = lab[t], lj1 = lab[t + 256], lj2 = lab[t + 512];
  float a0 = 0.f, a1 = 0.f, a2 = 0.f;
  for (int r = 0; r < 8; ++r) {
    const int i = bi + r;
    const int li = lab[i];
    const float* srow = sim + i * N_NODES;
    a0 += ((li == lj0) ? srow[t] : 0.f) + ((i == t) ? 1.f : 0.f) + 1e-6f;
    a1 += ((li == lj1) ? srow[t + 256] : 0.f) + ((i == t + 256) ? 1.f : 0.f) + 1e-6f;
    a2 += ((li == lj2) ? srow[t + 512] : 0.f) + ((i == t + 512) ? 1.f : 0.f) + 1e-6f;
  }
  atomicAdd(colsum + t, a0);
  atomicAdd(colsum + t + 256, a1);
  atomicAdd(colsum + t + 512, a2);
}

// aggr[i][:] = (e_row_i / max(sum|e_row_i|,1e-12)) @ feat,  e = colnorm(edge) with zero diag
__global__ void aggr_kernel(const float* __restrict__ sim, const int* __restrict__ lab,
                            const float* __restrict__ colsum, const float* __restrict__ feat,
                            float* __restrict__ aggr)
{
  __shared__ float wrow[N_NODES];
  __shared__ float red[128];
  const int i = (int)blockIdx.x, t = (int)threadIdx.x;
  const int li = lab[i];
  const float* srow = sim + i * N_NODES;
  float rs = 0.f;
  for (int s = 0; s < 6; ++s) {
    const int j = t + s * 128;
    const float e = ((li == lab[j]) ? srow[j] : 0.f) + ((i == j) ? 1.f : 0.f) + 1e-6f;
    const float w = (j == i) ? 0.f : e / colsum[j];
    wrow[j] = w;
    rs += w;
  }
  red[t] = rs;
  __syncthreads();
  for (int off = 64; off > 0; off >>= 1) {
    if (t < off) red[t] += red[t + off];
    __syncthreads();
  }
  const float inv = 1.f / fmaxf(red[0], 1e-12f);
  float acc = 0.f;
  for (int j = 0; j < N_NODES; ++j) acc += wrow[j] * feat[j * 128 + t];
  aggr[i * 128 + t] = acc * inv;
}

// node MLP layer0: h2[r][n] = lrelu(bn(n_w0 @ [feat;aggr]^T)), bn over n
__global__ void mlp0_kernel(const float* __restrict__ feat, const float* __restrict__ aggr,
                            const float* __restrict__ w, const float* __restrict__ gamma,
                            const float* __restrict__ beta, float* __restrict__ h2)
{
  __shared__ float wr[256];
  __shared__ float redA[256], redB[256];
  const int r = (int)blockIdx.x, t = (int)threadIdx.x;
  wr[t] = w[r * 256 + t];
  __syncthreads();
  float v[3];
#pragma unroll
  for (int s = 0; s < 3; ++s) {
    const int n = t + s * 256;
    const float* fr = feat + n * 128;
    const float* ar = aggr + n * 128;
    float acc = 0.f;
#pragma unroll 4
    for (int c = 0; c < 128; c += 4) {
      const f32x4_t fv = *(const f32x4_t*)(fr + c);
      acc += wr[c] * fv[0] + wr[c + 1] * fv[1] + wr[c + 2] * fv[2] + wr[c + 3] * fv[3];
    }
#pragma unroll 4
    for (int c = 0; c < 128; c += 4) {
      const f32x4_t av = *(const f32x4_t*)(ar + c);
      acc += wr[128 + c] * av[0] + wr[129 + c] * av[1] + wr[130 + c] * av[2] + wr[131 + c] * av[3];
    }
    v[s] = acc;
  }
  redA[t] = v[0] + v[1] + v[2];
  redB[t] = v[0] * v[0] + v[1] * v[1] + v[2] * v[2];
  __syncthreads();
  for (int off = 128; off > 0; off >>= 1) {
    if (t < off) { redA[t] += redA[t + off]; redB[t] += redB[t + off]; }
    __syncthreads();
  }
  const float m = redA[0] * (1.f / 768.f);
  const float var = redB[0] * (1.f / 768.f) - m * m;
  const float is = rsqrtf(var + 1e-5f);
  const float sc = gamma[r] * is;
  const float sh = beta[r] - m * sc;
#pragma unroll
  for (int s = 0; s < 3; ++s) {
    float y = v[s] * sc + sh;
    y = (y >= 0.f) ? y : 0.01f * y;
    h2[r * 768 + t + s * 256] = y;
  }
}

// node MLP layer1: logits[n][r] = bn(n_w1 @ h2)[r][n]  (no lrelu)
__global__ void mlp1_kernel(const float* __restrict__ h2, const float* __restrict__ w,
                            const float* __restrict__ gamma, const float* __restrict__ beta,
                            float* __restrict__ logits)
{
  __shared__ float wr[130];
  __shared__ float redA[256], redB[256];
  const int r = (int)blockIdx.x, t = (int)threadIdx.x;
  if (t < 130) wr[t] = w[r * 130 + t];
  __syncthreads();
  float v[3];
#pragma unroll
  for (int s = 0; s < 3; ++s) {
    const int n = t + s * 256;
    float acc = 0.f;
    for (int c = 0; c < 130; ++c) acc += wr[c] * h2[c * 768 + n];
    v[s] = acc;
  }
  redA[t] = v[0] + v[1] + v[2];
  redB[t] = v[0] * v[0] + v[1] * v[1] + v[2] * v[2];
  __syncthreads();
  for (int off = 128; off > 0; off >>= 1) {
    if (t < off) { redA[t] += redA[t + off]; redB[t] += redB[t + off]; }
    __syncthreads();
  }
  const float m = redA[0] * (1.f / 768.f);
  const float var = redB[0] * (1.f / 768.f) - m * m;
  const float is = rsqrtf(var + 1e-5f);
  const float sc = gamma[r] * is;
  const float sh = beta[r] - m * sc;
#pragma unroll
  for (int s = 0; s < 3; ++s) {
    const float y = v[s] * sc + sh;
    logits[(t + s * 256) * 65 + r] = y;
  }
}

// ---------------------------------------------------------------------------
extern "C" void kernel_launch(void* const* d_in, const int* in_sizes, int n_in,
                              void* d_out, int out_size, void* d_ws, size_t ws_size,
                              hipStream_t stream)
{
  (void)in_sizes; (void)n_in; (void)out_size; (void)ws_size;
  const float* feat   = (const float*)d_in[0];
  const int*   lab    = (const int*)d_in[1];
  const float* e_w0   = (const float*)d_in[2];
  const float* e_g0   = (const float*)d_in[3];
  const float* e_b0   = (const float*)d_in[4];
  const float* e_w1   = (const float*)d_in[5];
  const float* e_g1   = (const float*)d_in[6];
  const float* e_b1   = (const float*)d_in[7];
  const float* e_wout = (const float*)d_in[8];
  const float* e_bout = (const float*)d_in[9];
  const float* n_w0   = (const float*)d_in[10];
  const float* n_g0   = (const float*)d_in[11];
  const float* n_b0   = (const float*)d_in[12];
  const float* n_w1   = (const float*)d_in[13];
  const float* n_g1   = (const float*)d_in[14];
  const float* n_b1   = (const float*)d_in[15];

  float* out = (float*)d_out;
  float* logits = out;                 // 768*65
  float* sim = out + 768 * 65;         // 768*768

  // workspace layout (floats)
  float* wsf = (float*)d_ws;
  float* S0A = wsf + 0;      // 256  (sum z0)   [S0B = +256]
  float* S0B = wsf + 256;
  float* S1A = wsf + 512;    // 128  [S1B = +128]
  float* S1B = wsf + 640;
  float* colsum = wsf + 768; // 768
  float* sc0 = wsf + 1536;   // 256
  float* sh0 = wsf + 1792;   // 256
  float* sc1 = wsf + 2048;   // 128
  float* sh1 = wsf + 2176;   // 128
  float* aggr = wsf + 2304;            // 768*128 (tail only)
  float* h2 = wsf + 2304 + 768 * 128;  // 130*768
  // featb aliases aggr's region (aggr written only after phase 3)
  __bf16* featb = (__bf16*)(wsf + 2304);            // 98304 bf16 (192KB)
  __bf16* W0bf = (__bf16*)(wsf + 200448);           // 32768 bf16
  __bf16* W1bf = (__bf16*)(wsf + 216832);
  __bf16* W0s  = (__bf16*)(wsf + 233216);           // sc0-folded
  __bf16* W1s  = (__bf16*)(wsf + 249600);           // sc1-folded

  // zero stat + colsum accumulators (replayed every graph launch)
  hipMemsetAsync(d_ws, 0, 2304 * sizeof(float), stream);

  prep_kernel<<<384, 256, 0, stream>>>(feat, e_w0, e_w1, featb, W0bf, W1bf);

  pair_phase_kernel<1><<<2304, 512, 0, stream>>>(featb, W0bf, nullptr, nullptr, nullptr,
                                                 nullptr, nullptr, S0A, nullptr);
  finalize_kernel<<<1, 256, 0, stream>>>(S0A, S0B, e_g0, e_b0, sc0, sh0, 256);
  wscale_kernel<<<128, 256, 0, stream>>>(e_w0, sc0, W0s, 128, 32768);
  pair_phase_kernel<2><<<2304, 512, 0, stream>>>(featb, W0s, W1bf, nullptr, nullptr,
                                                 sh0, nullptr, S1A, nullptr);
  finalize_kernel<<<1, 128, 0, stream>>>(S1A, S1B, e_g1, e_b1, sc1, sh1, 128);
  wscale_kernel<<<128, 256, 0, stream>>>(e_w1, sc1, W1s, 256, 32768);
  pair_phase_kernel<3><<<2304, 512, 0, stream>>>(featb, W0s, W1s, e_wout, e_bout,
                                                 sh0, sh1, nullptr, sim);
  colsum_kernel<<<96, 256, 0, stream>>>(sim, lab, colsum);
  aggr_kernel<<<768, 128, 0, stream>>>(sim, lab, colsum, feat, aggr);
  mlp0_kernel<<<130, 256, 0, stream>>>(feat, aggr, n_w0, n_g0, n_b0, h2);
  mlp1_kernel<<<65, 256, 0, stream>>>(h2, n_w1, n_g1, n_b1, logits);
}

// Round 11
// 404.096 us; speedup vs baseline: 1.7367x; 1.0510x over previous
//
#include <hip/hip_runtime.h>
#include <cmath>

// ---------------------------------------------------------------------------
// ClassifierGNN: N=768 nodes, D=128 feat, edge-MLP channels 256->128->1,
// node-MLP 256->130->65.
// 3 recompute phases (stats0, stats1, sim) using bf16 MFMA 16x16x32.
// R10 -> R11: latency pipeline inside the MFMA loops.
//   R10 showed 21% MFMA / 31% VALU / ~50% LDS-pipe -> still dependency-bound:
//   each half-step's MFMA waited the full ~120cy LDS latency of loads issued
//   0 cycles before it (end-of-step SBAR blocked cross-step overlap).
//   Fix: explicit 1-deep ping-pong (LD(s+1); SBAR; MFMA(s); SBAR) in both
//   layers -- loads get a full MFMA-cluster + TLP of coverage. Zero extra
//   registers (same two 8-reg buffers alternated).
//   Also: lrelu = fmaxf(v, 0.01f*v) (2 VALU instead of 3).
// ---------------------------------------------------------------------------

#define N_NODES 768
#define NBJ 96          // j-tiles per row of tiles (768/8)
#define NTILES 9216     // (768/8) * (768/8)

// LDS layout (bytes): total 67584 -> 2 blocks/CU (=> 128-reg budget).
#define L_X0   0        // X buf0: 64 q * 128 c * bf16 = 16384
#define L_X1   16384    // X buf1: 16384
#define L_A0   32768    // 64 q * 256 c * bf16 = 32768
#define L_SB   65536    // 512 f32 = 2048 (stat/sim staging)
#define L_TOT  67584

static_assert(L_TOT > 53760 && L_TOT <= 81920, "want exactly 2 blocks/CU");

typedef __bf16 bf16x8_t __attribute__((ext_vector_type(8)));
typedef __bf16 bf16x4_t __attribute__((ext_vector_type(4)));
typedef unsigned short u16x8_t __attribute__((ext_vector_type(8)));
typedef float f32x4_t __attribute__((ext_vector_type(4)));

#define SBAR __builtin_amdgcn_sched_barrier(0)

// ---------------------------------------------------------------------------
// prep: cast feat (98304) and W0/W1 (32768 each) to bf16.
// ---------------------------------------------------------------------------
__global__ void prep_kernel(const float* __restrict__ feat,
                            const float* __restrict__ w0, const float* __restrict__ w1,
                            __bf16* __restrict__ featb,
                            __bf16* __restrict__ w0b, __bf16* __restrict__ w1b)
{
  const int i = (int)(blockIdx.x * 256 + threadIdx.x);
  if (i < 98304) featb[i] = (__bf16)feat[i];
  if (i < 32768) { w0b[i] = (__bf16)w0[i]; w1b[i] = (__bf16)w1[i]; }
}

// wscale: dst[i] = bf16(w[i] * sc[i/cols])  (fold BN scale into weight rows)
__global__ void wscale_kernel(const float* __restrict__ w, const float* __restrict__ sc,
                              __bf16* __restrict__ dst, int cols, int n)
{
  const int i = (int)(blockIdx.x * 256 + threadIdx.x);
  if (i < n) dst[i] = (__bf16)(w[i] * sc[i / cols]);
}

// ---------------------------------------------------------------------------
// gen_x split: LOAD (3 bf16x8 global loads, 12 regs in flight) / STORE
// (cvt + 2 swizzled LDS writes). jv is shared by both items (same j-row).
// ---------------------------------------------------------------------------
struct XLoad { bf16x8_t iv0, iv1, jv; };

__device__ __forceinline__ XLoad gen_x_load(const __bf16* __restrict__ featb,
                                            int i0, int j0, int q0, int c8)
{
  XLoad r;
  const __bf16* gi = featb + (i0 + (q0 >> 3)) * 128 + c8;
  r.iv0 = *(const bf16x8_t*)gi;
  r.iv1 = *(const bf16x8_t*)(gi + 512);     // item1: i-row + 4
  r.jv  = *(const bf16x8_t*)(featb + (j0 + (q0 & 7)) * 128 + c8);
  return r;
}

__device__ __forceinline__ bf16x8_t absdiff8(bf16x8_t a, bf16x8_t b)
{
  const u16x8_t ua = __builtin_bit_cast(u16x8_t, a);
  const u16x8_t ub = __builtin_bit_cast(u16x8_t, b);
  bf16x8_t r;
#pragma unroll
  for (int s = 0; s < 8; ++s) {
    const float fa = __uint_as_float(((unsigned int)ua[s]) << 16);
    const float fb = __uint_as_float(((unsigned int)ub[s]) << 16);
    r[s] = (__bf16)fabsf(fa - fb);
  }
  return r;
}

__device__ __forceinline__ void gen_x_store(const XLoad& x, unsigned char* __restrict__ Xdst,
                                            int xw)
{
  *(bf16x8_t*)(Xdst + xw) = absdiff8(x.iv0, x.jv);
  *(bf16x8_t*)(Xdst + xw + 8192) = absdiff8(x.iv1, x.jv);
}

// ---------------------------------------------------------------------------
// Fused pair-MLP kernel.
// Tile = 8 i-rows x 8 j-cols = 64 pairs (q = i_loc*8 + j_loc). 512 thr = 8 waves.
// Wave w owns o in [32w,32w+32) for layer0 and p in [16w,16w+16) for layer1;
// every wave processes all 64 q. Weights persistent VGPR fragments; BN scale
// pre-folded into W0b/W1b where available.
// PHASE 1: z0 -> per-channel sum/sumsq (atomics)
// PHASE 2: z0' -> a0 -> z1 -> sum/sumsq
// PHASE 3: z0' -> a0 -> z1' -> a1 -> sim = sigmoid(wout.a1 + bout)
// ---------------------------------------------------------------------------

// layer-0 pipeline primitives: step (KS, HF) covers q-half HF at k-slice KS
#define LD0(BUF, KS, HF)                                                       \
  { _Pragma("unroll") for (int h = 0; h < 2; ++h)                              \
      BUF[h] = *(const bf16x8_t*)(Xc + ((xr + (HF) * 8192 + h * 4096 + (KS) * 64) ^ swz)); }
#define MM0(BUF, KS, HF)                                                       \
  { _Pragma("unroll") for (int ot = 0; ot < 2; ++ot)                           \
      _Pragma("unroll") for (int h = 0; h < 2; ++h)                            \
        acc0[ot][(HF) * 2 + h] = __builtin_amdgcn_mfma_f32_16x16x32_bf16(      \
            W0f[ot][(KS)], BUF[h], acc0[ot][(HF) * 2 + h], 0, 0, 0); }

// layer-1 pipeline primitives
#define LD1(BUF, KS, HF)                                                       \
  { _Pragma("unroll") for (int h = 0; h < 2; ++h)                              \
      BUF[h] = *(const bf16x8_t*)(Ab + ((ar + (HF) * 16384 + h * 8192 + (KS) * 64) ^ swz)); }
#define MM1(BUF, KS, HF)                                                       \
  { _Pragma("unroll") for (int h = 0; h < 2; ++h)                              \
      acc1[(HF) * 2 + h] = __builtin_amdgcn_mfma_f32_16x16x32_bf16(            \
          W1f[(KS)], BUF[h], acc1[(HF) * 2 + h], 0, 0, 0); }

template<int PHASE>
__global__ void
__attribute__((amdgpu_flat_work_group_size(512, 512)))
pair_phase_kernel(const __bf16* __restrict__ featb,
                  const __bf16* __restrict__ W0b,
                  const __bf16* __restrict__ W1b,
                  const float* __restrict__ wout,
                  const float* __restrict__ boutp,
                  const float* __restrict__ sh0,
                  const float* __restrict__ sh1,
                  float* __restrict__ stats,
                  float* __restrict__ sim)
{
  __shared__ __align__(16) unsigned char smem[L_TOT];
  unsigned char* Ab = smem + L_A0;
  float* sb = (float*)(smem + L_SB);

  const int tid = (int)threadIdx.x;
  const int wid = tid >> 6;
  const int lane = tid & 63;
  const int lr = lane & 15;
  const int g = lane >> 4;

  // ---- persistent weight fragments (loaded once per block) ----
  bf16x8_t W0f[2][4];
#pragma unroll
  for (int ot = 0; ot < 2; ++ot)
#pragma unroll
    for (int ks = 0; ks < 4; ++ks)
      W0f[ot][ks] = *(const bf16x8_t*)(W0b + (wid * 32 + ot * 16 + lr) * 128 + ks * 32 + g * 8);

  bf16x8_t W1f[8];
  if constexpr (PHASE >= 2) {
#pragma unroll
    for (int ks = 0; ks < 8; ++ks)
      W1f[ks] = *(const bf16x8_t*)(W1b + (wid * 16 + lr) * 256 + ks * 32 + g * 8);
  }

  // persistent layer-0 BN shift (scale folded into W0b)
  f32x4_t sh0v[2];
  if constexpr (PHASE >= 2) {
#pragma unroll
    for (int ot = 0; ot < 2; ++ot)
      sh0v[ot] = *(const f32x4_t*)(sh0 + wid * 32 + ot * 16 + g * 4);
  }
  float bout = 0.f;
  if constexpr (PHASE == 3) bout = boutp[0];

  // per-lane LDS address bases (offsets added per access, then XOR swizzle)
  const int swz = (lr & 7) << 4;
  const int xr = (lr << 8) + (g << 4);           // layer-0 B-read
  const int ar = (lr << 9) + (g << 4);           // layer-1 B-read
  const int aw = (lr << 9) + wid * 64 + g * 8;   // a0 write
  const int q0 = tid >> 4;
  const int c8 = (tid & 15) * 8;
  const int xw = (((q0 << 8) + ((tid & 15) << 4)) ^ ((q0 & 7) << 4));  // X write

  float s1[2][4], s2v[2][4];   // phase1 stats (z0)
  float t1[4], t2v[4];         // phase2 stats (z1)
  if constexpr (PHASE == 1) {
#pragma unroll
    for (int ot = 0; ot < 2; ++ot)
#pragma unroll
      for (int r2 = 0; r2 < 4; ++r2) { s1[ot][r2] = 0.f; s2v[ot][r2] = 0.f; }
  }
  if constexpr (PHASE == 2) {
#pragma unroll
    for (int r2 = 0; r2 < 4; ++r2) { t1[r2] = 0.f; t2v[r2] = 0.f; }
  }

  // prologue: X for first tile -> buf0 (load+store back-to-back, one-time stall)
  {
    const int t0 = (int)blockIdx.x;
    const int ti = t0 / NBJ;
    XLoad xl = gen_x_load(featb, ti * 8, (t0 - ti * NBJ) * 8, q0, c8);
    gen_x_store(xl, smem + L_X0, xw);
  }
  int bufc = 0;
  int pi0 = -1, pj0 = -1;   // P3 deferred sim-write coords

  for (int tile = (int)blockIdx.x; tile < NTILES; tile += (int)gridDim.x) {
    const int ti = tile / NBJ;
    const int i0 = ti * 8;
    const int j0 = (tile - ti * NBJ) * 8;

    __syncthreads();   // B1: X[cur] visible; prev-tile LDS reads done

    // deferred sim write for previous tile
    if constexpr (PHASE == 3) {
      if (pi0 >= 0 && tid < 64) {
        float sv = bout;
#pragma unroll
        for (int w = 0; w < 8; ++w) sv += sb[w * 64 + tid];
        sim[(pi0 + (tid >> 3)) * N_NODES + pj0 + (tid & 7)] = 1.f / (1.f + expf(-sv));
      }
    }

    // issue next-tile gen_x loads (completion consumed AFTER layer-0)
    const int nxt = tile + (int)gridDim.x;
    const bool hn = (nxt < NTILES);
    XLoad xl;
    if (hn) {
      const int nti = nxt / NBJ;
      xl = gen_x_load(featb, nti * 8, (nxt - nti * NBJ) * 8, q0, c8);
    }
    unsigned char* Xc = smem + (bufc ? L_X1 : L_X0);
    unsigned char* Xa = smem + (bufc ? L_X0 : L_X1);
    bufc ^= 1;

    // ---- layer 0: z0[o][q] = W0 . X ---- (1-deep ping-pong, 8 half-steps)
    f32x4_t acc0[2][4];
#pragma unroll
    for (int ot = 0; ot < 2; ++ot)
#pragma unroll
      for (int qt = 0; qt < 4; ++qt)
        acc0[ot][qt] = f32x4_t{0.f, 0.f, 0.f, 0.f};
    {
      bf16x8_t BP[2], BQ[2];
      LD0(BP, 0, 0);
      LD0(BQ, 0, 1); SBAR; MM0(BP, 0, 0); SBAR;
      LD0(BP, 1, 0); SBAR; MM0(BQ, 0, 1); SBAR;
      LD0(BQ, 1, 1); SBAR; MM0(BP, 1, 0); SBAR;
      LD0(BP, 2, 0); SBAR; MM0(BQ, 1, 1); SBAR;
      LD0(BQ, 2, 1); SBAR; MM0(BP, 2, 0); SBAR;
      LD0(BP, 3, 0); SBAR; MM0(BQ, 2, 1); SBAR;
      LD0(BQ, 3, 1); SBAR; MM0(BP, 3, 0); SBAR;
      MM0(BQ, 3, 1);
    }

    // finish gen_x for next tile (vmcnt drained here, hidden by layer-0)
    if (hn) gen_x_store(xl, Xa, xw);

    if constexpr (PHASE == 1) {
#pragma unroll
      for (int ot = 0; ot < 2; ++ot)
#pragma unroll
        for (int qt = 0; qt < 4; ++qt)
#pragma unroll
          for (int r2 = 0; r2 < 4; ++r2) {
            const float z = acc0[ot][qt][r2];
            s1[ot][r2] += z;
            s2v[ot][r2] += z * z;
          }
    } else {
      // a0 = lrelu(z0' + sh0), bf16 into swizzled LDS [q][o]
#pragma unroll
      for (int ot = 0; ot < 2; ++ot) {
#pragma unroll
        for (int qt = 0; qt < 4; ++qt) {
          bf16x4_t pk;
#pragma unroll
          for (int r2 = 0; r2 < 4; ++r2) {
            const float z = acc0[ot][qt][r2] + sh0v[ot][r2];
            pk[r2] = (__bf16)fmaxf(z, 0.01f * z);
          }
          *(bf16x4_t*)(Ab + ((aw + ot * 32 + qt * 8192) ^ swz)) = pk;
        }
      }
      __syncthreads();   // B2: a0 visible before layer-1 reads

      // P3 per-tile invariants issued early (latency hidden under layer-1)
      f32x4_t sh1v{}, wv{};
      if constexpr (PHASE == 3) {
        sh1v = *(const f32x4_t*)(sh1 + wid * 16 + g * 4);
        wv = *(const f32x4_t*)(wout + wid * 16 + g * 4);
      }

      // ---- layer 1: z1[p][q] = W1 . a0 ---- (1-deep ping-pong, 16 steps)
      f32x4_t acc1[4];
#pragma unroll
      for (int qt = 0; qt < 4; ++qt)
        acc1[qt] = f32x4_t{0.f, 0.f, 0.f, 0.f};
      {
        bf16x8_t CP[2], CQ[2];
        LD1(CP, 0, 0);
        LD1(CQ, 0, 1); SBAR; MM1(CP, 0, 0); SBAR;
        LD1(CP, 1, 0); SBAR; MM1(CQ, 0, 1); SBAR;
        LD1(CQ, 1, 1); SBAR; MM1(CP, 1, 0); SBAR;
        LD1(CP, 2, 0); SBAR; MM1(CQ, 1, 1); SBAR;
        LD1(CQ, 2, 1); SBAR; MM1(CP, 2, 0); SBAR;
        LD1(CP, 3, 0); SBAR; MM1(CQ, 2, 1); SBAR;
        LD1(CQ, 3, 1); SBAR; MM1(CP, 3, 0); SBAR;
        LD1(CP, 4, 0); SBAR; MM1(CQ, 3, 1); SBAR;
        LD1(CQ, 4, 1); SBAR; MM1(CP, 4, 0); SBAR;
        LD1(CP, 5, 0); SBAR; MM1(CQ, 4, 1); SBAR;
        LD1(CQ, 5, 1); SBAR; MM1(CP, 5, 0); SBAR;
        LD1(CP, 6, 0); SBAR; MM1(CQ, 5, 1); SBAR;
        LD1(CQ, 6, 1); SBAR; MM1(CP, 6, 0); SBAR;
        LD1(CP, 7, 0); SBAR; MM1(CQ, 6, 1); SBAR;
        LD1(CQ, 7, 1); SBAR; MM1(CP, 7, 0); SBAR;
        MM1(CQ, 7, 1);
      }

      if constexpr (PHASE == 2) {
#pragma unroll
        for (int qt = 0; qt < 4; ++qt)
#pragma unroll
          for (int r2 = 0; r2 < 4; ++r2) {
            const float z = acc1[qt][r2];
            t1[r2] += z;
            t2v[r2] += z * z;
          }
      } else {
        // PHASE 3: a1 = lrelu(z1' + sh1); partial = wout.a1 -> sb (write only;
        // the sim store happens after next tile's B1)
        float part[4];
#pragma unroll
        for (int qt = 0; qt < 4; ++qt) {
          part[qt] = 0.f;
#pragma unroll
          for (int r2 = 0; r2 < 4; ++r2) {
            const float z = acc1[qt][r2] + sh1v[r2];
            part[qt] += wv[r2] * fmaxf(z, 0.01f * z);
          }
        }
#pragma unroll
        for (int qt = 0; qt < 4; ++qt) {   // reduce over g (p sub-slots)
          part[qt] += __shfl_xor(part[qt], 16, 64);
          part[qt] += __shfl_xor(part[qt], 32, 64);
        }
        if (lane < 16) {
#pragma unroll
          for (int qt = 0; qt < 4; ++qt)
            sb[wid * 64 + qt * 16 + lr] = part[qt];
        }
        pi0 = i0; pj0 = j0;
      }
    }
  }

  // ---- P3 drain: last tile's sim write ----
  if constexpr (PHASE == 3) {
    __syncthreads();
    if (tid < 64) {
      float sv = bout;
#pragma unroll
      for (int w = 0; w < 8; ++w) sv += sb[w * 64 + tid];
      sim[(pi0 + (tid >> 3)) * N_NODES + pj0 + (tid & 7)] = 1.f / (1.f + expf(-sv));
    }
  }

  // ---- stats flush: shuffle-reduce over the 16 q-lanes; o/p slices are
  //      wave-disjoint, so one LDS write + one atomicAdd per stat. ----
  if constexpr (PHASE == 1) {
#pragma unroll
    for (int ot = 0; ot < 2; ++ot)
#pragma unroll
      for (int r2 = 0; r2 < 4; ++r2) {
        float v1 = s1[ot][r2], v2 = s2v[ot][r2];
#pragma unroll
        for (int m = 1; m < 16; m <<= 1) {
          v1 += __shfl_xor(v1, m, 64);
          v2 += __shfl_xor(v2, m, 64);
        }
        s1[ot][r2] = v1; s2v[ot][r2] = v2;
      }
    __syncthreads();
    if (lr == 0) {
#pragma unroll
      for (int ot = 0; ot < 2; ++ot)
#pragma unroll
        for (int r2 = 0; r2 < 4; ++r2) {
          const int o = wid * 32 + ot * 16 + g * 4 + r2;
          sb[o] = s1[ot][r2];
          sb[256 + o] = s2v[ot][r2];
        }
    }
    __syncthreads();
    atomicAdd(stats + tid, sb[tid]);   // tid < 512: 256 sums + 256 sumsq
  }
  if constexpr (PHASE == 2) {
#pragma unroll
    for (int r2 = 0; r2 < 4; ++r2) {
      float v1 = t1[r2], v2 = t2v[r2];
#pragma unroll
      for (int m = 1; m < 16; m <<= 1) {
        v1 += __shfl_xor(v1, m, 64);
        v2 += __shfl_xor(v2, m, 64);
      }
      t1[r2] = v1; t2v[r2] = v2;
    }
    __syncthreads();
    if (lr == 0) {
#pragma unroll
      for (int r2 = 0; r2 < 4; ++r2) {
        const int p = wid * 16 + g * 4 + r2;
        sb[p] = t1[r2];
        sb[128 + p] = t2v[r2];
      }
    }
    __syncthreads();
    if (tid < 256) atomicAdd(stats + tid, sb[tid]);
  }
}

// ---------------------------------------------------------------------------
// finalize: mean/var -> per-channel scale/shift for BN(+gamma,beta)
// ---------------------------------------------------------------------------
__global__ void finalize_kernel(const float* __restrict__ ssum, const float* __restrict__ ssq,
                                const float* __restrict__ gamma, const float* __restrict__ beta,
                                float* __restrict__ sc, float* __restrict__ sh, int n)
{
  const int i = (int)(blockIdx.x * blockDim.x + threadIdx.x);
  if (i < n) {
    const float invN = 1.f / 589824.f;
    const float m = ssum[i] * invN;
    const float var = ssq[i] * invN - m * m;
    const float is = rsqrtf(var + 1e-5f);
    const float s = gamma[i] * is;
    sc[i] = s;
    sh[i] = beta[i] - m * s;
  }
}

// ---------------------------------------------------------------------------
// edge graph tail: colsum of edge matrix (edge = same_label*sim + I + 1e-6)
// ---------------------------------------------------------------------------
__global__ void colsum_kernel(const float* __restrict__ sim, const int* __restrict__ lab,
                              float* __restrict__ colsum)
{
  const int t = (int)threadIdx.x;
  const int bi = (int)blockIdx.x * 8;
  const int lj0 = lab[t], lj1 = lab[t + 256], lj2 = lab[t + 512];
  float a0 = 0.f, a1 = 0.f, a2 = 0.f;
  for (int r = 0; r < 8; ++r) {
    const int i = bi + r;
    const int li = lab[i];
    const float* srow = sim + i * N_NODES;
    a0 += ((li == lj0) ? srow[t] : 0.f) + ((i == t) ? 1.f : 0.f) + 1e-6f;
    a1 += ((li == lj1) ? srow[t + 256] : 0.f) + ((i == t + 256) ? 1.f : 0.f) + 1e-6f;
    a2 += ((li == lj2) ? srow[t + 512] : 0.f) + ((i == t + 512) ? 1.f : 0.f) + 1e-6f;
  }
  atomicAdd(colsum + t, a0);
  atomicAdd(colsum + t + 256, a1);
  atomicAdd(colsum + t + 512, a2);
}

// aggr[i][:] = (e_row_i / max(sum|e_row_i|,1e-12)) @ feat,  e = colnorm(edge) with zero diag
__global__ void aggr_kernel(const float* __restrict__ sim, const int* __restrict__ lab,
                            const float* __restrict__ colsum, const float* __restrict__ feat,
                            float* __restrict__ aggr)
{
  __shared__ float wrow[N_NODES];
  __shared__ float red[128];
  const int i = (int)blockIdx.x, t = (int)threadIdx.x;
  const int li = lab[i];
  const float* srow = sim + i * N_NODES;
  float rs = 0.f;
  for (int s = 0; s < 6; ++s) {
    const int j = t + s * 128;
    const float e = ((li == lab[j]) ? srow[j] : 0.f) + ((i == j) ? 1.f : 0.f) + 1e-6f;
    const float w = (j == i) ? 0.f : e / colsum[j];
    wrow[j] = w;
    rs += w;
  }
  red[t] = rs;
  __syncthreads();
  for (int off = 64; off > 0; off >>= 1) {
    if (t < off) red[t] += red[t + off];
    __syncthreads();
  }
  const float inv = 1.f / fmaxf(red[0], 1e-12f);
  float acc = 0.f;
  for (int j = 0; j < N_NODES; ++j) acc += wrow[j] * feat[j * 128 + t];
  aggr[i * 128 + t] = acc * inv;
}

// node MLP layer0: h2[r][n] = lrelu(bn(n_w0 @ [feat;aggr]^T)), bn over n
__global__ void mlp0_kernel(const float* __restrict__ feat, const float* __restrict__ aggr,
                            const float* __restrict__ w, const float* __restrict__ gamma,
                            const float* __restrict__ beta, float* __restrict__ h2)
{
  __shared__ float wr[256];
  __shared__ float redA[256], redB[256];
  const int r = (int)blockIdx.x, t = (int)threadIdx.x;
  wr[t] = w[r * 256 + t];
  __syncthreads();
  float v[3];
#pragma unroll
  for (int s = 0; s < 3; ++s) {
    const int n = t + s * 256;
    const float* fr = feat + n * 128;
    const float* ar = aggr + n * 128;
    float acc = 0.f;
#pragma unroll 4
    for (int c = 0; c < 128; c += 4) {
      const f32x4_t fv = *(const f32x4_t*)(fr + c);
      acc += wr[c] * fv[0] + wr[c + 1] * fv[1] + wr[c + 2] * fv[2] + wr[c + 3] * fv[3];
    }
#pragma unroll 4
    for (int c = 0; c < 128; c += 4) {
      const f32x4_t av = *(const f32x4_t*)(ar + c);
      acc += wr[128 + c] * av[0] + wr[129 + c] * av[1] + wr[130 + c] * av[2] + wr[131 + c] * av[3];
    }
    v[s] = acc;
  }
  redA[t] = v[0] + v[1] + v[2];
  redB[t] = v[0] * v[0] + v[1] * v[1] + v[2] * v[2];
  __syncthreads();
  for (int off = 128; off > 0; off >>= 1) {
    if (t < off) { redA[t] += redA[t + off]; redB[t] += redB[t + off]; }
    __syncthreads();
  }
  const float m = redA[0] * (1.f / 768.f);
  const float var = redB[0] * (1.f / 768.f) - m * m;
  const float is = rsqrtf(var + 1e-5f);
  const float sc = gamma[r] * is;
  const float sh = beta[r] - m * sc;
#pragma unroll
  for (int s = 0; s < 3; ++s) {
    float y = v[s] * sc + sh;
    y = (y >= 0.f) ? y : 0.01f * y;
    h2[r * 768 + t + s * 256] = y;
  }
}

// node MLP layer1: logits[n][r] = bn(n_w1 @ h2)[r][n]  (no lrelu)
__global__ void mlp1_kernel(const float* __restrict__ h2, const float* __restrict__ w,
                            const float* __restrict__ gamma, const float* __restrict__ beta,
                            float* __restrict__ logits)
{
  __shared__ float wr[130];
  __shared__ float redA[256], redB[256];
  const int r = (int)blockIdx.x, t = (int)threadIdx.x;
  if (t < 130) wr[t] = w[r * 130 + t];
  __syncthreads();
  float v[3];
#pragma unroll
  for (int s = 0; s < 3; ++s) {
    const int n = t + s * 256;
    float acc = 0.f;
    for (int c = 0; c < 130; ++c) acc += wr[c] * h2[c * 768 + n];
    v[s] = acc;
  }
  redA[t] = v[0] + v[1] + v[2];
  redB[t] = v[0] * v[0] + v[1] * v[1] + v[2] * v[2];
  __syncthreads();
  for (int off = 128; off > 0; off >>= 1) {
    if (t < off) { redA[t] += redA[t + off]; redB[t] += redB[t + off]; }
    __syncthreads();
  }
  const float m = redA[0] * (1.f / 768.f);
  const float var = redB[0] * (1.f / 768.f) - m * m;
  const float is = rsqrtf(var + 1e-5f);
  const float sc = gamma[r] * is;
  const float sh = beta[r] - m * sc;
#pragma unroll
  for (int s = 0; s < 3; ++s) {
    const float y = v[s] * sc + sh;
    logits[(t + s * 256) * 65 + r] = y;
  }
}

// ---------------------------------------------------------------------------
extern "C" void kernel_launch(void* const* d_in, const int* in_sizes, int n_in,
                              void* d_out, int out_size, void* d_ws, size_t ws_size,
                              hipStream_t stream)
{
  (void)in_sizes; (void)n_in; (void)out_size; (void)ws_size;
  const float* feat   = (const float*)d_in[0];
  const int*   lab    = (const int*)d_in[1];
  const float* e_w0   = (const float*)d_in[2];
  const float* e_g0   = (const float*)d_in[3];
  const float* e_b0   = (const float*)d_in[4];
  const float* e_w1   = (const float*)d_in[5];
  const float* e_g1   = (const float*)d_in[6];
  const float* e_b1   = (const float*)d_in[7];
  const float* e_wout = (const float*)d_in[8];
  const float* e_bout = (const float*)d_in[9];
  const float* n_w0   = (const float*)d_in[10];
  const float* n_g0   = (const float*)d_in[11];
  const float* n_b0   = (const float*)d_in[12];
  const float* n_w1   = (const float*)d_in[13];
  const float* n_g1   = (const float*)d_in[14];
  const float* n_b1   = (const float*)d_in[15];

  float* out = (float*)d_out;
  float* logits = out;                 // 768*65
  float* sim = out + 768 * 65;         // 768*768

  // workspace layout (floats)
  float* wsf = (float*)d_ws;
  float* S0A = wsf + 0;      // 256  (sum z0)   [S0B = +256]
  float* S0B = wsf + 256;
  float* S1A = wsf + 512;    // 128  [S1B = +128]
  float* S1B = wsf + 640;
  float* colsum = wsf + 768; // 768
  float* sc0 = wsf + 1536;   // 256
  float* sh0 = wsf + 1792;   // 256
  float* sc1 = wsf + 2048;   // 128
  float* sh1 = wsf + 2176;   // 128
  float* aggr = wsf + 2304;            // 768*128 (tail only)
  float* h2 = wsf + 2304 + 768 * 128;  // 130*768
  // featb aliases aggr's region (aggr written only after phase 3)
  __bf16* featb = (__bf16*)(wsf + 2304);            // 98304 bf16 (192KB)
  __bf16* W0bf = (__bf16*)(wsf + 200448);           // 32768 bf16
  __bf16* W1bf = (__bf16*)(wsf + 216832);
  __bf16* W0s  = (__bf16*)(wsf + 233216);           // sc0-folded
  __bf16* W1s  = (__bf16*)(wsf + 249600);           // sc1-folded

  // zero stat + colsum accumulators (replayed every graph launch)
  hipMemsetAsync(d_ws, 0, 2304 * sizeof(float), stream);

  prep_kernel<<<384, 256, 0, stream>>>(feat, e_w0, e_w1, featb, W0bf, W1bf);

  pair_phase_kernel<1><<<2304, 512, 0, stream>>>(featb, W0bf, nullptr, nullptr, nullptr,
                                                 nullptr, nullptr, S0A, nullptr);
  finalize_kernel<<<1, 256, 0, stream>>>(S0A, S0B, e_g0, e_b0, sc0, sh0, 256);
  wscale_kernel<<<128, 256, 0, stream>>>(e_w0, sc0, W0s, 128, 32768);
  pair_phase_kernel<2><<<2304, 512, 0, stream>>>(featb, W0s, W1bf, nullptr, nullptr,
                                                 sh0, nullptr, S1A, nullptr);
  finalize_kernel<<<1, 128, 0, stream>>>(S1A, S1B, e_g1, e_b1, sc1, sh1, 128);
  wscale_kernel<<<128, 256, 0, stream>>>(e_w1, sc1, W1s, 256, 32768);
  pair_phase_kernel<3><<<2304, 512, 0, stream>>>(featb, W0s, W1s, e_wout, e_bout,
                                                 sh0, sh1, nullptr, sim);
  colsum_kernel<<<96, 256, 0, stream>>>(sim, lab, colsum);
  aggr_kernel<<<768, 128, 0, stream>>>(sim, lab, colsum, feat, aggr);
  mlp0_kernel<<<130, 256, 0, stream>>>(feat, aggr, n_w0, n_g0, n_b0, h2);
  mlp1_kernel<<<65, 256, 0, stream>>>(h2, n_w1, n_g1, n_b1, logits);
}

// Round 12
// 401.819 us; speedup vs baseline: 1.7466x; 1.0057x over previous
//
#include <hip/hip_runtime.h>
#include <cmath>

// ---------------------------------------------------------------------------
// ClassifierGNN: N=768 nodes, D=128 feat, edge-MLP channels 256->128->1,
// node-MLP 256->130->65.
// 3 recompute phases (stats0, stats1, sim) using bf16 MFMA 16x16x32.
// R11 -> R12: phase-specialized tiling + setprio.
//   - P1 (stats0, no L1/a0) gets 8x16 tiles (128 pairs): X=32KB dbuf'd, L0 in
//     two 4-qt chunks (acc0 32 regs, stats folded per chunk). Front-end cost
//     per pair halves; registers ~120 <= 128 (P1 has no W1f/sh0/acc1).
//   - s_setprio(1/0) around MFMA clusters in all phases (2 independent
//     blocks/CU = wave role diversity, T5 prerequisite).
// ---------------------------------------------------------------------------

#define N_NODES 768
#define NBJ 96          // P2/P3: j-tiles per row (768/8)
#define NTILES 9216     // P2/P3: (768/8)*(768/8)
#define NBJ1 48         // P1: j-tiles per row (768/16)
#define NTILES1 4608    // P1: (768/8)*(768/16)

// LDS layout (bytes): total 67584 -> 2 blocks/CU (=> 128-reg budget).
// P2/P3: X dbuf 2x16K @0, A0 32K @32768, sb @65536
// P1:    X dbuf 2x32K @0,                sb @65536
#define L_X0   0
#define L_X1   16384
#define L_A0   32768
#define L_X1P  32768    // P1's second X buffer
#define L_SB   65536
#define L_TOT  67584

static_assert(L_TOT > 53760 && L_TOT <= 81920, "want exactly 2 blocks/CU");

typedef __bf16 bf16x8_t __attribute__((ext_vector_type(8)));
typedef __bf16 bf16x4_t __attribute__((ext_vector_type(4)));
typedef unsigned short u16x8_t __attribute__((ext_vector_type(8)));
typedef float f32x4_t __attribute__((ext_vector_type(4)));

#define SBAR __builtin_amdgcn_sched_barrier(0)

// ---------------------------------------------------------------------------
// prep: cast feat (98304) and W0/W1 (32768 each) to bf16.
// ---------------------------------------------------------------------------
__global__ void prep_kernel(const float* __restrict__ feat,
                            const float* __restrict__ w0, const float* __restrict__ w1,
                            __bf16* __restrict__ featb,
                            __bf16* __restrict__ w0b, __bf16* __restrict__ w1b)
{
  const int i = (int)(blockIdx.x * 256 + threadIdx.x);
  if (i < 98304) featb[i] = (__bf16)feat[i];
  if (i < 32768) { w0b[i] = (__bf16)w0[i]; w1b[i] = (__bf16)w1[i]; }
}

// wscale: dst[i] = bf16(w[i] * sc[i/cols])  (fold BN scale into weight rows)
__global__ void wscale_kernel(const float* __restrict__ w, const float* __restrict__ sc,
                              __bf16* __restrict__ dst, int cols, int n)
{
  const int i = (int)(blockIdx.x * 256 + threadIdx.x);
  if (i < n) dst[i] = (__bf16)(w[i] * sc[i / cols]);
}

// ---------------------------------------------------------------------------
// abs-diff of 8 bf16 lanes via f32 (cvt_pk on the way back)
// ---------------------------------------------------------------------------
__device__ __forceinline__ bf16x8_t absdiff8(bf16x8_t a, bf16x8_t b)
{
  const u16x8_t ua = __builtin_bit_cast(u16x8_t, a);
  const u16x8_t ub = __builtin_bit_cast(u16x8_t, b);
  bf16x8_t r;
#pragma unroll
  for (int s = 0; s < 8; ++s) {
    const float fa = __uint_as_float(((unsigned int)ua[s]) << 16);
    const float fb = __uint_as_float(((unsigned int)ub[s]) << 16);
    r[s] = (__bf16)fabsf(fa - fb);
  }
  return r;
}

// ---------------------------------------------------------------------------
// P2/P3 gen_x split (8x8 tile): LOAD (3 bf16x8 global) / STORE (cvt + 2 LDS).
// ---------------------------------------------------------------------------
struct XLoad { bf16x8_t iv0, iv1, jv; };

__device__ __forceinline__ XLoad gen_x_load(const __bf16* __restrict__ featb,
                                            int i0, int j0, int q0, int c8)
{
  XLoad r;
  const __bf16* gi = featb + (i0 + (q0 >> 3)) * 128 + c8;
  r.iv0 = *(const bf16x8_t*)gi;
  r.iv1 = *(const bf16x8_t*)(gi + 512);
  r.jv  = *(const bf16x8_t*)(featb + (j0 + (q0 & 7)) * 128 + c8);
  return r;
}

__device__ __forceinline__ void gen_x_store(const XLoad& x, unsigned char* __restrict__ Xdst,
                                            int xw)
{
  *(bf16x8_t*)(Xdst + xw) = absdiff8(x.iv0, x.jv);
  *(bf16x8_t*)(Xdst + xw + 8192) = absdiff8(x.iv1, x.jv);
}

// ---------------------------------------------------------------------------
// pipeline primitives (shared by phases)
// ---------------------------------------------------------------------------
#define LD0Q(BUF, KS, HF, QB)                                                  \
  { _Pragma("unroll") for (int h = 0; h < 2; ++h)                              \
      BUF[h] = *(const bf16x8_t*)(Xc + ((xr + (QB) + (HF) * 8192 + h * 4096 + (KS) * 64) ^ swz)); }
#define MM0(BUF, KS, HF)                                                       \
  { _Pragma("unroll") for (int ot = 0; ot < 2; ++ot)                           \
      _Pragma("unroll") for (int h = 0; h < 2; ++h)                            \
        acc0[ot][(HF) * 2 + h] = __builtin_amdgcn_mfma_f32_16x16x32_bf16(      \
            W0f[ot][(KS)], BUF[h], acc0[ot][(HF) * 2 + h], 0, 0, 0); }
#define MM0P(BUF, KS, HF)                                                      \
  { __builtin_amdgcn_s_setprio(1); MM0(BUF, KS, HF); __builtin_amdgcn_s_setprio(0); }

#define LD1(BUF, KS, HF)                                                       \
  { _Pragma("unroll") for (int h = 0; h < 2; ++h)                              \
      BUF[h] = *(const bf16x8_t*)(Ab + ((ar + (HF) * 16384 + h * 8192 + (KS) * 64) ^ swz)); }
#define MM1(BUF, KS, HF)                                                       \
  { _Pragma("unroll") for (int h = 0; h < 2; ++h)                              \
      acc1[(HF) * 2 + h] = __builtin_amdgcn_mfma_f32_16x16x32_bf16(            \
          W1f[(KS)], BUF[h], acc1[(HF) * 2 + h], 0, 0, 0); }
#define MM1P(BUF, KS, HF)                                                      \
  { __builtin_amdgcn_s_setprio(1); MM1(BUF, KS, HF); __builtin_amdgcn_s_setprio(0); }

// one full L0 ping-pong pass over 4 qt-tiles at X base QB
#define L0CHUNK(QB)                                                            \
  {                                                                            \
    bf16x8_t BP[2], BQ[2];                                                     \
    LD0Q(BP, 0, 0, QB);                                                        \
    LD0Q(BQ, 0, 1, QB); SBAR; MM0P(BP, 0, 0); SBAR;                            \
    LD0Q(BP, 1, 0, QB); SBAR; MM0P(BQ, 0, 1); SBAR;                            \
    LD0Q(BQ, 1, 1, QB); SBAR; MM0P(BP, 1, 0); SBAR;                            \
    LD0Q(BP, 2, 0, QB); SBAR; MM0P(BQ, 1, 1); SBAR;                            \
    LD0Q(BQ, 2, 1, QB); SBAR; MM0P(BP, 2, 0); SBAR;                            \
    LD0Q(BP, 3, 0, QB); SBAR; MM0P(BQ, 2, 1); SBAR;                            \
    LD0Q(BQ, 3, 1, QB); SBAR; MM0P(BP, 3, 0); SBAR;                            \
    MM0P(BQ, 3, 1);                                                            \
  }

// ---------------------------------------------------------------------------
// PHASE 1 kernel: 8x16 tile (128 pairs), z0 stats only.
// q = i_loc*16 + j_loc; X[128][128] bf16, double-buffered.
// L0 in two chunks of 4 qt (acc0 stays 32 regs; stats folded per chunk).
// ---------------------------------------------------------------------------
__global__ void
__attribute__((amdgpu_flat_work_group_size(512, 512)))
pair_phase1_kernel(const __bf16* __restrict__ featb,
                   const __bf16* __restrict__ W0b,
                   float* __restrict__ stats)
{
  __shared__ __align__(16) unsigned char smem[L_TOT];
  float* sb = (float*)(smem + L_SB);

  const int tid = (int)threadIdx.x;
  const int wid = tid >> 6;
  const int lane = tid & 63;
  const int lr = lane & 15;
  const int g = lane >> 4;

  bf16x8_t W0f[2][4];
#pragma unroll
  for (int ot = 0; ot < 2; ++ot)
#pragma unroll
    for (int ks = 0; ks < 4; ++ks)
      W0f[ot][ks] = *(const bf16x8_t*)(W0b + (wid * 32 + ot * 16 + lr) * 128 + ks * 32 + g * 8);

  const int swz = (lr & 7) << 4;
  const int xr = (lr << 8) + (g << 4);
  const int c8 = (tid & 15) * 8;
  const int jl = (tid >> 4) & 15;      // j_loc (constant per thread)
  const int ib = tid >> 8;             // i base (0 or 1); i_loc = ib + it*2
  const int xw0 = (((tid >> 4) << 8) + ((tid & 15) << 4)) ^ (((tid >> 4) & 7) << 4);

  float s1[2][4], s2v[2][4];
#pragma unroll
  for (int ot = 0; ot < 2; ++ot)
#pragma unroll
    for (int r2 = 0; r2 < 4; ++r2) { s1[ot][r2] = 0.f; s2v[ot][r2] = 0.f; }

  // prologue: X for first tile -> buf0
  {
    const int t0 = (int)blockIdx.x;
    const int ti = t0 / NBJ1;
    const int i0 = ti * 8, j0 = (t0 - ti * NBJ1) * 16;
    const bf16x8_t jv = *(const bf16x8_t*)(featb + (j0 + jl) * 128 + c8);
#pragma unroll
    for (int it = 0; it < 4; ++it) {
      const bf16x8_t iv = *(const bf16x8_t*)(featb + (i0 + ib + it * 2) * 128 + c8);
      *(bf16x8_t*)(smem + L_X0 + xw0 + it * 8192) = absdiff8(iv, jv);
    }
  }
  int bufc = 0;

  for (int tile = (int)blockIdx.x; tile < NTILES1; tile += (int)gridDim.x) {
    __syncthreads();   // B1: X[cur] visible; prev-tile reads done

    const int nxt = tile + (int)gridDim.x;
    const bool hn = (nxt < NTILES1);
    bf16x8_t jvn{}, ivA0{}, ivA1{};
    int ni0 = 0, nj0 = 0;
    if (hn) {
      const int nti = nxt / NBJ1;
      ni0 = nti * 8; nj0 = (nxt - nti * NBJ1) * 16;
      jvn  = *(const bf16x8_t*)(featb + (nj0 + jl) * 128 + c8);
      ivA0 = *(const bf16x8_t*)(featb + (ni0 + ib + 0) * 128 + c8);
      ivA1 = *(const bf16x8_t*)(featb + (ni0 + ib + 2) * 128 + c8);
    }
    unsigned char* Xc = smem + (bufc ? L_X1P : L_X0);
    unsigned char* Xa = smem + (bufc ? L_X0 : L_X1P);
    bufc ^= 1;

    // ---- chunk 0: q in [0,64) ----
    f32x4_t acc0[2][4];
#pragma unroll
    for (int ot = 0; ot < 2; ++ot)
#pragma unroll
      for (int qt = 0; qt < 4; ++qt) acc0[ot][qt] = f32x4_t{0.f, 0.f, 0.f, 0.f};
    L0CHUNK(0);
#pragma unroll
    for (int ot = 0; ot < 2; ++ot)
#pragma unroll
      for (int qt = 0; qt < 4; ++qt)
#pragma unroll
        for (int r2 = 0; r2 < 4; ++r2) {
          const float z = acc0[ot][qt][r2];
          s1[ot][r2] += z; s2v[ot][r2] += z * z;
        }

    // mid: store prefetch group A (items 0,1), issue group B loads (items 2,3)
    if (hn) {
      *(bf16x8_t*)(Xa + xw0) = absdiff8(ivA0, jvn);
      *(bf16x8_t*)(Xa + xw0 + 8192) = absdiff8(ivA1, jvn);
      ivA0 = *(const bf16x8_t*)(featb + (ni0 + ib + 4) * 128 + c8);
      ivA1 = *(const bf16x8_t*)(featb + (ni0 + ib + 6) * 128 + c8);
    }

    // ---- chunk 1: q in [64,128) ----
#pragma unroll
    for (int ot = 0; ot < 2; ++ot)
#pragma unroll
      for (int qt = 0; qt < 4; ++qt) acc0[ot][qt] = f32x4_t{0.f, 0.f, 0.f, 0.f};
    L0CHUNK(16384);
#pragma unroll
    for (int ot = 0; ot < 2; ++ot)
#pragma unroll
      for (int qt = 0; qt < 4; ++qt)
#pragma unroll
        for (int r2 = 0; r2 < 4; ++r2) {
          const float z = acc0[ot][qt][r2];
          s1[ot][r2] += z; s2v[ot][r2] += z * z;
        }

    if (hn) {
      *(bf16x8_t*)(Xa + xw0 + 16384) = absdiff8(ivA0, jvn);
      *(bf16x8_t*)(Xa + xw0 + 24576) = absdiff8(ivA1, jvn);
    }
  }

  // ---- stats flush ----
#pragma unroll
  for (int ot = 0; ot < 2; ++ot)
#pragma unroll
    for (int r2 = 0; r2 < 4; ++r2) {
      float v1 = s1[ot][r2], v2 = s2v[ot][r2];
#pragma unroll
      for (int m = 1; m < 16; m <<= 1) {
        v1 += __shfl_xor(v1, m, 64);
        v2 += __shfl_xor(v2, m, 64);
      }
      s1[ot][r2] = v1; s2v[ot][r2] = v2;
    }
  __syncthreads();
  if (lr == 0) {
#pragma unroll
    for (int ot = 0; ot < 2; ++ot)
#pragma unroll
      for (int r2 = 0; r2 < 4; ++r2) {
        const int o = wid * 32 + ot * 16 + g * 4 + r2;
        sb[o] = s1[ot][r2];
        sb[256 + o] = s2v[ot][r2];
      }
  }
  __syncthreads();
  atomicAdd(stats + tid, sb[tid]);
}

// ---------------------------------------------------------------------------
// PHASE 2/3 kernel: 8x8 tile, full chain. (unchanged from R11 + setprio)
// ---------------------------------------------------------------------------
template<int PHASE>
__global__ void
__attribute__((amdgpu_flat_work_group_size(512, 512)))
pair_phase_kernel(const __bf16* __restrict__ featb,
                  const __bf16* __restrict__ W0b,
                  const __bf16* __restrict__ W1b,
                  const float* __restrict__ wout,
                  const float* __restrict__ boutp,
                  const float* __restrict__ sh0,
                  const float* __restrict__ sh1,
                  float* __restrict__ stats,
                  float* __restrict__ sim)
{
  __shared__ __align__(16) unsigned char smem[L_TOT];
  unsigned char* Ab = smem + L_A0;
  float* sb = (float*)(smem + L_SB);

  const int tid = (int)threadIdx.x;
  const int wid = tid >> 6;
  const int lane = tid & 63;
  const int lr = lane & 15;
  const int g = lane >> 4;

  bf16x8_t W0f[2][4];
#pragma unroll
  for (int ot = 0; ot < 2; ++ot)
#pragma unroll
    for (int ks = 0; ks < 4; ++ks)
      W0f[ot][ks] = *(const bf16x8_t*)(W0b + (wid * 32 + ot * 16 + lr) * 128 + ks * 32 + g * 8);

  bf16x8_t W1f[8];
#pragma unroll
  for (int ks = 0; ks < 8; ++ks)
    W1f[ks] = *(const bf16x8_t*)(W1b + (wid * 16 + lr) * 256 + ks * 32 + g * 8);

  f32x4_t sh0v[2];
#pragma unroll
  for (int ot = 0; ot < 2; ++ot)
    sh0v[ot] = *(const f32x4_t*)(sh0 + wid * 32 + ot * 16 + g * 4);

  float bout = 0.f;
  if constexpr (PHASE == 3) bout = boutp[0];

  const int swz = (lr & 7) << 4;
  const int xr = (lr << 8) + (g << 4);
  const int ar = (lr << 9) + (g << 4);
  const int aw = (lr << 9) + wid * 64 + g * 8;
  const int q0 = tid >> 4;
  const int c8 = (tid & 15) * 8;
  const int xw = (((q0 << 8) + ((tid & 15) << 4)) ^ ((q0 & 7) << 4));

  float t1[4], t2v[4];
  if constexpr (PHASE == 2) {
#pragma unroll
    for (int r2 = 0; r2 < 4; ++r2) { t1[r2] = 0.f; t2v[r2] = 0.f; }
  }

  {
    const int t0 = (int)blockIdx.x;
    const int ti = t0 / NBJ;
    XLoad xl = gen_x_load(featb, ti * 8, (t0 - ti * NBJ) * 8, q0, c8);
    gen_x_store(xl, smem + L_X0, xw);
  }
  int bufc = 0;
  int pi0 = -1, pj0 = -1;

  for (int tile = (int)blockIdx.x; tile < NTILES; tile += (int)gridDim.x) {
    const int ti = tile / NBJ;
    const int i0 = ti * 8;
    const int j0 = (tile - ti * NBJ) * 8;

    __syncthreads();   // B1

    if constexpr (PHASE == 3) {
      if (pi0 >= 0 && tid < 64) {
        float sv = bout;
#pragma unroll
        for (int w = 0; w < 8; ++w) sv += sb[w * 64 + tid];
        sim[(pi0 + (tid >> 3)) * N_NODES + pj0 + (tid & 7)] = 1.f / (1.f + expf(-sv));
      }
    }

    const int nxt = tile + (int)gridDim.x;
    const bool hn = (nxt < NTILES);
    XLoad xl;
    if (hn) {
      const int nti = nxt / NBJ;
      xl = gen_x_load(featb, nti * 8, (nxt - nti * NBJ) * 8, q0, c8);
    }
    unsigned char* Xc = smem + (bufc ? L_X1 : L_X0);
    unsigned char* Xa = smem + (bufc ? L_X0 : L_X1);
    bufc ^= 1;

    // ---- layer 0 ----
    f32x4_t acc0[2][4];
#pragma unroll
    for (int ot = 0; ot < 2; ++ot)
#pragma unroll
      for (int qt = 0; qt < 4; ++qt) acc0[ot][qt] = f32x4_t{0.f, 0.f, 0.f, 0.f};
    L0CHUNK(0);

    if (hn) gen_x_store(xl, Xa, xw);

    // a0 = lrelu(z0' + sh0)
#pragma unroll
    for (int ot = 0; ot < 2; ++ot) {
#pragma unroll
      for (int qt = 0; qt < 4; ++qt) {
        bf16x4_t pk;
#pragma unroll
        for (int r2 = 0; r2 < 4; ++r2) {
          const float z = acc0[ot][qt][r2] + sh0v[ot][r2];
          pk[r2] = (__bf16)fmaxf(z, 0.01f * z);
        }
        *(bf16x4_t*)(Ab + ((aw + ot * 32 + qt * 8192) ^ swz)) = pk;
      }
    }
    __syncthreads();   // B2

    f32x4_t sh1v{}, wv{};
    if constexpr (PHASE == 3) {
      sh1v = *(const f32x4_t*)(sh1 + wid * 16 + g * 4);
      wv = *(const f32x4_t*)(wout + wid * 16 + g * 4);
    }

    // ---- layer 1 ----
    f32x4_t acc1[4];
#pragma unroll
    for (int qt = 0; qt < 4; ++qt) acc1[qt] = f32x4_t{0.f, 0.f, 0.f, 0.f};
    {
      bf16x8_t CP[2], CQ[2];
      LD1(CP, 0, 0);
      LD1(CQ, 0, 1); SBAR; MM1P(CP, 0, 0); SBAR;
      LD1(CP, 1, 0); SBAR; MM1P(CQ, 0, 1); SBAR;
      LD1(CQ, 1, 1); SBAR; MM1P(CP, 1, 0); SBAR;
      LD1(CP, 2, 0); SBAR; MM1P(CQ, 1, 1); SBAR;
      LD1(CQ, 2, 1); SBAR; MM1P(CP, 2, 0); SBAR;
      LD1(CP, 3, 0); SBAR; MM1P(CQ, 2, 1); SBAR;
      LD1(CQ, 3, 1); SBAR; MM1P(CP, 3, 0); SBAR;
      LD1(CP, 4, 0); SBAR; MM1P(CQ, 3, 1); SBAR;
      LD1(CQ, 4, 1); SBAR; MM1P(CP, 4, 0); SBAR;
      LD1(CP, 5, 0); SBAR; MM1P(CQ, 4, 1); SBAR;
      LD1(CQ, 5, 1); SBAR; MM1P(CP, 5, 0); SBAR;
      LD1(CP, 6, 0); SBAR; MM1P(CQ, 5, 1); SBAR;
      LD1(CQ, 6, 1); SBAR; MM1P(CP, 6, 0); SBAR;
      LD1(CP, 7, 0); SBAR; MM1P(CQ, 6, 1); SBAR;
      LD1(CQ, 7, 1); SBAR; MM1P(CP, 7, 0); SBAR;
      MM1P(CQ, 7, 1);
    }

    if constexpr (PHASE == 2) {
#pragma unroll
      for (int qt = 0; qt < 4; ++qt)
#pragma unroll
        for (int r2 = 0; r2 < 4; ++r2) {
          const float z = acc1[qt][r2];
          t1[r2] += z;
          t2v[r2] += z * z;
        }
    } else {
      float part[4];
#pragma unroll
      for (int qt = 0; qt < 4; ++qt) {
        part[qt] = 0.f;
#pragma unroll
        for (int r2 = 0; r2 < 4; ++r2) {
          const float z = acc1[qt][r2] + sh1v[r2];
          part[qt] += wv[r2] * fmaxf(z, 0.01f * z);
        }
      }
#pragma unroll
      for (int qt = 0; qt < 4; ++qt) {
        part[qt] += __shfl_xor(part[qt], 16, 64);
        part[qt] += __shfl_xor(part[qt], 32, 64);
      }
      if (lane < 16) {
#pragma unroll
        for (int qt = 0; qt < 4; ++qt)
          sb[wid * 64 + qt * 16 + lr] = part[qt];
      }
      pi0 = i0; pj0 = j0;
    }
  }

  if constexpr (PHASE == 3) {
    __syncthreads();
    if (tid < 64) {
      float sv = bout;
#pragma unroll
      for (int w = 0; w < 8; ++w) sv += sb[w * 64 + tid];
      sim[(pi0 + (tid >> 3)) * N_NODES + pj0 + (tid & 7)] = 1.f / (1.f + expf(-sv));
    }
  }

  if constexpr (PHASE == 2) {
#pragma unroll
    for (int r2 = 0; r2 < 4; ++r2) {
      float v1 = t1[r2], v2 = t2v[r2];
#pragma unroll
      for (int m = 1; m < 16; m <<= 1) {
        v1 += __shfl_xor(v1, m, 64);
        v2 += __shfl_xor(v2, m, 64);
      }
      t1[r2] = v1; t2v[r2] = v2;
    }
    __syncthreads();
    if (lr == 0) {
#pragma unroll
      for (int r2 = 0; r2 < 4; ++r2) {
        const int p = wid * 16 + g * 4 + r2;
        sb[p] = t1[r2];
        sb[128 + p] = t2v[r2];
      }
    }
    __syncthreads();
    if (tid < 256) atomicAdd(stats + tid, sb[tid]);
  }
}

// ---------------------------------------------------------------------------
// finalize: mean/var -> per-channel scale/shift for BN(+gamma,beta)
// ---------------------------------------------------------------------------
__global__ void finalize_kernel(const float* __restrict__ ssum, const float* __restrict__ ssq,
                                const float* __restrict__ gamma, const float* __restrict__ beta,
                                float* __restrict__ sc, float* __restrict__ sh, int n)
{
  const int i = (int)(blockIdx.x * blockDim.x + threadIdx.x);
  if (i < n) {
    const float invN = 1.f / 589824.f;
    const float m = ssum[i] * invN;
    const float var = ssq[i] * invN - m * m;
    const float is = rsqrtf(var + 1e-5f);
    const float s = gamma[i] * is;
    sc[i] = s;
    sh[i] = beta[i] - m * s;
  }
}

// ---------------------------------------------------------------------------
// edge graph tail (unchanged)
// ---------------------------------------------------------------------------
__global__ void colsum_kernel(const float* __restrict__ sim, const int* __restrict__ lab,
                              float* __restrict__ colsum)
{
  const int t = (int)threadIdx.x;
  const int bi = (int)blockIdx.x * 8;
  const int lj0 = lab[t], lj1 = lab[t + 256], lj2 = lab[t + 512];
  float a0 = 0.f, a1 = 0.f, a2 = 0.f;
  for (int r = 0; r < 8; ++r) {
    const int i = bi + r;
    const int li = lab[i];
    const float* srow = sim + i * N_NODES;
    a0 += ((li == lj0) ? srow[t] : 0.f) + ((i == t) ? 1.f : 0.f) + 1e-6f;
    a1 += ((li == lj1) ? srow[t + 256] : 0.f) + ((i == t + 256) ? 1.f : 0.f) + 1e-6f;
    a2 += ((li == lj2) ? srow[t + 512] : 0.f) + ((i == t + 512) ? 1.f : 0.f) + 1e-6f;
  }
  atomicAdd(colsum + t, a0);
  atomicAdd(colsum + t + 256, a1);
  atomicAdd(colsum + t + 512, a2);
}

__global__ void aggr_kernel(const float* __restrict__ sim, const int* __restrict__ lab,
                            const float* __restrict__ colsum, const float* __restrict__ feat,
                            float* __restrict__ aggr)
{
  __shared__ float wrow[N_NODES];
  __shared__ float red[128];
  const int i = (int)blockIdx.x, t = (int)threadIdx.x;
  const int li = lab[i];
  const float* srow = sim + i * N_NODES;
  float rs = 0.f;
  for (int s = 0; s < 6; ++s) {
    const int j = t + s * 128;
    const float e = ((li == lab[j]) ? srow[j] : 0.f) + ((i == j) ? 1.f : 0.f) + 1e-6f;
    const float w = (j == i) ? 0.f : e / colsum[j];
    wrow[j] = w;
    rs += w;
  }
  red[t] = rs;
  __syncthreads();
  for (int off = 64; off > 0; off >>= 1) {
    if (t < off) red[t] += red[t + off];
    __syncthreads();
  }
  const float inv = 1.f / fmaxf(red[0], 1e-12f);
  float acc = 0.f;
  for (int j = 0; j < N_NODES; ++j) acc += wrow[j] * feat[j * 128 + t];
  aggr[i * 128 + t] = acc * inv;
}

__global__ void mlp0_kernel(const float* __restrict__ feat, const float* __restrict__ aggr,
                            const float* __restrict__ w, const float* __restrict__ gamma,
                            const float* __restrict__ beta, float* __restrict__ h2)
{
  __shared__ float wr[256];
  __shared__ float redA[256], redB[256];
  const int r = (int)blockIdx.x, t = (int)threadIdx.x;
  wr[t] = w[r * 256 + t];
  __syncthreads();
  float v[3];
#pragma unroll
  for (int s = 0; s < 3; ++s) {
    const int n = t + s * 256;
    const float* fr = feat + n * 128;
    const float* ar = aggr + n * 128;
    float acc = 0.f;
#pragma unroll 4
    for (int c = 0; c < 128; c += 4) {
      const f32x4_t fv = *(const f32x4_t*)(fr + c);
      acc += wr[c] * fv[0] + wr[c + 1] * fv[1] + wr[c + 2] * fv[2] + wr[c + 3] * fv[3];
    }
#pragma unroll 4
    for (int c = 0; c < 128; c += 4) {
      const f32x4_t av = *(const f32x4_t*)(ar + c);
      acc += wr[128 + c] * av[0] + wr[129 + c] * av[1] + wr[130 + c] * av[2] + wr[131 + c] * av[3];
    }
    v[s] = acc;
  }
  redA[t] = v[0] + v[1] + v[2];
  redB[t] = v[0] * v[0] + v[1] * v[1] + v[2] * v[2];
  __syncthreads();
  for (int off = 128; off > 0; off >>= 1) {
    if (t < off) { redA[t] += redA[t + off]; redB[t] += redB[t + off]; }
    __syncthreads();
  }
  const float m = redA[0] * (1.f / 768.f);
  const float var = redB[0] * (1.f / 768.f) - m * m;
  const float is = rsqrtf(var + 1e-5f);
  const float sc = gamma[r] * is;
  const float sh = beta[r] - m * sc;
#pragma unroll
  for (int s = 0; s < 3; ++s) {
    float y = v[s] * sc + sh;
    y = (y >= 0.f) ? y : 0.01f * y;
    h2[r * 768 + t + s * 256] = y;
  }
}

__global__ void mlp1_kernel(const float* __restrict__ h2, const float* __restrict__ w,
                            const float* __restrict__ gamma, const float* __restrict__ beta,
                            float* __restrict__ logits)
{
  __shared__ float wr[130];
  __shared__ float redA[256], redB[256];
  const int r = (int)blockIdx.x, t = (int)threadIdx.x;
  if (t < 130) wr[t] = w[r * 130 + t];
  __syncthreads();
  float v[3];
#pragma unroll
  for (int s = 0; s < 3; ++s) {
    const int n = t + s * 256;
    float acc = 0.f;
    for (int c = 0; c < 130; ++c) acc += wr[c] * h2[c * 768 + n];
    v[s] = acc;
  }
  redA[t] = v[0] + v[1] + v[2];
  redB[t] = v[0] * v[0] + v[1] * v[1] + v[2] * v[2];
  __syncthreads();
  for (int off = 128; off > 0; off >>= 1) {
    if (t < off) { redA[t] += redA[t + off]; redB[t] += redB[t + off]; }
    __syncthreads();
  }
  const float m = redA[0] * (1.f / 768.f);
  const float var = redB[0] * (1.f / 768.f) - m * m;
  const float is = rsqrtf(var + 1e-5f);
  const float sc = gamma[r] * is;
  const float sh = beta[r] - m * sc;
#pragma unroll
  for (int s = 0; s < 3; ++s) {
    const float y = v[s] * sc + sh;
    logits[(t + s * 256) * 65 + r] = y;
  }
}

// ---------------------------------------------------------------------------
extern "C" void kernel_launch(void* const* d_in, const int* in_sizes, int n_in,
                              void* d_out, int out_size, void* d_ws, size_t ws_size,
                              hipStream_t stream)
{
  (void)in_sizes; (void)n_in; (void)out_size; (void)ws_size;
  const float* feat   = (const float*)d_in[0];
  const int*   lab    = (const int*)d_in[1];
  const float* e_w0   = (const float*)d_in[2];
  const float* e_g0   = (const float*)d_in[3];
  const float* e_b0   = (const float*)d_in[4];
  const float* e_w1   = (const float*)d_in[5];
  const float* e_g1   = (const float*)d_in[6];
  const float* e_b1   = (const float*)d_in[7];
  const float* e_wout = (const float*)d_in[8];
  const float* e_bout = (const float*)d_in[9];
  const float* n_w0   = (const float*)d_in[10];
  const float* n_g0   = (const float*)d_in[11];
  const float* n_b0   = (const float*)d_in[12];
  const float* n_w1   = (const float*)d_in[13];
  const float* n_g1   = (const float*)d_in[14];
  const float* n_b1   = (const float*)d_in[15];

  float* out = (float*)d_out;
  float* logits = out;                 // 768*65
  float* sim = out + 768 * 65;         // 768*768

  // workspace layout (floats)
  float* wsf = (float*)d_ws;
  float* S0A = wsf + 0;      // 256 sums + 256 sumsq
  float* S0B = wsf + 256;
  float* S1A = wsf + 512;    // 128 + 128
  float* S1B = wsf + 640;
  float* colsum = wsf + 768; // 768
  float* sc0 = wsf + 1536;   // 256
  float* sh0 = wsf + 1792;   // 256
  float* sc1 = wsf + 2048;   // 128
  float* sh1 = wsf + 2176;   // 128
  float* aggr = wsf + 2304;            // 768*128 (tail only)
  float* h2 = wsf + 2304 + 768 * 128;  // 130*768
  // featb aliases aggr's region (aggr written only after phase 3)
  __bf16* featb = (__bf16*)(wsf + 2304);            // 98304 bf16 (192KB)
  __bf16* W0bf = (__bf16*)(wsf + 200448);           // 32768 bf16
  __bf16* W1bf = (__bf16*)(wsf + 216832);
  __bf16* W0s  = (__bf16*)(wsf + 233216);           // sc0-folded
  __bf16* W1s  = (__bf16*)(wsf + 249600);           // sc1-folded

  hipMemsetAsync(d_ws, 0, 2304 * sizeof(float), stream);

  prep_kernel<<<384, 256, 0, stream>>>(feat, e_w0, e_w1, featb, W0bf, W1bf);

  pair_phase1_kernel<<<2304, 512, 0, stream>>>(featb, W0bf, S0A);
  finalize_kernel<<<1, 256, 0, stream>>>(S0A, S0B, e_g0, e_b0, sc0, sh0, 256);
  wscale_kernel<<<128, 256, 0, stream>>>(e_w0, sc0, W0s, 128, 32768);
  pair_phase_kernel<2><<<2304, 512, 0, stream>>>(featb, W0s, W1bf, nullptr, nullptr,
                                                 sh0, nullptr, S1A, nullptr);
  finalize_kernel<<<1, 128, 0, stream>>>(S1A, S1B, e_g1, e_b1, sc1, sh1, 128);
  wscale_kernel<<<128, 256, 0, stream>>>(e_w1, sc1, W1s, 256, 32768);
  pair_phase_kernel<3><<<2304, 512, 0, stream>>>(featb, W0s, W1s, e_wout, e_bout,
                                                 sh0, sh1, nullptr, sim);
  colsum_kernel<<<96, 256, 0, stream>>>(sim, lab, colsum);
  aggr_kernel<<<768, 128, 0, stream>>>(sim, lab, colsum, feat, aggr);
  mlp0_kernel<<<130, 256, 0, stream>>>(feat, aggr, n_w0, n_g0, n_b0, h2);
  mlp1_kernel<<<65, 256, 0, stream>>>(h2, n_w1, n_g1, n_b1, logits);
}

// Round 13
// 319.227 us; speedup vs baseline: 2.1985x; 1.2587x over previous
//
#include <hip/hip_runtime.h>
#include <cmath>

// ---------------------------------------------------------------------------
// ClassifierGNN: N=768 nodes, D=128 feat, edge-MLP channels 256->128->1,
// node-MLP 256->130->65.
// 3 recompute phases (stats0, stats1, sim) using bf16 MFMA 16x16x32.
// R12 -> R13: persistent blocks + invariant hoisting.
//   - grid 2304 -> 512 (exactly 2 blocks/CU resident): per-block fixed costs
//     (16 scattered weight-frag L2 loads, prologue gen_x stall, ramp/drain)
//     paid once per residency slot instead of 4.5x. 18 tiles/block (P1: 9).
//   - P3's sh1v/wv were reloaded from global EVERY tile -> hoisted to
//     persistent registers (+8 VGPR, ~124 <= 128 budget).
// ---------------------------------------------------------------------------

#define N_NODES 768
#define NBJ 96          // P2/P3: j-tiles per row (768/8)
#define NTILES 9216     // P2/P3: (768/8)*(768/8)
#define NBJ1 48         // P1: j-tiles per row (768/16)
#define NTILES1 4608    // P1: (768/8)*(768/16)
#define PAIR_GRID 512   // persistent: 2 blocks/CU on 256 CUs

// LDS layout (bytes): total 67584 -> 2 blocks/CU (=> 128-reg budget).
// P2/P3: X dbuf 2x16K @0, A0 32K @32768, sb @65536
// P1:    X dbuf 2x32K @0,                sb @65536
#define L_X0   0
#define L_X1   16384
#define L_A0   32768
#define L_X1P  32768    // P1's second X buffer
#define L_SB   65536
#define L_TOT  67584

static_assert(L_TOT > 53760 && L_TOT <= 81920, "want exactly 2 blocks/CU");

typedef __bf16 bf16x8_t __attribute__((ext_vector_type(8)));
typedef __bf16 bf16x4_t __attribute__((ext_vector_type(4)));
typedef unsigned short u16x8_t __attribute__((ext_vector_type(8)));
typedef float f32x4_t __attribute__((ext_vector_type(4)));

#define SBAR __builtin_amdgcn_sched_barrier(0)

// ---------------------------------------------------------------------------
// prep: cast feat (98304) and W0/W1 (32768 each) to bf16.
// ---------------------------------------------------------------------------
__global__ void prep_kernel(const float* __restrict__ feat,
                            const float* __restrict__ w0, const float* __restrict__ w1,
                            __bf16* __restrict__ featb,
                            __bf16* __restrict__ w0b, __bf16* __restrict__ w1b)
{
  const int i = (int)(blockIdx.x * 256 + threadIdx.x);
  if (i < 98304) featb[i] = (__bf16)feat[i];
  if (i < 32768) { w0b[i] = (__bf16)w0[i]; w1b[i] = (__bf16)w1[i]; }
}

// wscale: dst[i] = bf16(w[i] * sc[i/cols])  (fold BN scale into weight rows)
__global__ void wscale_kernel(const float* __restrict__ w, const float* __restrict__ sc,
                              __bf16* __restrict__ dst, int cols, int n)
{
  const int i = (int)(blockIdx.x * 256 + threadIdx.x);
  if (i < n) dst[i] = (__bf16)(w[i] * sc[i / cols]);
}

// ---------------------------------------------------------------------------
// abs-diff of 8 bf16 lanes via f32 (cvt_pk on the way back)
// ---------------------------------------------------------------------------
__device__ __forceinline__ bf16x8_t absdiff8(bf16x8_t a, bf16x8_t b)
{
  const u16x8_t ua = __builtin_bit_cast(u16x8_t, a);
  const u16x8_t ub = __builtin_bit_cast(u16x8_t, b);
  bf16x8_t r;
#pragma unroll
  for (int s = 0; s < 8; ++s) {
    const float fa = __uint_as_float(((unsigned int)ua[s]) << 16);
    const float fb = __uint_as_float(((unsigned int)ub[s]) << 16);
    r[s] = (__bf16)fabsf(fa - fb);
  }
  return r;
}

// ---------------------------------------------------------------------------
// P2/P3 gen_x split (8x8 tile): LOAD (3 bf16x8 global) / STORE (cvt + 2 LDS).
// ---------------------------------------------------------------------------
struct XLoad { bf16x8_t iv0, iv1, jv; };

__device__ __forceinline__ XLoad gen_x_load(const __bf16* __restrict__ featb,
                                            int i0, int j0, int q0, int c8)
{
  XLoad r;
  const __bf16* gi = featb + (i0 + (q0 >> 3)) * 128 + c8;
  r.iv0 = *(const bf16x8_t*)gi;
  r.iv1 = *(const bf16x8_t*)(gi + 512);
  r.jv  = *(const bf16x8_t*)(featb + (j0 + (q0 & 7)) * 128 + c8);
  return r;
}

__device__ __forceinline__ void gen_x_store(const XLoad& x, unsigned char* __restrict__ Xdst,
                                            int xw)
{
  *(bf16x8_t*)(Xdst + xw) = absdiff8(x.iv0, x.jv);
  *(bf16x8_t*)(Xdst + xw + 8192) = absdiff8(x.iv1, x.jv);
}

// ---------------------------------------------------------------------------
// pipeline primitives (shared by phases)
// ---------------------------------------------------------------------------
#define LD0Q(BUF, KS, HF, QB)                                                  \
  { _Pragma("unroll") for (int h = 0; h < 2; ++h)                              \
      BUF[h] = *(const bf16x8_t*)(Xc + ((xr + (QB) + (HF) * 8192 + h * 4096 + (KS) * 64) ^ swz)); }
#define MM0(BUF, KS, HF)                                                       \
  { _Pragma("unroll") for (int ot = 0; ot < 2; ++ot)                           \
      _Pragma("unroll") for (int h = 0; h < 2; ++h)                            \
        acc0[ot][(HF) * 2 + h] = __builtin_amdgcn_mfma_f32_16x16x32_bf16(      \
            W0f[ot][(KS)], BUF[h], acc0[ot][(HF) * 2 + h], 0, 0, 0); }
#define MM0P(BUF, KS, HF)                                                      \
  { __builtin_amdgcn_s_setprio(1); MM0(BUF, KS, HF); __builtin_amdgcn_s_setprio(0); }

#define LD1(BUF, KS, HF)                                                       \
  { _Pragma("unroll") for (int h = 0; h < 2; ++h)                              \
      BUF[h] = *(const bf16x8_t*)(Ab + ((ar + (HF) * 16384 + h * 8192 + (KS) * 64) ^ swz)); }
#define MM1(BUF, KS, HF)                                                       \
  { _Pragma("unroll") for (int h = 0; h < 2; ++h)                              \
      acc1[(HF) * 2 + h] = __builtin_amdgcn_mfma_f32_16x16x32_bf16(            \
          W1f[(KS)], BUF[h], acc1[(HF) * 2 + h], 0, 0, 0); }
#define MM1P(BUF, KS, HF)                                                      \
  { __builtin_amdgcn_s_setprio(1); MM1(BUF, KS, HF); __builtin_amdgcn_s_setprio(0); }

// one full L0 ping-pong pass over 4 qt-tiles at X base QB
#define L0CHUNK(QB)                                                            \
  {                                                                            \
    bf16x8_t BP[2], BQ[2];                                                     \
    LD0Q(BP, 0, 0, QB);                                                        \
    LD0Q(BQ, 0, 1, QB); SBAR; MM0P(BP, 0, 0); SBAR;                            \
    LD0Q(BP, 1, 0, QB); SBAR; MM0P(BQ, 0, 1); SBAR;                            \
    LD0Q(BQ, 1, 1, QB); SBAR; MM0P(BP, 1, 0); SBAR;                            \
    LD0Q(BP, 2, 0, QB); SBAR; MM0P(BQ, 1, 1); SBAR;                            \
    LD0Q(BQ, 2, 1, QB); SBAR; MM0P(BP, 2, 0); SBAR;                            \
    LD0Q(BP, 3, 0, QB); SBAR; MM0P(BQ, 2, 1); SBAR;                            \
    LD0Q(BQ, 3, 1, QB); SBAR; MM0P(BP, 3, 0); SBAR;                            \
    MM0P(BQ, 3, 1);                                                            \
  }

// ---------------------------------------------------------------------------
// PHASE 1 kernel: 8x16 tile (128 pairs), z0 stats only.
// q = i_loc*16 + j_loc; X[128][128] bf16, double-buffered.
// L0 in two chunks of 4 qt (acc0 stays 32 regs; stats folded per chunk).
// ---------------------------------------------------------------------------
__global__ void
__attribute__((amdgpu_flat_work_group_size(512, 512)))
pair_phase1_kernel(const __bf16* __restrict__ featb,
                   const __bf16* __restrict__ W0b,
                   float* __restrict__ stats)
{
  __shared__ __align__(16) unsigned char smem[L_TOT];
  float* sb = (float*)(smem + L_SB);

  const int tid = (int)threadIdx.x;
  const int wid = tid >> 6;
  const int lane = tid & 63;
  const int lr = lane & 15;
  const int g = lane >> 4;

  bf16x8_t W0f[2][4];
#pragma unroll
  for (int ot = 0; ot < 2; ++ot)
#pragma unroll
    for (int ks = 0; ks < 4; ++ks)
      W0f[ot][ks] = *(const bf16x8_t*)(W0b + (wid * 32 + ot * 16 + lr) * 128 + ks * 32 + g * 8);

  const int swz = (lr & 7) << 4;
  const int xr = (lr << 8) + (g << 4);
  const int c8 = (tid & 15) * 8;
  const int jl = (tid >> 4) & 15;      // j_loc (constant per thread)
  const int ib = tid >> 8;             // i base (0 or 1); i_loc = ib + it*2
  const int xw0 = (((tid >> 4) << 8) + ((tid & 15) << 4)) ^ (((tid >> 4) & 7) << 4);

  float s1[2][4], s2v[2][4];
#pragma unroll
  for (int ot = 0; ot < 2; ++ot)
#pragma unroll
    for (int r2 = 0; r2 < 4; ++r2) { s1[ot][r2] = 0.f; s2v[ot][r2] = 0.f; }

  // prologue: X for first tile -> buf0
  {
    const int t0 = (int)blockIdx.x;
    const int ti = t0 / NBJ1;
    const int i0 = ti * 8, j0 = (t0 - ti * NBJ1) * 16;
    const bf16x8_t jv = *(const bf16x8_t*)(featb + (j0 + jl) * 128 + c8);
#pragma unroll
    for (int it = 0; it < 4; ++it) {
      const bf16x8_t iv = *(const bf16x8_t*)(featb + (i0 + ib + it * 2) * 128 + c8);
      *(bf16x8_t*)(smem + L_X0 + xw0 + it * 8192) = absdiff8(iv, jv);
    }
  }
  int bufc = 0;

  for (int tile = (int)blockIdx.x; tile < NTILES1; tile += (int)gridDim.x) {
    __syncthreads();   // B1: X[cur] visible; prev-tile reads done

    const int nxt = tile + (int)gridDim.x;
    const bool hn = (nxt < NTILES1);
    bf16x8_t jvn{}, ivA0{}, ivA1{};
    int ni0 = 0, nj0 = 0;
    if (hn) {
      const int nti = nxt / NBJ1;
      ni0 = nti * 8; nj0 = (nxt - nti * NBJ1) * 16;
      jvn  = *(const bf16x8_t*)(featb + (nj0 + jl) * 128 + c8);
      ivA0 = *(const bf16x8_t*)(featb + (ni0 + ib + 0) * 128 + c8);
      ivA1 = *(const bf16x8_t*)(featb + (ni0 + ib + 2) * 128 + c8);
    }
    unsigned char* Xc = smem + (bufc ? L_X1P : L_X0);
    unsigned char* Xa = smem + (bufc ? L_X0 : L_X1P);
    bufc ^= 1;

    // ---- chunk 0: q in [0,64) ----
    f32x4_t acc0[2][4];
#pragma unroll
    for (int ot = 0; ot < 2; ++ot)
#pragma unroll
      for (int qt = 0; qt < 4; ++qt) acc0[ot][qt] = f32x4_t{0.f, 0.f, 0.f, 0.f};
    L0CHUNK(0);
#pragma unroll
    for (int ot = 0; ot < 2; ++ot)
#pragma unroll
      for (int qt = 0; qt < 4; ++qt)
#pragma unroll
        for (int r2 = 0; r2 < 4; ++r2) {
          const float z = acc0[ot][qt][r2];
          s1[ot][r2] += z; s2v[ot][r2] += z * z;
        }

    // mid: store prefetch group A (items 0,1), issue group B loads (items 2,3)
    if (hn) {
      *(bf16x8_t*)(Xa + xw0) = absdiff8(ivA0, jvn);
      *(bf16x8_t*)(Xa + xw0 + 8192) = absdiff8(ivA1, jvn);
      ivA0 = *(const bf16x8_t*)(featb + (ni0 + ib + 4) * 128 + c8);
      ivA1 = *(const bf16x8_t*)(featb + (ni0 + ib + 6) * 128 + c8);
    }

    // ---- chunk 1: q in [64,128) ----
#pragma unroll
    for (int ot = 0; ot < 2; ++ot)
#pragma unroll
      for (int qt = 0; qt < 4; ++qt) acc0[ot][qt] = f32x4_t{0.f, 0.f, 0.f, 0.f};
    L0CHUNK(16384);
#pragma unroll
    for (int ot = 0; ot < 2; ++ot)
#pragma unroll
      for (int qt = 0; qt < 4; ++qt)
#pragma unroll
        for (int r2 = 0; r2 < 4; ++r2) {
          const float z = acc0[ot][qt][r2];
          s1[ot][r2] += z; s2v[ot][r2] += z * z;
        }

    if (hn) {
      *(bf16x8_t*)(Xa + xw0 + 16384) = absdiff8(ivA0, jvn);
      *(bf16x8_t*)(Xa + xw0 + 24576) = absdiff8(ivA1, jvn);
    }
  }

  // ---- stats flush ----
#pragma unroll
  for (int ot = 0; ot < 2; ++ot)
#pragma unroll
    for (int r2 = 0; r2 < 4; ++r2) {
      float v1 = s1[ot][r2], v2 = s2v[ot][r2];
#pragma unroll
      for (int m = 1; m < 16; m <<= 1) {
        v1 += __shfl_xor(v1, m, 64);
        v2 += __shfl_xor(v2, m, 64);
      }
      s1[ot][r2] = v1; s2v[ot][r2] = v2;
    }
  __syncthreads();
  if (lr == 0) {
#pragma unroll
    for (int ot = 0; ot < 2; ++ot)
#pragma unroll
      for (int r2 = 0; r2 < 4; ++r2) {
        const int o = wid * 32 + ot * 16 + g * 4 + r2;
        sb[o] = s1[ot][r2];
        sb[256 + o] = s2v[ot][r2];
      }
  }
  __syncthreads();
  atomicAdd(stats + tid, sb[tid]);
}

// ---------------------------------------------------------------------------
// PHASE 2/3 kernel: 8x8 tile, full chain.
// ---------------------------------------------------------------------------
template<int PHASE>
__global__ void
__attribute__((amdgpu_flat_work_group_size(512, 512)))
pair_phase_kernel(const __bf16* __restrict__ featb,
                  const __bf16* __restrict__ W0b,
                  const __bf16* __restrict__ W1b,
                  const float* __restrict__ wout,
                  const float* __restrict__ boutp,
                  const float* __restrict__ sh0,
                  const float* __restrict__ sh1,
                  float* __restrict__ stats,
                  float* __restrict__ sim)
{
  __shared__ __align__(16) unsigned char smem[L_TOT];
  unsigned char* Ab = smem + L_A0;
  float* sb = (float*)(smem + L_SB);

  const int tid = (int)threadIdx.x;
  const int wid = tid >> 6;
  const int lane = tid & 63;
  const int lr = lane & 15;
  const int g = lane >> 4;

  bf16x8_t W0f[2][4];
#pragma unroll
  for (int ot = 0; ot < 2; ++ot)
#pragma unroll
    for (int ks = 0; ks < 4; ++ks)
      W0f[ot][ks] = *(const bf16x8_t*)(W0b + (wid * 32 + ot * 16 + lr) * 128 + ks * 32 + g * 8);

  bf16x8_t W1f[8];
#pragma unroll
  for (int ks = 0; ks < 8; ++ks)
    W1f[ks] = *(const bf16x8_t*)(W1b + (wid * 16 + lr) * 256 + ks * 32 + g * 8);

  f32x4_t sh0v[2];
#pragma unroll
  for (int ot = 0; ot < 2; ++ot)
    sh0v[ot] = *(const f32x4_t*)(sh0 + wid * 32 + ot * 16 + g * 4);

  // P3 loop-invariants hoisted to persistent registers (were reloaded/tile)
  float bout = 0.f;
  f32x4_t sh1v{}, wv{};
  if constexpr (PHASE == 3) {
    bout = boutp[0];
    sh1v = *(const f32x4_t*)(sh1 + wid * 16 + g * 4);
    wv = *(const f32x4_t*)(wout + wid * 16 + g * 4);
  }

  const int swz = (lr & 7) << 4;
  const int xr = (lr << 8) + (g << 4);
  const int ar = (lr << 9) + (g << 4);
  const int aw = (lr << 9) + wid * 64 + g * 8;
  const int q0 = tid >> 4;
  const int c8 = (tid & 15) * 8;
  const int xw = (((q0 << 8) + ((tid & 15) << 4)) ^ ((q0 & 7) << 4));

  float t1[4], t2v[4];
  if constexpr (PHASE == 2) {
#pragma unroll
    for (int r2 = 0; r2 < 4; ++r2) { t1[r2] = 0.f; t2v[r2] = 0.f; }
  }

  {
    const int t0 = (int)blockIdx.x;
    const int ti = t0 / NBJ;
    XLoad xl = gen_x_load(featb, ti * 8, (t0 - ti * NBJ) * 8, q0, c8);
    gen_x_store(xl, smem + L_X0, xw);
  }
  int bufc = 0;
  int pi0 = -1, pj0 = -1;

  for (int tile = (int)blockIdx.x; tile < NTILES; tile += (int)gridDim.x) {
    const int ti = tile / NBJ;
    const int i0 = ti * 8;
    const int j0 = (tile - ti * NBJ) * 8;

    __syncthreads();   // B1

    if constexpr (PHASE == 3) {
      if (pi0 >= 0 && tid < 64) {
        float sv = bout;
#pragma unroll
        for (int w = 0; w < 8; ++w) sv += sb[w * 64 + tid];
        sim[(pi0 + (tid >> 3)) * N_NODES + pj0 + (tid & 7)] = 1.f / (1.f + expf(-sv));
      }
    }

    const int nxt = tile + (int)gridDim.x;
    const bool hn = (nxt < NTILES);
    XLoad xl;
    if (hn) {
      const int nti = nxt / NBJ;
      xl = gen_x_load(featb, nti * 8, (nxt - nti * NBJ) * 8, q0, c8);
    }
    unsigned char* Xc = smem + (bufc ? L_X1 : L_X0);
    unsigned char* Xa = smem + (bufc ? L_X0 : L_X1);
    bufc ^= 1;

    // ---- layer 0 ----
    f32x4_t acc0[2][4];
#pragma unroll
    for (int ot = 0; ot < 2; ++ot)
#pragma unroll
      for (int qt = 0; qt < 4; ++qt) acc0[ot][qt] = f32x4_t{0.f, 0.f, 0.f, 0.f};
    L0CHUNK(0);

    if (hn) gen_x_store(xl, Xa, xw);

    // a0 = lrelu(z0' + sh0)
#pragma unroll
    for (int ot = 0; ot < 2; ++ot) {
#pragma unroll
      for (int qt = 0; qt < 4; ++qt) {
        bf16x4_t pk;
#pragma unroll
        for (int r2 = 0; r2 < 4; ++r2) {
          const float z = acc0[ot][qt][r2] + sh0v[ot][r2];
          pk[r2] = (__bf16)fmaxf(z, 0.01f * z);
        }
        *(bf16x4_t*)(Ab + ((aw + ot * 32 + qt * 8192) ^ swz)) = pk;
      }
    }
    __syncthreads();   // B2

    // ---- layer 1 ----
    f32x4_t acc1[4];
#pragma unroll
    for (int qt = 0; qt < 4; ++qt) acc1[qt] = f32x4_t{0.f, 0.f, 0.f, 0.f};
    {
      bf16x8_t CP[2], CQ[2];
      LD1(CP, 0, 0);
      LD1(CQ, 0, 1); SBAR; MM1P(CP, 0, 0); SBAR;
      LD1(CP, 1, 0); SBAR; MM1P(CQ, 0, 1); SBAR;
      LD1(CQ, 1, 1); SBAR; MM1P(CP, 1, 0); SBAR;
      LD1(CP, 2, 0); SBAR; MM1P(CQ, 1, 1); SBAR;
      LD1(CQ, 2, 1); SBAR; MM1P(CP, 2, 0); SBAR;
      LD1(CP, 3, 0); SBAR; MM1P(CQ, 2, 1); SBAR;
      LD1(CQ, 3, 1); SBAR; MM1P(CP, 3, 0); SBAR;
      LD1(CP, 4, 0); SBAR; MM1P(CQ, 3, 1); SBAR;
      LD1(CQ, 4, 1); SBAR; MM1P(CP, 4, 0); SBAR;
      LD1(CP, 5, 0); SBAR; MM1P(CQ, 4, 1); SBAR;
      LD1(CQ, 5, 1); SBAR; MM1P(CP, 5, 0); SBAR;
      LD1(CP, 6, 0); SBAR; MM1P(CQ, 5, 1); SBAR;
      LD1(CQ, 6, 1); SBAR; MM1P(CP, 6, 0); SBAR;
      LD1(CP, 7, 0); SBAR; MM1P(CQ, 6, 1); SBAR;
      LD1(CQ, 7, 1); SBAR; MM1P(CP, 7, 0); SBAR;
      MM1P(CQ, 7, 1);
    }

    if constexpr (PHASE == 2) {
#pragma unroll
      for (int qt = 0; qt < 4; ++qt)
#pragma unroll
        for (int r2 = 0; r2 < 4; ++r2) {
          const float z = acc1[qt][r2];
          t1[r2] += z;
          t2v[r2] += z * z;
        }
    } else {
      float part[4];
#pragma unroll
      for (int qt = 0; qt < 4; ++qt) {
        part[qt] = 0.f;
#pragma unroll
        for (int r2 = 0; r2 < 4; ++r2) {
          const float z = acc1[qt][r2] + sh1v[r2];
          part[qt] += wv[r2] * fmaxf(z, 0.01f * z);
        }
      }
#pragma unroll
      for (int qt = 0; qt < 4; ++qt) {
        part[qt] += __shfl_xor(part[qt], 16, 64);
        part[qt] += __shfl_xor(part[qt], 32, 64);
      }
      if (lane < 16) {
#pragma unroll
        for (int qt = 0; qt < 4; ++qt)
          sb[wid * 64 + qt * 16 + lr] = part[qt];
      }
      pi0 = i0; pj0 = j0;
    }
  }

  if constexpr (PHASE == 3) {
    __syncthreads();
    if (tid < 64) {
      float sv = bout;
#pragma unroll
      for (int w = 0; w < 8; ++w) sv += sb[w * 64 + tid];
      sim[(pi0 + (tid >> 3)) * N_NODES + pj0 + (tid & 7)] = 1.f / (1.f + expf(-sv));
    }
  }

  if constexpr (PHASE == 2) {
#pragma unroll
    for (int r2 = 0; r2 < 4; ++r2) {
      float v1 = t1[r2], v2 = t2v[r2];
#pragma unroll
      for (int m = 1; m < 16; m <<= 1) {
        v1 += __shfl_xor(v1, m, 64);
        v2 += __shfl_xor(v2, m, 64);
      }
      t1[r2] = v1; t2v[r2] = v2;
    }
    __syncthreads();
    if (lr == 0) {
#pragma unroll
      for (int r2 = 0; r2 < 4; ++r2) {
        const int p = wid * 16 + g * 4 + r2;
        sb[p] = t1[r2];
        sb[128 + p] = t2v[r2];
      }
    }
    __syncthreads();
    if (tid < 256) atomicAdd(stats + tid, sb[tid]);
  }
}

// ---------------------------------------------------------------------------
// finalize: mean/var -> per-channel scale/shift for BN(+gamma,beta)
// ---------------------------------------------------------------------------
__global__ void finalize_kernel(const float* __restrict__ ssum, const float* __restrict__ ssq,
                                const float* __restrict__ gamma, const float* __restrict__ beta,
                                float* __restrict__ sc, float* __restrict__ sh, int n)
{
  const int i = (int)(blockIdx.x * blockDim.x + threadIdx.x);
  if (i < n) {
    const float invN = 1.f / 589824.f;
    const float m = ssum[i] * invN;
    const float var = ssq[i] * invN - m * m;
    const float is = rsqrtf(var + 1e-5f);
    const float s = gamma[i] * is;
    sc[i] = s;
    sh[i] = beta[i] - m * s;
  }
}

// ---------------------------------------------------------------------------
// edge graph tail (unchanged)
// ---------------------------------------------------------------------------
__global__ void colsum_kernel(const float* __restrict__ sim, const int* __restrict__ lab,
                              float* __restrict__ colsum)
{
  const int t = (int)threadIdx.x;
  const int bi = (int)blockIdx.x * 8;
  const int lj0 = lab[t], lj1 = lab[t + 256], lj2 = lab[t + 512];
  float a0 = 0.f, a1 = 0.f, a2 = 0.f;
  for (int r = 0; r < 8; ++r) {
    const int i = bi + r;
    const int li = lab[i];
    const float* srow = sim + i * N_NODES;
    a0 += ((li == lj0) ? srow[t] : 0.f) + ((i == t) ? 1.f : 0.f) + 1e-6f;
    a1 += ((li == lj1) ? srow[t + 256] : 0.f) + ((i == t + 256) ? 1.f : 0.f) + 1e-6f;
    a2 += ((li == lj2) ? srow[t + 512] : 0.f) + ((i == t + 512) ? 1.f : 0.f) + 1e-6f;
  }
  atomicAdd(colsum + t, a0);
  atomicAdd(colsum + t + 256, a1);
  atomicAdd(colsum + t + 512, a2);
}

__global__ void aggr_kernel(const float* __restrict__ sim, const int* __restrict__ lab,
                            const float* __restrict__ colsum, const float* __restrict__ feat,
                            float* __restrict__ aggr)
{
  __shared__ float wrow[N_NODES];
  __shared__ float red[128];
  const int i = (int)blockIdx.x, t = (int)threadIdx.x;
  const int li = lab[i];
  const float* srow = sim + i * N_NODES;
  float rs = 0.f;
  for (int s = 0; s < 6; ++s) {
    const int j = t + s * 128;
    const float e = ((li == lab[j]) ? srow[j] : 0.f) + ((i == j) ? 1.f : 0.f) + 1e-6f;
    const float w = (j == i) ? 0.f : e / colsum[j];
    wrow[j] = w;
    rs += w;
  }
  red[t] = rs;
  __syncthreads();
  for (int off = 64; off > 0; off >>= 1) {
    if (t < off) red[t] += red[t + off];
    __syncthreads();
  }
  const float inv = 1.f / fmaxf(red[0], 1e-12f);
  float acc = 0.f;
  for (int j = 0; j < N_NODES; ++j) acc += wrow[j] * feat[j * 128 + t];
  aggr[i * 128 + t] = acc * inv;
}

__global__ void mlp0_kernel(const float* __restrict__ feat, const float* __restrict__ aggr,
                            const float* __restrict__ w, const float* __restrict__ gamma,
                            const float* __restrict__ beta, float* __restrict__ h2)
{
  __shared__ float wr[256];
  __shared__ float redA[256], redB[256];
  const int r = (int)blockIdx.x, t = (int)threadIdx.x;
  wr[t] = w[r * 256 + t];
  __syncthreads();
  float v[3];
#pragma unroll
  for (int s = 0; s < 3; ++s) {
    const int n = t + s * 256;
    const float* fr = feat + n * 128;
    const float* ar = aggr + n * 128;
    float acc = 0.f;
#pragma unroll 4
    for (int c = 0; c < 128; c += 4) {
      const f32x4_t fv = *(const f32x4_t*)(fr + c);
      acc += wr[c] * fv[0] + wr[c + 1] * fv[1] + wr[c + 2] * fv[2] + wr[c + 3] * fv[3];
    }
#pragma unroll 4
    for (int c = 0; c < 128; c += 4) {
      const f32x4_t av = *(const f32x4_t*)(ar + c);
      acc += wr[128 + c] * av[0] + wr[129 + c] * av[1] + wr[130 + c] * av[2] + wr[131 + c] * av[3];
    }
    v[s] = acc;
  }
  redA[t] = v[0] + v[1] + v[2];
  redB[t] = v[0] * v[0] + v[1] * v[1] + v[2] * v[2];
  __syncthreads();
  for (int off = 128; off > 0; off >>= 1) {
    if (t < off) { redA[t] += redA[t + off]; redB[t] += redB[t + off]; }
    __syncthreads();
  }
  const float m = redA[0] * (1.f / 768.f);
  const float var = redB[0] * (1.f / 768.f) - m * m;
  const float is = rsqrtf(var + 1e-5f);
  const float sc = gamma[r] * is;
  const float sh = beta[r] - m * sc;
#pragma unroll
  for (int s = 0; s < 3; ++s) {
    float y = v[s] * sc + sh;
    y = (y >= 0.f) ? y : 0.01f * y;
    h2[r * 768 + t + s * 256] = y;
  }
}

__global__ void mlp1_kernel(const float* __restrict__ h2, const float* __restrict__ w,
                            const float* __restrict__ gamma, const float* __restrict__ beta,
                            float* __restrict__ logits)
{
  __shared__ float wr[130];
  __shared__ float redA[256], redB[256];
  const int r = (int)blockIdx.x, t = (int)threadIdx.x;
  if (t < 130) wr[t] = w[r * 130 + t];
  __syncthreads();
  float v[3];
#pragma unroll
  for (int s = 0; s < 3; ++s) {
    const int n = t + s * 256;
    float acc = 0.f;
    for (int c = 0; c < 130; ++c) acc += wr[c] * h2[c * 768 + n];
    v[s] = acc;
  }
  redA[t] = v[0] + v[1] + v[2];
  redB[t] = v[0] * v[0] + v[1] * v[1] + v[2] * v[2];
  __syncthreads();
  for (int off = 128; off > 0; off >>= 1) {
    if (t < off) { redA[t] += redA[t + off]; redB[t] += redB[t + off]; }
    __syncthreads();
  }
  const float m = redA[0] * (1.f / 768.f);
  const float var = redB[0] * (1.f / 768.f) - m * m;
  const float is = rsqrtf(var + 1e-5f);
  const float sc = gamma[r] * is;
  const float sh = beta[r] - m * sc;
#pragma unroll
  for (int s = 0; s < 3; ++s) {
    const float y = v[s] * sc + sh;
    logits[(t + s * 256) * 65 + r] = y;
  }
}

// ---------------------------------------------------------------------------
extern "C" void kernel_launch(void* const* d_in, const int* in_sizes, int n_in,
                              void* d_out, int out_size, void* d_ws, size_t ws_size,
                              hipStream_t stream)
{
  (void)in_sizes; (void)n_in; (void)out_size; (void)ws_size;
  const float* feat   = (const float*)d_in[0];
  const int*   lab    = (const int*)d_in[1];
  const float* e_w0   = (const float*)d_in[2];
  const float* e_g0   = (const float*)d_in[3];
  const float* e_b0   = (const float*)d_in[4];
  const float* e_w1   = (const float*)d_in[5];
  const float* e_g1   = (const float*)d_in[6];
  const float* e_b1   = (const float*)d_in[7];
  const float* e_wout = (const float*)d_in[8];
  const float* e_bout = (const float*)d_in[9];
  const float* n_w0   = (const float*)d_in[10];
  const float* n_g0   = (const float*)d_in[11];
  const float* n_b0   = (const float*)d_in[12];
  const float* n_w1   = (const float*)d_in[13];
  const float* n_g1   = (const float*)d_in[14];
  const float* n_b1   = (const float*)d_in[15];

  float* out = (float*)d_out;
  float* logits = out;                 // 768*65
  float* sim = out + 768 * 65;         // 768*768

  // workspace layout (floats)
  float* wsf = (float*)d_ws;
  float* S0A = wsf + 0;      // 256 sums + 256 sumsq
  float* S0B = wsf + 256;
  float* S1A = wsf + 512;    // 128 + 128
  float* S1B = wsf + 640;
  float* colsum = wsf + 768; // 768
  float* sc0 = wsf + 1536;   // 256
  float* sh0 = wsf + 1792;   // 256
  float* sc1 = wsf + 2048;   // 128
  float* sh1 = wsf + 2176;   // 128
  float* aggr = wsf + 2304;            // 768*128 (tail only)
  float* h2 = wsf + 2304 + 768 * 128;  // 130*768
  // featb aliases aggr's region (aggr written only after phase 3)
  __bf16* featb = (__bf16*)(wsf + 2304);            // 98304 bf16 (192KB)
  __bf16* W0bf = (__bf16*)(wsf + 200448);           // 32768 bf16
  __bf16* W1bf = (__bf16*)(wsf + 216832);
  __bf16* W0s  = (__bf16*)(wsf + 233216);           // sc0-folded
  __bf16* W1s  = (__bf16*)(wsf + 249600);           // sc1-folded

  hipMemsetAsync(d_ws, 0, 2304 * sizeof(float), stream);

  prep_kernel<<<384, 256, 0, stream>>>(feat, e_w0, e_w1, featb, W0bf, W1bf);

  pair_phase1_kernel<<<PAIR_GRID, 512, 0, stream>>>(featb, W0bf, S0A);
  finalize_kernel<<<1, 256, 0, stream>>>(S0A, S0B, e_g0, e_b0, sc0, sh0, 256);
  wscale_kernel<<<128, 256, 0, stream>>>(e_w0, sc0, W0s, 128, 32768);
  pair_phase_kernel<2><<<PAIR_GRID, 512, 0, stream>>>(featb, W0s, W1bf, nullptr, nullptr,
                                                      sh0, nullptr, S1A, nullptr);
  finalize_kernel<<<1, 128, 0, stream>>>(S1A, S1B, e_g1, e_b1, sc1, sh1, 128);
  wscale_kernel<<<128, 256, 0, stream>>>(e_w1, sc1, W1s, 256, 32768);
  pair_phase_kernel<3><<<PAIR_GRID, 512, 0, stream>>>(featb, W0s, W1s, e_wout, e_bout,
                                                      sh0, sh1, nullptr, sim);
  colsum_kernel<<<96, 256, 0, stream>>>(sim, lab, colsum);
  aggr_kernel<<<768, 128, 0, stream>>>(sim, lab, colsum, feat, aggr);
  mlp0_kernel<<<130, 256, 0, stream>>>(feat, aggr, n_w0, n_g0, n_b0, h2);
  mlp1_kernel<<<65, 256, 0, stream>>>(h2, n_w1, n_g1, n_b1, logits);
}